// Round 2
// baseline (2202.297 us; speedup 1.0000x reference)
//
#include <hip/hip_runtime.h>
#include <hip/hip_bf16.h>

typedef __hip_bfloat16 bf16;

#define N_NODES    50000
#define E_EDGES    400000
#define E_TOT      450000
#define NUM_GRAPHS 2048

// ---------- type helpers ----------
__device__ __forceinline__ float ldf(const float* p) { return *p; }
__device__ __forceinline__ float ldf(const bf16* p)  { return __bfloat162float(*p); }
__device__ __forceinline__ void  stf(float* p, float v) { *p = v; }
__device__ __forceinline__ void  stf(bf16* p, float v)  { *p = __float2bfloat16(v); }

// ---------- diagnostic: encode ws budget into out[0] if we must bail ----------
__global__ void diag_kernel(float* out, float v) { if (threadIdx.x == 0) out[0] = v; }

// ---------- graph build: counting sort of edges by dst ----------
__global__ void hist_kernel(const int* __restrict__ ei, int* __restrict__ counts) {
    int e = blockIdx.x * 256 + threadIdx.x;
    if (e >= E_TOT) return;
    int d = (e < E_EDGES) ? ei[E_EDGES + e] : (e - E_EDGES);
    atomicAdd(&counts[d], 1);
}

__global__ void scan_kernel(const int* __restrict__ counts, int* __restrict__ offsets) {
    __shared__ int sh[1024];
    const int N = N_NODES;
    const int CH = (N + 1023) / 1024;  // 49
    int t = threadIdx.x;
    int base = t * CH;
    int lsum = 0;
    for (int i = 0; i < CH; i++) {
        int idx = base + i;
        if (idx < N) lsum += counts[idx];
    }
    sh[t] = lsum;
    __syncthreads();
    for (int d = 1; d < 1024; d <<= 1) {
        int v = (t >= d) ? sh[t - d] : 0;
        __syncthreads();
        sh[t] += v;
        __syncthreads();
    }
    int run = sh[t] - lsum;   // exclusive prefix
    for (int i = 0; i < CH; i++) {
        int idx = base + i;
        if (idx < N) { offsets[idx] = run; run += counts[idx]; }
    }
    if (t == 0) offsets[N] = E_TOT;
}

__global__ void copy_kernel(const int* __restrict__ src, int* __restrict__ dst, int n) {
    int i = blockIdx.x * 256 + threadIdx.x;
    if (i < n) dst[i] = src[i];
}

__global__ void scatter_kernel(const int* __restrict__ ei, int* __restrict__ cursor,
                               int* __restrict__ srcs) {
    int e = blockIdx.x * 256 + threadIdx.x;
    if (e >= E_TOT) return;
    int s, d;
    if (e < E_EDGES) { s = ei[e]; d = ei[E_EDGES + e]; }
    else             { s = d = e - E_EDGES; }
    int pos = atomicAdd(&cursor[d], 1);
    srcs[pos] = s;
}

// ---------- generic GEMM: C = A@B + bias, optional relu; A row-major [M,K] lda,
// B fp32 [K, Nslice] with row stride ldb, C [M, Nslice] ldc ----------
template <bool RELU, typename TA, typename TO>
__global__ __launch_bounds__(256) void gemm_bias(const TA* __restrict__ A,
                                                 const float* __restrict__ B,
                                                 const float* __restrict__ bias,
                                                 TO* __restrict__ C,
                                                 int M, int N, int K,
                                                 int lda, int ldb, int ldc) {
    __shared__ float As[32][65];
    __shared__ float Bs[32][65];
    int tid = threadIdx.x;
    int tm = tid >> 4, tn = tid & 15;
    int bm = blockIdx.y * 64, bn = blockIdx.x * 64;
    float acc[4][4] = {};
    for (int k0 = 0; k0 < K; k0 += 32) {
        #pragma unroll
        for (int i = 0; i < 8; i++) {
            int e = tid + i * 256;
            int r = e >> 5, k = e & 31;
            int row = bm + r, kk = k0 + k;
            float v = 0.f;
            if (row < M && kk < K) v = ldf(&A[(size_t)row * lda + kk]);
            As[k][r] = v;
        }
        #pragma unroll
        for (int i = 0; i < 8; i++) {
            int e = tid + i * 256;
            int k = e >> 6, n = e & 63;
            int kk = k0 + k, col = bn + n;
            float v = 0.f;
            if (kk < K && col < N) v = B[(size_t)kk * ldb + col];
            Bs[k][n] = v;
        }
        __syncthreads();
        #pragma unroll
        for (int k = 0; k < 32; k++) {
            float a0 = As[k][tm * 4 + 0];
            float a1 = As[k][tm * 4 + 1];
            float a2 = As[k][tm * 4 + 2];
            float a3 = As[k][tm * 4 + 3];
            float b0 = Bs[k][tn * 4 + 0];
            float b1 = Bs[k][tn * 4 + 1];
            float b2 = Bs[k][tn * 4 + 2];
            float b3 = Bs[k][tn * 4 + 3];
            acc[0][0] += a0 * b0; acc[0][1] += a0 * b1; acc[0][2] += a0 * b2; acc[0][3] += a0 * b3;
            acc[1][0] += a1 * b0; acc[1][1] += a1 * b1; acc[1][2] += a1 * b2; acc[1][3] += a1 * b3;
            acc[2][0] += a2 * b0; acc[2][1] += a2 * b1; acc[2][2] += a2 * b2; acc[2][3] += a2 * b3;
            acc[3][0] += a3 * b0; acc[3][1] += a3 * b1; acc[3][2] += a3 * b2; acc[3][3] += a3 * b3;
        }
        __syncthreads();
    }
    #pragma unroll
    for (int i = 0; i < 4; i++) {
        int row = bm + tm * 4 + i;
        if (row >= M) continue;
        #pragma unroll
        for (int j = 0; j < 4; j++) {
            int col = bn + tn * 4 + j;
            if (col >= N) continue;
            float v = acc[i][j] + bias[col];
            if (RELU) v = fmaxf(v, 0.f);
            stf(&C[(size_t)row * ldc + col], v);
        }
    }
}

// ---------- GATv2 aggregation, one head at a time: wave per node, online softmax ----
// XL/XR: [N, CHH] bf16 (this head's transforms); att_h: [CHH]; OUT: [N, CHH] bf16.
// MODE 0: first head (OUT = v); 1: middle (OUT += v); 2: last (OUT = relu((OUT+v)/3 + bias))
template <int CHH, int MODE>
__global__ __launch_bounds__(256) void gat_head(const bf16* __restrict__ XL,
                                                const bf16* __restrict__ XR,
                                                const float* __restrict__ att_h,
                                                const float* __restrict__ bias,
                                                const int* __restrict__ offsets,
                                                const int* __restrict__ srcs,
                                                bf16* __restrict__ OUT, int N) {
    constexpr int R = CHH / 64;
    int wid  = threadIdx.x >> 6;
    int lane = threadIdx.x & 63;
    int n = blockIdx.x * 4 + wid;
    if (n >= N) return;

    float xr_[R], att_[R], acc[R];
    const bf16* xrp = XR + (size_t)n * CHH;
    #pragma unroll
    for (int r = 0; r < R; r++) {
        xr_[r]  = __bfloat162float(xrp[r * 64 + lane]);
        att_[r] = att_h[r * 64 + lane];
        acc[r]  = 0.f;
    }
    float m = -3.0e38f, denom = 0.f;

    int e0 = offsets[n], e1 = offsets[n + 1];
    for (int e = e0; e < e1; ++e) {
        int s = srcs[e];
        const bf16* xlp = XL + (size_t)s * CHH;
        float xls[R];
        #pragma unroll
        for (int r = 0; r < R; r++) xls[r] = __bfloat162float(xlp[r * 64 + lane]);

        float part = 0.f;
        #pragma unroll
        for (int r = 0; r < R; r++) {
            float v = xls[r] + xr_[r];
            v = (v > 0.f) ? v : 0.2f * v;      // leaky_relu(0.2)
            part += att_[r] * v;
        }
        #pragma unroll
        for (int ofs = 32; ofs > 0; ofs >>= 1)
            part += __shfl_xor(part, ofs);

        float mn = fmaxf(m, part);
        float sc = __expf(m - mn);
        float w  = __expf(part - mn);
        denom = denom * sc + w;
        m = mn;
        #pragma unroll
        for (int r = 0; r < R; r++) acc[r] = acc[r] * sc + w * xls[r];
    }

    float inv = 1.f / (denom + 1e-16f);
    #pragma unroll
    for (int r = 0; r < R; r++) {
        int c = r * 64 + lane;
        size_t idx = (size_t)n * CHH + c;
        float v = acc[r] * inv;
        if (MODE > 0) v += __bfloat162float(OUT[idx]);
        if (MODE == 2) {
            v = v * (1.f / 3.f) + bias[c];
            v = fmaxf(v, 0.f);                 // outer relu on every layer
        }
        OUT[idx] = __float2bfloat16(v);
    }
}

// ---------- pooling: g[batch[n]] += h3[n] ----------
__global__ void pool_kernel(const bf16* __restrict__ h, const int* __restrict__ batch,
                            float* __restrict__ g) {
    int n = blockIdx.x;
    int c = threadIdx.x;
    float v = __bfloat162float(h[(size_t)n * 256 + c]);
    atomicAdd(&g[(size_t)batch[n] * 256 + c], v);
}

// ---------- output assembly: split + symmetrize ----------
__global__ void assemble_kernel(const float* __restrict__ o3, float* __restrict__ out) {
    int g = blockIdx.x;
    const float* row = o3 + (size_t)g * 1160;
    float* xrec = out + (size_t)g * 319;
    for (int p = threadIdx.x; p < 319; p += 256) xrec[p] = row[p];
    float* adj = out + 653312 + (size_t)g * 841;
    for (int p = threadIdx.x; p < 841; p += 256) {
        int i = p / 29, j = p % 29;
        adj[p] = 0.5f * (row[319 + p] + row[319 + j * 29 + i]);
    }
}

// ---------- launch ----------
extern "C" void kernel_launch(void* const* d_in, const int* in_sizes, int n_in,
                              void* d_out, int out_size, void* d_ws, size_t ws_size,
                              hipStream_t stream) {
    const float* x     = (const float*)d_in[0];
    const int*   ei    = (const int*)d_in[1];
    const int*   batch = (const int*)d_in[2];
    const float* Wl1 = (const float*)d_in[3];
    const float* bl1 = (const float*)d_in[4];
    const float* Wr1 = (const float*)d_in[5];
    const float* br1 = (const float*)d_in[6];
    const float* att1= (const float*)d_in[7];
    const float* b1  = (const float*)d_in[8];
    const float* Wl2 = (const float*)d_in[9];
    const float* bl2 = (const float*)d_in[10];
    const float* Wr2 = (const float*)d_in[11];
    const float* br2 = (const float*)d_in[12];
    const float* att2= (const float*)d_in[13];
    const float* b2  = (const float*)d_in[14];
    const float* Wl3 = (const float*)d_in[15];
    const float* bl3 = (const float*)d_in[16];
    const float* Wr3 = (const float*)d_in[17];
    const float* br3 = (const float*)d_in[18];
    const float* att3= (const float*)d_in[19];
    const float* b3  = (const float*)d_in[20];
    const float* Wmu = (const float*)d_in[21];
    const float* bmu = (const float*)d_in[22];
    const float* Wlv = (const float*)d_in[23];
    const float* blv = (const float*)d_in[24];
    const float* Wd1 = (const float*)d_in[25];
    const float* bd1 = (const float*)d_in[26];
    const float* Wd2 = (const float*)d_in[27];
    const float* bd2 = (const float*)d_in[28];
    const float* Wd3 = (const float*)d_in[29];
    const float* bd3 = (const float*)d_in[30];
    float* out = (float*)d_out;

    // ---- workspace layout (bytes) ----
    // h3 (bf16 50000x256) at 0; h1 (bf16 50000x64) aliases its head (disjoint lifetime)
    // h2 (bf16 50000x128) | XL (bf16 50000x256) | XR (bf16 50000x256) | CSR
    // decoder scratch (G,O1,O2,O3 fp32 ~17.9MB) aliases XL region (dead after layer-3 agg)
    char* wsb = (char*)d_ws;
    bf16* h3 = (bf16*)(wsb + 0);
    bf16* h1 = (bf16*)(wsb + 0);
    bf16* h2 = (bf16*)(wsb + 25600000);
    bf16* XL = (bf16*)(wsb + 38400000);
    bf16* XR = (bf16*)(wsb + 64000000);
    float* G  = (float*)(wsb + 38400000);   // alias XL region
    float* O1 = G  + 524288;                //  2048*256
    float* O2 = O1 + 524288;                //  2048*512
    float* O3 = O2 + 1048576;               //  2048*1160 (ends < 56.3MB, inside XL+dec region)
    int* counts  = (int*)(wsb + 89600000);
    int* offsets = counts + (N_NODES + 1);
    int* cursor  = offsets + (N_NODES + 1);
    int* srcs    = cursor + (N_NODES + 1);  // 450000 ints

    size_t needed = 89600000 + (size_t)(3 * (N_NODES + 1) + E_TOT) * 4;  // ~92.0 MB
    if (ws_size < needed) {
        // diagnostic: absmax error will read ~= ws_size in MB
        hipLaunchKernelGGL(diag_kernel, dim3(1), dim3(64), 0, stream, out, (float)(ws_size >> 20));
        return;
    }

    const int MU_OFF = 2375680;   // 653312 + 1722368
    const int LV_OFF = 2506752;

    // ---- build CSR (dst-sorted edge list), shared by all layers ----
    hipMemsetAsync(counts, 0, sizeof(int) * (N_NODES + 1), stream);
    hipLaunchKernelGGL(hist_kernel, dim3((E_TOT + 255) / 256), dim3(256), 0, stream, ei, counts);
    hipLaunchKernelGGL(scan_kernel, dim3(1), dim3(1024), 0, stream, counts, offsets);
    hipLaunchKernelGGL(copy_kernel, dim3((N_NODES + 255) / 256), dim3(256), 0, stream,
                       offsets, cursor, N_NODES);
    hipLaunchKernelGGL(scatter_kernel, dim3((E_TOT + 255) / 256), dim3(256), 0, stream,
                       ei, cursor, srcs);

    const int MB = (N_NODES + 63) / 64;   // 782
    const dim3 AGG_GRID(N_NODES / 4);     // 12500 blocks, 4 waves each

    // ---- layer 1: in=11 (fp32 x), per-head C=64 ----
    for (int h = 0; h < 3; ++h) {
        hipLaunchKernelGGL((gemm_bias<false, float, bf16>), dim3(1, MB), dim3(256), 0, stream,
                           x, Wl1 + h * 64, bl1 + h * 64, XL, N_NODES, 64, 11, 11, 192, 64);
        hipLaunchKernelGGL((gemm_bias<false, float, bf16>), dim3(1, MB), dim3(256), 0, stream,
                           x, Wr1 + h * 64, br1 + h * 64, XR, N_NODES, 64, 11, 11, 192, 64);
        if (h == 0)      hipLaunchKernelGGL((gat_head<64, 0>), AGG_GRID, dim3(256), 0, stream,
                                            XL, XR, att1 + h * 64, b1, offsets, srcs, h1, N_NODES);
        else if (h == 1) hipLaunchKernelGGL((gat_head<64, 1>), AGG_GRID, dim3(256), 0, stream,
                                            XL, XR, att1 + h * 64, b1, offsets, srcs, h1, N_NODES);
        else             hipLaunchKernelGGL((gat_head<64, 2>), AGG_GRID, dim3(256), 0, stream,
                                            XL, XR, att1 + h * 64, b1, offsets, srcs, h1, N_NODES);
    }

    // ---- layer 2: in=64 (bf16 h1), per-head C=128 ----
    for (int h = 0; h < 3; ++h) {
        hipLaunchKernelGGL((gemm_bias<false, bf16, bf16>), dim3(2, MB), dim3(256), 0, stream,
                           h1, Wl2 + h * 128, bl2 + h * 128, XL, N_NODES, 128, 64, 64, 384, 128);
        hipLaunchKernelGGL((gemm_bias<false, bf16, bf16>), dim3(2, MB), dim3(256), 0, stream,
                           h1, Wr2 + h * 128, br2 + h * 128, XR, N_NODES, 128, 64, 64, 384, 128);
        if (h == 0)      hipLaunchKernelGGL((gat_head<128, 0>), AGG_GRID, dim3(256), 0, stream,
                                            XL, XR, att2 + h * 128, b2, offsets, srcs, h2, N_NODES);
        else if (h == 1) hipLaunchKernelGGL((gat_head<128, 1>), AGG_GRID, dim3(256), 0, stream,
                                            XL, XR, att2 + h * 128, b2, offsets, srcs, h2, N_NODES);
        else             hipLaunchKernelGGL((gat_head<128, 2>), AGG_GRID, dim3(256), 0, stream,
                                            XL, XR, att2 + h * 128, b2, offsets, srcs, h2, N_NODES);
    }

    // ---- layer 3: in=128 (bf16 h2), per-head C=256; h3 aliases h1 (h1 dead now) ----
    for (int h = 0; h < 3; ++h) {
        hipLaunchKernelGGL((gemm_bias<false, bf16, bf16>), dim3(4, MB), dim3(256), 0, stream,
                           h2, Wl3 + h * 256, bl3 + h * 256, XL, N_NODES, 256, 128, 128, 768, 256);
        hipLaunchKernelGGL((gemm_bias<false, bf16, bf16>), dim3(4, MB), dim3(256), 0, stream,
                           h2, Wr3 + h * 256, br3 + h * 256, XR, N_NODES, 256, 128, 128, 768, 256);
        if (h == 0)      hipLaunchKernelGGL((gat_head<256, 0>), AGG_GRID, dim3(256), 0, stream,
                                            XL, XR, att3 + h * 256, b3, offsets, srcs, h3, N_NODES);
        else if (h == 1) hipLaunchKernelGGL((gat_head<256, 1>), AGG_GRID, dim3(256), 0, stream,
                                            XL, XR, att3 + h * 256, b3, offsets, srcs, h3, N_NODES);
        else             hipLaunchKernelGGL((gat_head<256, 2>), AGG_GRID, dim3(256), 0, stream,
                                            XL, XR, att3 + h * 256, b3, offsets, srcs, h3, N_NODES);
    }

    // ---- global add pool (G aliases XL region — XL/XR dead now) ----
    hipMemsetAsync(G, 0, sizeof(float) * NUM_GRAPHS * 256, stream);
    hipLaunchKernelGGL(pool_kernel, dim3(N_NODES), dim3(256), 0, stream, h3, batch, G);

    // ---- VAE heads + decoder (all fp32) ----
    hipLaunchKernelGGL((gemm_bias<false, float, float>), dim3(1, 32), dim3(256), 0, stream,
                       G, Wmu, bmu, out + MU_OFF, NUM_GRAPHS, 64, 256, 256, 64, 64);
    hipLaunchKernelGGL((gemm_bias<false, float, float>), dim3(1, 32), dim3(256), 0, stream,
                       G, Wlv, blv, out + LV_OFF, NUM_GRAPHS, 64, 256, 256, 64, 64);
    hipLaunchKernelGGL((gemm_bias<true, float, float>), dim3(4, 32), dim3(256), 0, stream,
                       out + MU_OFF, Wd1, bd1, O1, NUM_GRAPHS, 256, 64, 64, 256, 256);
    hipLaunchKernelGGL((gemm_bias<true, float, float>), dim3(8, 32), dim3(256), 0, stream,
                       O1, Wd2, bd2, O2, NUM_GRAPHS, 512, 256, 256, 512, 512);
    hipLaunchKernelGGL((gemm_bias<false, float, float>), dim3(19, 32), dim3(256), 0, stream,
                       O2, Wd3, bd3, O3, NUM_GRAPHS, 1160, 512, 512, 1160, 1160);
    hipLaunchKernelGGL(assemble_kernel, dim3(NUM_GRAPHS), dim3(256), 0, stream, O3, out);
}

// Round 3
// 1420.234 us; speedup vs baseline: 1.5507x; 1.5507x over previous
//
#include <hip/hip_runtime.h>
#include <hip/hip_bf16.h>

typedef __hip_bfloat16 bf16;
typedef unsigned short ushortT;
typedef ushortT u16x2 __attribute__((ext_vector_type(2)));
typedef ushortT u16x4 __attribute__((ext_vector_type(4)));
typedef ushortT u16x8 __attribute__((ext_vector_type(8)));
typedef __bf16   bf16x8 __attribute__((ext_vector_type(8)));
typedef float    f32x4  __attribute__((ext_vector_type(4)));

#define N_NODES    50000
#define E_EDGES    400000
#define E_TOT      450000
#define NUM_GRAPHS 2048

// ---------- helpers ----------
__device__ __forceinline__ float fromb(ushortT u) {
    unsigned int i = ((unsigned int)u) << 16;
    return __builtin_bit_cast(float, i);
}
__device__ __forceinline__ ushortT tob(float v) {
    bf16 h = __float2bfloat16(v);
    return __builtin_bit_cast(ushortT, h);
}
__device__ __forceinline__ float ldf(const float* p) { return *p; }
__device__ __forceinline__ float ldf(const bf16* p)  { return __bfloat162float(*p); }
__device__ __forceinline__ void  stf(float* p, float v) { *p = v; }
__device__ __forceinline__ void  stf(bf16* p, float v)  { *p = __float2bfloat16(v); }

template <int VEC> struct RawV;
template <> struct RawV<1> { using T = ushortT; };
template <> struct RawV<2> { using T = u16x2; };
template <> struct RawV<4> { using T = u16x4; };

__device__ __forceinline__ void cvtv(ushortT r, float* f) { f[0] = fromb(r); }
__device__ __forceinline__ void cvtv(u16x2 r, float* f)   { f[0] = fromb(r.x); f[1] = fromb(r.y); }
__device__ __forceinline__ void cvtv(u16x4 r, float* f)   { f[0] = fromb(r.x); f[1] = fromb(r.y);
                                                            f[2] = fromb(r.z); f[3] = fromb(r.w); }

// ---------- diagnostic ----------
__global__ void diag_kernel(float* out, float v) { if (threadIdx.x == 0) out[0] = v; }

// ---------- CSR build ----------
__global__ void hist_kernel(const int* __restrict__ ei, int* __restrict__ counts) {
    int e = blockIdx.x * 256 + threadIdx.x;
    if (e >= E_TOT) return;
    int d = (e < E_EDGES) ? ei[E_EDGES + e] : (e - E_EDGES);
    atomicAdd(&counts[d], 1);
}

__global__ void scan_kernel(const int* __restrict__ counts, int* __restrict__ offsets) {
    __shared__ int sh[1024];
    const int N = N_NODES;
    const int CH = (N + 1023) / 1024;
    int t = threadIdx.x;
    int base = t * CH;
    int lsum = 0;
    for (int i = 0; i < CH; i++) {
        int idx = base + i;
        if (idx < N) lsum += counts[idx];
    }
    sh[t] = lsum;
    __syncthreads();
    for (int d = 1; d < 1024; d <<= 1) {
        int v = (t >= d) ? sh[t - d] : 0;
        __syncthreads();
        sh[t] += v;
        __syncthreads();
    }
    int run = sh[t] - lsum;
    for (int i = 0; i < CH; i++) {
        int idx = base + i;
        if (idx < N) { offsets[idx] = run; run += counts[idx]; }
    }
    if (t == 0) offsets[N] = E_TOT;
}

__global__ void copy_kernel(const int* __restrict__ src, int* __restrict__ dst, int n) {
    int i = blockIdx.x * 256 + threadIdx.x;
    if (i < n) dst[i] = src[i];
}

__global__ void scatter_kernel(const int* __restrict__ ei, int* __restrict__ cursor,
                               int* __restrict__ srcs) {
    int e = blockIdx.x * 256 + threadIdx.x;
    if (e >= E_TOT) return;
    int s, d;
    if (e < E_EDGES) { s = ei[e]; d = ei[E_EDGES + e]; }
    else             { s = d = e - E_EDGES; }
    int pos = atomicAdd(&cursor[d], 1);
    srcs[pos] = s;
}

// ---------- weight repack: W fp32 [K,N] -> Bp bf16 [(k>>3)*N + n]*8 + (k&7) ----------
__global__ void repack_kernel(const float* __restrict__ W, ushortT* __restrict__ Bp,
                              int K, int N) {
    int idx = blockIdx.x * 256 + threadIdx.x;
    if (idx >= K * N) return;
    int k = idx / N, n = idx % N;
    Bp[((size_t)(k >> 3) * N + n) * 8 + (k & 7)] = tob(W[idx]);
}

// ---------- SIMT fp32 GEMM (layer-1 + decoder) ----------
template <bool RELU, typename TA, typename TO>
__global__ __launch_bounds__(256) void gemm_bias(const TA* __restrict__ A,
                                                 const float* __restrict__ B,
                                                 const float* __restrict__ bias,
                                                 TO* __restrict__ C,
                                                 int M, int N, int K,
                                                 int lda, int ldb, int ldc) {
    __shared__ float As[32][65];
    __shared__ float Bs[32][65];
    int tid = threadIdx.x;
    int tm = tid >> 4, tn = tid & 15;
    int bm = blockIdx.y * 64, bn = blockIdx.x * 64;
    float acc[4][4] = {};
    for (int k0 = 0; k0 < K; k0 += 32) {
        #pragma unroll
        for (int i = 0; i < 8; i++) {
            int e = tid + i * 256;
            int r = e >> 5, k = e & 31;
            int row = bm + r, kk = k0 + k;
            float v = 0.f;
            if (row < M && kk < K) v = ldf(&A[(size_t)row * lda + kk]);
            As[k][r] = v;
        }
        #pragma unroll
        for (int i = 0; i < 8; i++) {
            int e = tid + i * 256;
            int k = e >> 6, n = e & 63;
            int kk = k0 + k, col = bn + n;
            float v = 0.f;
            if (kk < K && col < N) v = B[(size_t)kk * ldb + col];
            Bs[k][n] = v;
        }
        __syncthreads();
        #pragma unroll
        for (int k = 0; k < 32; k++) {
            float a0 = As[k][tm * 4 + 0], a1 = As[k][tm * 4 + 1];
            float a2 = As[k][tm * 4 + 2], a3 = As[k][tm * 4 + 3];
            float b0 = Bs[k][tn * 4 + 0], b1 = Bs[k][tn * 4 + 1];
            float b2 = Bs[k][tn * 4 + 2], b3 = Bs[k][tn * 4 + 3];
            acc[0][0] += a0 * b0; acc[0][1] += a0 * b1; acc[0][2] += a0 * b2; acc[0][3] += a0 * b3;
            acc[1][0] += a1 * b0; acc[1][1] += a1 * b1; acc[1][2] += a1 * b2; acc[1][3] += a1 * b3;
            acc[2][0] += a2 * b0; acc[2][1] += a2 * b1; acc[2][2] += a2 * b2; acc[2][3] += a2 * b3;
            acc[3][0] += a3 * b0; acc[3][1] += a3 * b1; acc[3][2] += a3 * b2; acc[3][3] += a3 * b3;
        }
        __syncthreads();
    }
    #pragma unroll
    for (int i = 0; i < 4; i++) {
        int row = bm + tm * 4 + i;
        if (row >= M) continue;
        #pragma unroll
        for (int j = 0; j < 4; j++) {
            int col = bn + tn * 4 + j;
            if (col >= N) continue;
            float v = acc[i][j] + bias[col];
            if (RELU) v = fmaxf(v, 0.f);
            stf(&C[(size_t)row * ldc + col], v);
        }
    }
}

// ---------- MFMA bf16 GEMM for node transforms ----------
// A bf16 [M,K]; BpL/BpR repacked weights over full [K,Nfull]; head slice at n0, width CHH.
// Block: 256 thr (4 waves, 2x2), tile 128 rows x 128 cols; cols<CHH -> XL, else -> XR.
template <int K, int CHH>
__global__ __launch_bounds__(256) void mfma_gemm(const ushortT* __restrict__ A,
                                                 const ushortT* __restrict__ BpL,
                                                 const ushortT* __restrict__ BpR,
                                                 const float* __restrict__ bl,
                                                 const float* __restrict__ br,
                                                 bf16* __restrict__ XL,
                                                 bf16* __restrict__ XR,
                                                 int M, int Nfull, int n0) {
    constexpr int KU = K / 8;               // 16B units per A row
    __shared__ ushortT Alds[KU * 128 * 8];  // [kg][row][8] with XOR(kg&7) swizzle on unit idx
    const int tid = threadIdx.x;
    const int bm  = blockIdx.y * 128;
    const int bnb = blockIdx.x * 128;       // col_local base of block (0..2*CHH-1)

    // ---- stage A tile (coalesced global, swizzled LDS) ----
    for (int u = tid; u < 128 * KU; u += 256) {
        int row = u / KU, kg = u % KU;
        int rg = bm + row; if (rg > M - 1) rg = M - 1;
        u16x8 v = *reinterpret_cast<const u16x8*>(A + (size_t)rg * K + kg * 8);
        int unit = (kg * 128 + row) ^ (kg & 7);
        *reinterpret_cast<u16x8*>(&Alds[unit * 8]) = v;
    }
    __syncthreads();

    const int lane = tid & 63;
    const int l15 = lane & 15, lg = lane >> 4;
    const int wid = tid >> 6;
    const int wm = wid >> 1, wn = wid & 1;

    f32x4 acc[4][4] = {};
    #pragma unroll
    for (int s = 0; s < K / 32; s++) {
        int kg = s * 4 + lg;
        bf16x8 a[4], b[4];
        #pragma unroll
        for (int mf = 0; mf < 4; mf++) {
            int row = wm * 64 + mf * 16 + l15;
            int unit = (kg * 128 + row) ^ (kg & 7);
            a[mf] = __builtin_bit_cast(bf16x8,
                    *reinterpret_cast<const u16x8*>(&Alds[unit * 8]));
        }
        #pragma unroll
        for (int nf = 0; nf < 4; nf++) {
            int cb = bnb + wn * 64 + nf * 16;          // uniform per nf
            const ushortT* bp; int n;
            if (cb < CHH) { bp = BpL; n = n0 + cb + l15; }
            else          { bp = BpR; n = n0 + cb - CHH + l15; }
            b[nf] = __builtin_bit_cast(bf16x8,
                    *reinterpret_cast<const u16x8*>(bp + ((size_t)kg * Nfull + n) * 8));
        }
        #pragma unroll
        for (int mf = 0; mf < 4; mf++)
            #pragma unroll
            for (int nf = 0; nf < 4; nf++)
                acc[mf][nf] = __builtin_amdgcn_mfma_f32_16x16x32_bf16(
                    a[mf], b[nf], acc[mf][nf], 0, 0, 0);
    }

    // ---- epilogue: C/D map col=lane&15, row=(lane>>4)*4+q ----
    #pragma unroll
    for (int nf = 0; nf < 4; nf++) {
        int cb = bnb + wn * 64 + nf * 16;
        bf16* Cp; const float* bs; int c;
        if (cb < CHH) { Cp = XL; bs = bl; c = cb + l15; }
        else          { Cp = XR; bs = br; c = cb - CHH + l15; }
        float bv = bs[c];
        #pragma unroll
        for (int mf = 0; mf < 4; mf++) {
            #pragma unroll
            for (int q = 0; q < 4; q++) {
                int r = bm + wm * 64 + mf * 16 + lg * 4 + q;
                if (r < M) Cp[(size_t)r * CHH + c] = __float2bfloat16(acc[mf][nf][q] + bv);
            }
        }
    }
}

// ---------- GATv2 aggregation per head: wave/node, online softmax, vectorized gather ----
template <int CHH, int MODE>
__global__ __launch_bounds__(256) void gat_head(const ushortT* __restrict__ XL,
                                                const ushortT* __restrict__ XR,
                                                int ldx, int offx,
                                                const float* __restrict__ att_h,
                                                const float* __restrict__ bias,
                                                const int* __restrict__ offsets,
                                                const int* __restrict__ srcs,
                                                ushortT* __restrict__ OUT, int N) {
    constexpr int VEC = CHH / 64;
    using RT = typename RawV<VEC>::T;
    int wid  = threadIdx.x >> 6;
    int lane = threadIdx.x & 63;
    int n = blockIdx.x * 4 + wid;
    if (n >= N) return;

    float xr_[VEC], att_[VEC], acc[VEC];
    const ushortT* xrp = XR + (size_t)n * ldx + offx + VEC * lane;
    #pragma unroll
    for (int i = 0; i < VEC; i++) {
        xr_[i]  = fromb(xrp[i]);
        att_[i] = att_h[VEC * lane + i];
        acc[i]  = 0.f;
    }
    float m = -3.0e38f, denom = 0.f;

    int e0 = offsets[n], e1 = offsets[n + 1];
    RT nxt = *reinterpret_cast<const RT*>(XL + (size_t)srcs[e0] * ldx + offx + VEC * lane);
    for (int e = e0; e < e1; ++e) {
        RT cur = nxt;
        if (e + 1 < e1)
            nxt = *reinterpret_cast<const RT*>(XL + (size_t)srcs[e + 1] * ldx + offx + VEC * lane);
        float xl[VEC];
        cvtv(cur, xl);
        float part = 0.f;
        #pragma unroll
        for (int i = 0; i < VEC; i++) {
            float v = xl[i] + xr_[i];
            v = (v > 0.f) ? v : 0.2f * v;           // leaky_relu(0.2)
            part += att_[i] * v;
        }
        #pragma unroll
        for (int ofs = 32; ofs > 0; ofs >>= 1)
            part += __shfl_xor(part, ofs);

        float mn = fmaxf(m, part);
        float sc = __expf(m - mn);
        float w  = __expf(part - mn);
        denom = denom * sc + w;
        m = mn;
        #pragma unroll
        for (int i = 0; i < VEC; i++) acc[i] = acc[i] * sc + w * xl[i];
    }

    float inv = 1.f / (denom + 1e-16f);
    #pragma unroll
    for (int i = 0; i < VEC; i++) {
        int c = VEC * lane + i;
        size_t idx = (size_t)n * CHH + c;
        float v = acc[i] * inv;
        if (MODE > 0) v += fromb(OUT[idx]);
        if (MODE == 2) { v = v * (1.f / 3.f) + bias[c]; v = fmaxf(v, 0.f); }
        OUT[idx] = tob(v);
    }
}

// ---------- pool: block per graph, binary search on sorted batch, no atomics ----------
__global__ void pool_kernel(const ushortT* __restrict__ h3, const int* __restrict__ batch,
                            float* __restrict__ G) {
    int g = blockIdx.x;
    int c = threadIdx.x;
    int lo = 0, hi = N_NODES;
    while (lo < hi) { int mid = (lo + hi) >> 1; if (batch[mid] < g) lo = mid + 1; else hi = mid; }
    int s0 = lo;
    hi = N_NODES;
    while (lo < hi) { int mid = (lo + hi) >> 1; if (batch[mid] < g + 1) lo = mid + 1; else hi = mid; }
    int s1 = lo;
    float sum = 0.f;
    for (int n = s0; n < s1; n++) sum += fromb(h3[(size_t)n * 256 + c]);
    G[(size_t)g * 256 + c] = sum;
}

// ---------- output assembly ----------
__global__ void assemble_kernel(const float* __restrict__ o3, float* __restrict__ out) {
    int g = blockIdx.x;
    const float* row = o3 + (size_t)g * 1160;
    float* xrec = out + (size_t)g * 319;
    for (int p = threadIdx.x; p < 319; p += 256) xrec[p] = row[p];
    float* adj = out + 653312 + (size_t)g * 841;
    for (int p = threadIdx.x; p < 841; p += 256) {
        int i = p / 29, j = p % 29;
        adj[p] = 0.5f * (row[319 + p] + row[319 + j * 29 + i]);
    }
}

// ---------- launch ----------
extern "C" void kernel_launch(void* const* d_in, const int* in_sizes, int n_in,
                              void* d_out, int out_size, void* d_ws, size_t ws_size,
                              hipStream_t stream) {
    const float* x     = (const float*)d_in[0];
    const int*   ei    = (const int*)d_in[1];
    const int*   batch = (const int*)d_in[2];
    const float* Wl1 = (const float*)d_in[3];
    const float* bl1 = (const float*)d_in[4];
    const float* Wr1 = (const float*)d_in[5];
    const float* br1 = (const float*)d_in[6];
    const float* att1= (const float*)d_in[7];
    const float* b1  = (const float*)d_in[8];
    const float* Wl2 = (const float*)d_in[9];
    const float* bl2 = (const float*)d_in[10];
    const float* Wr2 = (const float*)d_in[11];
    const float* br2 = (const float*)d_in[12];
    const float* att2= (const float*)d_in[13];
    const float* b2  = (const float*)d_in[14];
    const float* Wl3 = (const float*)d_in[15];
    const float* bl3 = (const float*)d_in[16];
    const float* Wr3 = (const float*)d_in[17];
    const float* br3 = (const float*)d_in[18];
    const float* att3= (const float*)d_in[19];
    const float* b3  = (const float*)d_in[20];
    const float* Wmu = (const float*)d_in[21];
    const float* bmu = (const float*)d_in[22];
    const float* Wlv = (const float*)d_in[23];
    const float* blv = (const float*)d_in[24];
    const float* Wd1 = (const float*)d_in[25];
    const float* bd1 = (const float*)d_in[26];
    const float* Wd2 = (const float*)d_in[27];
    const float* bd2 = (const float*)d_in[28];
    const float* Wd3 = (const float*)d_in[29];
    const float* bd3 = (const float*)d_in[30];
    float* out = (float*)d_out;

    // ---- workspace layout (bytes) ----
    char* wsb = (char*)d_ws;
    bf16*    h3b = (bf16*)(wsb + 0);            // 50000x256 bf16 (aliases h1)
    ushortT* h3u = (ushortT*)(wsb + 0);
    bf16*    h1b = (bf16*)(wsb + 0);            // 50000x64
    ushortT* h1u = (ushortT*)(wsb + 0);
    bf16*    h2b = (bf16*)(wsb + 25600000);     // 50000x128
    ushortT* h2u = (ushortT*)(wsb + 25600000);
    bf16*    XLb = (bf16*)(wsb + 38400000);     // up to 50000x256
    ushortT* XLu = (ushortT*)(wsb + 38400000);
    bf16*    XRb = (bf16*)(wsb + 64000000);
    ushortT* XRu = (ushortT*)(wsb + 64000000);
    float* G  = (float*)(wsb + 38400000);       // decoder scratch aliases XL/XR (dead then)
    float* O1 = G  + 524288;
    float* O2 = O1 + 524288;
    float* O3 = O2 + 1048576;
    int* counts  = (int*)(wsb + 89600000);
    int* offsets = counts + (N_NODES + 1);
    int* cursor  = offsets + (N_NODES + 1);
    int* srcs    = cursor + (N_NODES + 1);      // 450000 ints
    ushortT* BpL2 = (ushortT*)(wsb + 92000016); // 64x384  repacked
    ushortT* BpR2 = (ushortT*)(wsb + 92049168);
    ushortT* BpL3 = (ushortT*)(wsb + 92098320); // 128x768 repacked
    ushortT* BpR3 = (ushortT*)(wsb + 92294928);

    size_t needed = 92491536;
    if (ws_size < needed) {
        hipLaunchKernelGGL(diag_kernel, dim3(1), dim3(64), 0, stream, out, (float)(ws_size >> 20));
        return;
    }

    const int MU_OFF = 2375680;
    const int LV_OFF = 2506752;

    // ---- CSR build ----
    hipMemsetAsync(counts, 0, sizeof(int) * (N_NODES + 1), stream);
    hipLaunchKernelGGL(hist_kernel, dim3((E_TOT + 255) / 256), dim3(256), 0, stream, ei, counts);
    hipLaunchKernelGGL(scan_kernel, dim3(1), dim3(1024), 0, stream, counts, offsets);
    hipLaunchKernelGGL(copy_kernel, dim3((N_NODES + 255) / 256), dim3(256), 0, stream,
                       offsets, cursor, N_NODES);
    hipLaunchKernelGGL(scatter_kernel, dim3((E_TOT + 255) / 256), dim3(256), 0, stream,
                       ei, cursor, srcs);

    // ---- weight repack (bf16, fragment-friendly) ----
    hipLaunchKernelGGL(repack_kernel, dim3((64 * 384 + 255) / 256), dim3(256), 0, stream,
                       Wl2, BpL2, 64, 384);
    hipLaunchKernelGGL(repack_kernel, dim3((64 * 384 + 255) / 256), dim3(256), 0, stream,
                       Wr2, BpR2, 64, 384);
    hipLaunchKernelGGL(repack_kernel, dim3((128 * 768 + 255) / 256), dim3(256), 0, stream,
                       Wl3, BpL3, 128, 768);
    hipLaunchKernelGGL(repack_kernel, dim3((128 * 768 + 255) / 256), dim3(256), 0, stream,
                       Wr3, BpR3, 128, 768);

    const int MB = (N_NODES + 63) / 64;   // 782
    const dim3 AGG_GRID(N_NODES / 4);

    // ---- layer 1 (K=11, SIMT): full-width N=192 in 2 launches ----
    hipLaunchKernelGGL((gemm_bias<false, float, bf16>), dim3(3, MB), dim3(256), 0, stream,
                       x, Wl1, bl1, XLb, N_NODES, 192, 11, 11, 192, 192);
    hipLaunchKernelGGL((gemm_bias<false, float, bf16>), dim3(3, MB), dim3(256), 0, stream,
                       x, Wr1, br1, XRb, N_NODES, 192, 11, 11, 192, 192);
    hipLaunchKernelGGL((gat_head<64, 0>), AGG_GRID, dim3(256), 0, stream,
                       XLu, XRu, 192, 0,   att1 + 0,   b1, offsets, srcs, h1u, N_NODES);
    hipLaunchKernelGGL((gat_head<64, 1>), AGG_GRID, dim3(256), 0, stream,
                       XLu, XRu, 192, 64,  att1 + 64,  b1, offsets, srcs, h1u, N_NODES);
    hipLaunchKernelGGL((gat_head<64, 2>), AGG_GRID, dim3(256), 0, stream,
                       XLu, XRu, 192, 128, att1 + 128, b1, offsets, srcs, h1u, N_NODES);

    // ---- layer 2 (K=64, CHH=128, MFMA fused Wl|Wr per head) ----
    for (int h = 0; h < 3; ++h) {
        hipLaunchKernelGGL((mfma_gemm<64, 128>), dim3(2, 391), dim3(256), 0, stream,
                           h1u, BpL2, BpR2, bl2 + h * 128, br2 + h * 128,
                           XLb, XRb, N_NODES, 384, h * 128);
        if (h == 0)      hipLaunchKernelGGL((gat_head<128, 0>), AGG_GRID, dim3(256), 0, stream,
                             XLu, XRu, 128, 0, att2 + h * 128, b2, offsets, srcs, h2u, N_NODES);
        else if (h == 1) hipLaunchKernelGGL((gat_head<128, 1>), AGG_GRID, dim3(256), 0, stream,
                             XLu, XRu, 128, 0, att2 + h * 128, b2, offsets, srcs, h2u, N_NODES);
        else             hipLaunchKernelGGL((gat_head<128, 2>), AGG_GRID, dim3(256), 0, stream,
                             XLu, XRu, 128, 0, att2 + h * 128, b2, offsets, srcs, h2u, N_NODES);
    }

    // ---- layer 3 (K=128, CHH=256, MFMA fused Wl|Wr per head) ----
    for (int h = 0; h < 3; ++h) {
        hipLaunchKernelGGL((mfma_gemm<128, 256>), dim3(4, 391), dim3(256), 0, stream,
                           h2u, BpL3, BpR3, bl3 + h * 256, br3 + h * 256,
                           XLb, XRb, N_NODES, 768, h * 256);
        if (h == 0)      hipLaunchKernelGGL((gat_head<256, 0>), AGG_GRID, dim3(256), 0, stream,
                             XLu, XRu, 256, 0, att3 + h * 256, b3, offsets, srcs, h3u, N_NODES);
        else if (h == 1) hipLaunchKernelGGL((gat_head<256, 1>), AGG_GRID, dim3(256), 0, stream,
                             XLu, XRu, 256, 0, att3 + h * 256, b3, offsets, srcs, h3u, N_NODES);
        else             hipLaunchKernelGGL((gat_head<256, 2>), AGG_GRID, dim3(256), 0, stream,
                             XLu, XRu, 256, 0, att3 + h * 256, b3, offsets, srcs, h3u, N_NODES);
    }

    // ---- pool (no atomics; batch sorted) ----
    hipLaunchKernelGGL(pool_kernel, dim3(NUM_GRAPHS), dim3(256), 0, stream, h3u, batch, G);

    // ---- VAE heads + decoder (fp32 SIMT) ----
    hipLaunchKernelGGL((gemm_bias<false, float, float>), dim3(1, 32), dim3(256), 0, stream,
                       G, Wmu, bmu, out + MU_OFF, NUM_GRAPHS, 64, 256, 256, 64, 64);
    hipLaunchKernelGGL((gemm_bias<false, float, float>), dim3(1, 32), dim3(256), 0, stream,
                       G, Wlv, blv, out + LV_OFF, NUM_GRAPHS, 64, 256, 256, 64, 64);
    hipLaunchKernelGGL((gemm_bias<true, float, float>), dim3(4, 32), dim3(256), 0, stream,
                       out + MU_OFF, Wd1, bd1, O1, NUM_GRAPHS, 256, 64, 64, 256, 256);
    hipLaunchKernelGGL((gemm_bias<true, float, float>), dim3(8, 32), dim3(256), 0, stream,
                       O1, Wd2, bd2, O2, NUM_GRAPHS, 512, 256, 256, 512, 512);
    hipLaunchKernelGGL((gemm_bias<false, float, float>), dim3(19, 32), dim3(256), 0, stream,
                       O2, Wd3, bd3, O3, NUM_GRAPHS, 1160, 512, 512, 1160, 1160);
    hipLaunchKernelGGL(assemble_kernel, dim3(NUM_GRAPHS), dim3(256), 0, stream, O3, out);
}

// Round 4
// 1196.159 us; speedup vs baseline: 1.8411x; 1.1873x over previous
//
#include <hip/hip_runtime.h>
#include <hip/hip_bf16.h>

typedef __hip_bfloat16 bf16;
typedef unsigned short ushortT;
typedef ushortT u16x2 __attribute__((ext_vector_type(2)));
typedef ushortT u16x4 __attribute__((ext_vector_type(4)));
typedef ushortT u16x8 __attribute__((ext_vector_type(8)));
typedef __bf16   bf16x8 __attribute__((ext_vector_type(8)));
typedef float    f32x4  __attribute__((ext_vector_type(4)));

#define N_NODES    50000
#define E_EDGES    400000
#define E_TOT      450000
#define NUM_GRAPHS 2048

// ---------- helpers ----------
__device__ __forceinline__ float fromb(ushortT u) {
    unsigned int i = ((unsigned int)u) << 16;
    return __builtin_bit_cast(float, i);
}
__device__ __forceinline__ ushortT tob(float v) {
    bf16 h = __float2bfloat16(v);
    return __builtin_bit_cast(ushortT, h);
}

template <int VEC> struct RawV;
template <> struct RawV<1> { using T = ushortT; };
template <> struct RawV<2> { using T = u16x2; };
template <> struct RawV<4> { using T = u16x4; };

__device__ __forceinline__ void cvtv(ushortT r, float* f) { f[0] = fromb(r); }
__device__ __forceinline__ void cvtv(u16x2 r, float* f)   { f[0] = fromb(r.x); f[1] = fromb(r.y); }
__device__ __forceinline__ void cvtv(u16x4 r, float* f)   { f[0] = fromb(r.x); f[1] = fromb(r.y);
                                                            f[2] = fromb(r.z); f[3] = fromb(r.w); }

// ---------- diagnostic ----------
__global__ void diag_kernel(float* out, float v) { if (threadIdx.x == 0) out[0] = v; }

// ---------- CSR build ----------
__global__ void hist_kernel(const int* __restrict__ ei, int* __restrict__ counts) {
    int e = blockIdx.x * 256 + threadIdx.x;
    if (e >= E_TOT) return;
    int d = (e < E_EDGES) ? ei[E_EDGES + e] : (e - E_EDGES);
    atomicAdd(&counts[d], 1);
}

__global__ void scan_kernel(const int* __restrict__ counts, int* __restrict__ offsets) {
    __shared__ int sh[1024];
    const int N = N_NODES;
    const int CH = (N + 1023) / 1024;
    int t = threadIdx.x;
    int base = t * CH;
    int lsum = 0;
    for (int i = 0; i < CH; i++) {
        int idx = base + i;
        if (idx < N) lsum += counts[idx];
    }
    sh[t] = lsum;
    __syncthreads();
    for (int d = 1; d < 1024; d <<= 1) {
        int v = (t >= d) ? sh[t - d] : 0;
        __syncthreads();
        sh[t] += v;
        __syncthreads();
    }
    int run = sh[t] - lsum;
    for (int i = 0; i < CH; i++) {
        int idx = base + i;
        if (idx < N) { offsets[idx] = run; run += counts[idx]; }
    }
    if (t == 0) offsets[N] = E_TOT;
}

__global__ void copy_kernel(const int* __restrict__ src, int* __restrict__ dst, int n) {
    int i = blockIdx.x * 256 + threadIdx.x;
    if (i < n) dst[i] = src[i];
}

__global__ void scatter_kernel(const int* __restrict__ ei, int* __restrict__ cursor,
                               int* __restrict__ srcs) {
    int e = blockIdx.x * 256 + threadIdx.x;
    if (e >= E_TOT) return;
    int s, d;
    if (e < E_EDGES) { s = ei[e]; d = ei[E_EDGES + e]; }
    else             { s = d = e - E_EDGES; }
    int pos = atomicAdd(&cursor[d], 1);
    srcs[pos] = s;
}

// ---------- weight repack: W fp32 [K,N] -> Bp bf16 [(k>>3)*N + n]*8 + (k&7) ----------
__global__ void repack_kernel(const float* __restrict__ W, ushortT* __restrict__ Bp,
                              int K, int N) {
    int idx = blockIdx.x * 256 + threadIdx.x;
    if (idx >= K * N) return;
    int k = idx / N, n = idx % N;
    Bp[((size_t)(k >> 3) * N + n) * 8 + (k & 7)] = tob(W[idx]);
}

// ---------- layer-1 fused transform: XL = x@Wl1+bl1, XR = x@Wr1+br1 (K=11, N=192) ----
// 192 threads/block; thread owns col c=tid; block covers 64 rows; W cols in registers.
__global__ __launch_bounds__(192) void l1_transform(const float* __restrict__ x,
                                                    const float* __restrict__ Wl,
                                                    const float* __restrict__ bl,
                                                    const float* __restrict__ Wr,
                                                    const float* __restrict__ br,
                                                    ushortT* __restrict__ XL,
                                                    ushortT* __restrict__ XR, int M) {
    __shared__ float xs[64][11];
    const int tid = threadIdx.x;
    const int bm  = blockIdx.x * 64;
    const int rows = (M - bm < 64) ? (M - bm) : 64;

    float wl[11], wr[11];
    #pragma unroll
    for (int k = 0; k < 11; k++) {
        wl[k] = Wl[k * 192 + tid];
        wr[k] = Wr[k * 192 + tid];
    }
    float blc = bl[tid], brc = br[tid];

    for (int i = tid; i < rows * 11; i += 192)
        xs[i / 11][i % 11] = x[(size_t)bm * 11 + i];
    __syncthreads();

    for (int r = 0; r < rows; r++) {
        float al = blc, ar = brc;
        #pragma unroll
        for (int k = 0; k < 11; k++) {
            float xv = xs[r][k];
            al += xv * wl[k];
            ar += xv * wr[k];
        }
        size_t o = (size_t)(bm + r) * 192 + tid;
        XL[o] = tob(al);
        XR[o] = tob(ar);
    }
}

// ---------- decoder fp32 GEMM, 32x64 tile (grid-rich for small M) ----------
template <bool RELU>
__global__ __launch_bounds__(256) void gemm_dec(const float* __restrict__ A,
                                                const float* __restrict__ B,
                                                const float* __restrict__ bias,
                                                float* __restrict__ C,
                                                int M, int N, int K,
                                                int lda, int ldb, int ldc) {
    __shared__ float As[32][33];
    __shared__ float Bs[32][65];
    int tid = threadIdx.x;
    int tm = tid >> 4, tn = tid & 15;
    int bm = blockIdx.y * 32, bn = blockIdx.x * 64;
    float acc[2][4] = {};
    for (int k0 = 0; k0 < K; k0 += 32) {
        #pragma unroll
        for (int i = 0; i < 4; i++) {
            int e = tid + i * 256;
            int r = e >> 5, k = e & 31;
            int row = bm + r, kk = k0 + k;
            float v = 0.f;
            if (row < M && kk < K) v = A[(size_t)row * lda + kk];
            As[k][r] = v;
        }
        #pragma unroll
        for (int i = 0; i < 8; i++) {
            int e = tid + i * 256;
            int k = e >> 6, n = e & 63;
            int kk = k0 + k, col = bn + n;
            float v = 0.f;
            if (kk < K && col < N) v = B[(size_t)kk * ldb + col];
            Bs[k][n] = v;
        }
        __syncthreads();
        #pragma unroll
        for (int k = 0; k < 32; k++) {
            float a0 = As[k][tm * 2 + 0], a1 = As[k][tm * 2 + 1];
            float b0 = Bs[k][tn * 4 + 0], b1 = Bs[k][tn * 4 + 1];
            float b2 = Bs[k][tn * 4 + 2], b3 = Bs[k][tn * 4 + 3];
            acc[0][0] += a0 * b0; acc[0][1] += a0 * b1; acc[0][2] += a0 * b2; acc[0][3] += a0 * b3;
            acc[1][0] += a1 * b0; acc[1][1] += a1 * b1; acc[1][2] += a1 * b2; acc[1][3] += a1 * b3;
        }
        __syncthreads();
    }
    #pragma unroll
    for (int i = 0; i < 2; i++) {
        int row = bm + tm * 2 + i;
        if (row >= M) continue;
        #pragma unroll
        for (int j = 0; j < 4; j++) {
            int col = bn + tn * 4 + j;
            if (col >= N) continue;
            float v = acc[i][j] + bias[col];
            if (RELU) v = fmaxf(v, 0.f);
            C[(size_t)row * ldc + col] = v;
        }
    }
}

// ---------- MFMA bf16 GEMM for node transforms ----------
template <int K, int CHH>
__global__ __launch_bounds__(256) void mfma_gemm(const ushortT* __restrict__ A,
                                                 const ushortT* __restrict__ BpL,
                                                 const ushortT* __restrict__ BpR,
                                                 const float* __restrict__ bl,
                                                 const float* __restrict__ br,
                                                 bf16* __restrict__ XL,
                                                 bf16* __restrict__ XR,
                                                 int M, int Nfull, int n0) {
    constexpr int KU = K / 8;
    __shared__ ushortT Alds[KU * 128 * 8];
    const int tid = threadIdx.x;
    const int bm  = blockIdx.y * 128;
    const int bnb = blockIdx.x * 128;

    for (int u = tid; u < 128 * KU; u += 256) {
        int row = u / KU, kg = u % KU;
        int rg = bm + row; if (rg > M - 1) rg = M - 1;
        u16x8 v = *reinterpret_cast<const u16x8*>(A + (size_t)rg * K + kg * 8);
        int unit = (kg * 128 + row) ^ (kg & 7);
        *reinterpret_cast<u16x8*>(&Alds[unit * 8]) = v;
    }
    __syncthreads();

    const int lane = tid & 63;
    const int l15 = lane & 15, lg = lane >> 4;
    const int wid = tid >> 6;
    const int wm = wid >> 1, wn = wid & 1;

    f32x4 acc[4][4] = {};
    #pragma unroll
    for (int s = 0; s < K / 32; s++) {
        int kg = s * 4 + lg;
        bf16x8 a[4], b[4];
        #pragma unroll
        for (int mf = 0; mf < 4; mf++) {
            int row = wm * 64 + mf * 16 + l15;
            int unit = (kg * 128 + row) ^ (kg & 7);
            a[mf] = __builtin_bit_cast(bf16x8,
                    *reinterpret_cast<const u16x8*>(&Alds[unit * 8]));
        }
        #pragma unroll
        for (int nf = 0; nf < 4; nf++) {
            int cb = bnb + wn * 64 + nf * 16;
            const ushortT* bp; int n;
            if (cb < CHH) { bp = BpL; n = n0 + cb + l15; }
            else          { bp = BpR; n = n0 + cb - CHH + l15; }
            b[nf] = __builtin_bit_cast(bf16x8,
                    *reinterpret_cast<const u16x8*>(bp + ((size_t)kg * Nfull + n) * 8));
        }
        #pragma unroll
        for (int mf = 0; mf < 4; mf++)
            #pragma unroll
            for (int nf = 0; nf < 4; nf++)
                acc[mf][nf] = __builtin_amdgcn_mfma_f32_16x16x32_bf16(
                    a[mf], b[nf], acc[mf][nf], 0, 0, 0);
    }

    #pragma unroll
    for (int nf = 0; nf < 4; nf++) {
        int cb = bnb + wn * 64 + nf * 16;
        bf16* Cp; const float* bs; int c;
        if (cb < CHH) { Cp = XL; bs = bl; c = cb + l15; }
        else          { Cp = XR; bs = br; c = cb - CHH + l15; }
        float bv = bs[c];
        #pragma unroll
        for (int mf = 0; mf < 4; mf++) {
            #pragma unroll
            for (int q = 0; q < 4; q++) {
                int r = bm + wm * 64 + mf * 16 + lg * 4 + q;
                if (r < M) Cp[(size_t)r * CHH + c] = __float2bfloat16(acc[mf][nf][q] + bv);
            }
        }
    }
}

// ---------- GATv2 aggregation per head: wave/node, online softmax ----------
// srcs preloaded into a register and __shfl'd -> no per-edge address-load latency;
// 2-deep gather pipeline.
template <int CHH, int MODE>
__global__ __launch_bounds__(256) void gat_head(const ushortT* __restrict__ XL,
                                                const ushortT* __restrict__ XR,
                                                int ldx, int offx,
                                                const float* __restrict__ att_h,
                                                const float* __restrict__ bias,
                                                const int* __restrict__ offsets,
                                                const int* __restrict__ srcs,
                                                ushortT* __restrict__ OUT, int N) {
    constexpr int VEC = CHH / 64;
    using RT = typename RawV<VEC>::T;
    int wid  = threadIdx.x >> 6;
    int lane = threadIdx.x & 63;
    int n = blockIdx.x * 4 + wid;
    if (n >= N) return;

    float xr_[VEC], att_[VEC], acc[VEC];
    const ushortT* xrp = XR + (size_t)n * ldx + offx + VEC * lane;
    #pragma unroll
    for (int i = 0; i < VEC; i++) {
        xr_[i]  = fromb(xrp[i]);
        att_[i] = att_h[VEC * lane + i];
        acc[i]  = 0.f;
    }
    float m = -3.0e38f, denom = 0.f;

    const int e0 = offsets[n], e1 = offsets[n + 1];
    const int deg = e1 - e0;
    const int loff = offx + VEC * lane;

    for (int base = 0; base < deg; base += 64) {
        int cnt = deg - base; if (cnt > 64) cnt = 64;
        int sl = srcs[e0 + base + ((lane < cnt) ? lane : (cnt - 1))];

        RT pf0, pf1;
        pf0 = *reinterpret_cast<const RT*>(XL + (size_t)__shfl(sl, 0) * ldx + loff);
        if (cnt > 1)
            pf1 = *reinterpret_cast<const RT*>(XL + (size_t)__shfl(sl, 1) * ldx + loff);

        for (int j = 0; j < cnt; ++j) {
            RT cur = pf0;
            pf0 = pf1;
            if (j + 2 < cnt)
                pf1 = *reinterpret_cast<const RT*>(XL + (size_t)__shfl(sl, j + 2) * ldx + loff);

            float xl[VEC];
            cvtv(cur, xl);
            float part = 0.f;
            #pragma unroll
            for (int i = 0; i < VEC; i++) {
                float v = xl[i] + xr_[i];
                v = (v > 0.f) ? v : 0.2f * v;       // leaky_relu(0.2)
                part += att_[i] * v;
            }
            #pragma unroll
            for (int ofs = 32; ofs > 0; ofs >>= 1)
                part += __shfl_xor(part, ofs);

            float mn = fmaxf(m, part);
            float sc = __expf(m - mn);
            float w  = __expf(part - mn);
            denom = denom * sc + w;
            m = mn;
            #pragma unroll
            for (int i = 0; i < VEC; i++) acc[i] = acc[i] * sc + w * xl[i];
        }
    }

    float inv = 1.f / (denom + 1e-16f);
    #pragma unroll
    for (int i = 0; i < VEC; i++) {
        int c = VEC * lane + i;
        size_t idx = (size_t)n * CHH + c;
        float v = acc[i] * inv;
        if (MODE > 0) v += fromb(OUT[idx]);
        if (MODE == 2) { v = v * (1.f / 3.f) + bias[c]; v = fmaxf(v, 0.f); }
        OUT[idx] = tob(v);
    }
}

// ---------- pool: block per graph, binary search on sorted batch ----------
__global__ void pool_kernel(const ushortT* __restrict__ h3, const int* __restrict__ batch,
                            float* __restrict__ G) {
    int g = blockIdx.x;
    int c = threadIdx.x;
    int lo = 0, hi = N_NODES;
    while (lo < hi) { int mid = (lo + hi) >> 1; if (batch[mid] < g) lo = mid + 1; else hi = mid; }
    int s0 = lo;
    hi = N_NODES;
    while (lo < hi) { int mid = (lo + hi) >> 1; if (batch[mid] < g + 1) lo = mid + 1; else hi = mid; }
    int s1 = lo;
    float sum = 0.f;
    for (int n = s0; n < s1; n++) sum += fromb(h3[(size_t)n * 256 + c]);
    G[(size_t)g * 256 + c] = sum;
}

// ---------- output assembly ----------
__global__ void assemble_kernel(const float* __restrict__ o3, float* __restrict__ out) {
    int g = blockIdx.x;
    const float* row = o3 + (size_t)g * 1160;
    float* xrec = out + (size_t)g * 319;
    for (int p = threadIdx.x; p < 319; p += 256) xrec[p] = row[p];
    float* adj = out + 653312 + (size_t)g * 841;
    for (int p = threadIdx.x; p < 841; p += 256) {
        int i = p / 29, j = p % 29;
        adj[p] = 0.5f * (row[319 + p] + row[319 + j * 29 + i]);
    }
}

// ---------- launch ----------
extern "C" void kernel_launch(void* const* d_in, const int* in_sizes, int n_in,
                              void* d_out, int out_size, void* d_ws, size_t ws_size,
                              hipStream_t stream) {
    const float* x     = (const float*)d_in[0];
    const int*   ei    = (const int*)d_in[1];
    const int*   batch = (const int*)d_in[2];
    const float* Wl1 = (const float*)d_in[3];
    const float* bl1 = (const float*)d_in[4];
    const float* Wr1 = (const float*)d_in[5];
    const float* br1 = (const float*)d_in[6];
    const float* att1= (const float*)d_in[7];
    const float* b1  = (const float*)d_in[8];
    const float* Wl2 = (const float*)d_in[9];
    const float* bl2 = (const float*)d_in[10];
    const float* Wr2 = (const float*)d_in[11];
    const float* br2 = (const float*)d_in[12];
    const float* att2= (const float*)d_in[13];
    const float* b2  = (const float*)d_in[14];
    const float* Wl3 = (const float*)d_in[15];
    const float* bl3 = (const float*)d_in[16];
    const float* Wr3 = (const float*)d_in[17];
    const float* br3 = (const float*)d_in[18];
    const float* att3= (const float*)d_in[19];
    const float* b3  = (const float*)d_in[20];
    const float* Wmu = (const float*)d_in[21];
    const float* bmu = (const float*)d_in[22];
    const float* Wlv = (const float*)d_in[23];
    const float* blv = (const float*)d_in[24];
    const float* Wd1 = (const float*)d_in[25];
    const float* bd1 = (const float*)d_in[26];
    const float* Wd2 = (const float*)d_in[27];
    const float* bd2 = (const float*)d_in[28];
    const float* Wd3 = (const float*)d_in[29];
    const float* bd3 = (const float*)d_in[30];
    float* out = (float*)d_out;

    // ---- workspace layout (bytes) ----
    char* wsb = (char*)d_ws;
    ushortT* h3u = (ushortT*)(wsb + 0);         // 50000x256 (aliases h1)
    ushortT* h1u = (ushortT*)(wsb + 0);         // 50000x64
    ushortT* h2u = (ushortT*)(wsb + 25600000);  // 50000x128
    bf16*    XLb = (bf16*)(wsb + 38400000);
    ushortT* XLu = (ushortT*)(wsb + 38400000);
    bf16*    XRb = (bf16*)(wsb + 64000000);
    ushortT* XRu = (ushortT*)(wsb + 64000000);
    float* G  = (float*)(wsb + 38400000);       // decoder scratch aliases XL/XR
    float* O1 = G  + 524288;
    float* O2 = O1 + 524288;
    float* O3 = O2 + 1048576;
    int* counts  = (int*)(wsb + 89600000);
    int* offsets = counts + (N_NODES + 1);
    int* cursor  = offsets + (N_NODES + 1);
    int* srcs    = cursor + (N_NODES + 1);
    ushortT* BpL2 = (ushortT*)(wsb + 92000016);
    ushortT* BpR2 = (ushortT*)(wsb + 92049168);
    ushortT* BpL3 = (ushortT*)(wsb + 92098320);
    ushortT* BpR3 = (ushortT*)(wsb + 92294928);

    size_t needed = 92491536;
    if (ws_size < needed) {
        hipLaunchKernelGGL(diag_kernel, dim3(1), dim3(64), 0, stream, out, (float)(ws_size >> 20));
        return;
    }

    const int MU_OFF = 2375680;
    const int LV_OFF = 2506752;

    // ---- CSR build ----
    hipMemsetAsync(counts, 0, sizeof(int) * (N_NODES + 1), stream);
    hipLaunchKernelGGL(hist_kernel, dim3((E_TOT + 255) / 256), dim3(256), 0, stream, ei, counts);
    hipLaunchKernelGGL(scan_kernel, dim3(1), dim3(1024), 0, stream, counts, offsets);
    hipLaunchKernelGGL(copy_kernel, dim3((N_NODES + 255) / 256), dim3(256), 0, stream,
                       offsets, cursor, N_NODES);
    hipLaunchKernelGGL(scatter_kernel, dim3((E_TOT + 255) / 256), dim3(256), 0, stream,
                       ei, cursor, srcs);

    // ---- weight repack ----
    hipLaunchKernelGGL(repack_kernel, dim3((64 * 384 + 255) / 256), dim3(256), 0, stream,
                       Wl2, BpL2, 64, 384);
    hipLaunchKernelGGL(repack_kernel, dim3((64 * 384 + 255) / 256), dim3(256), 0, stream,
                       Wr2, BpR2, 64, 384);
    hipLaunchKernelGGL(repack_kernel, dim3((128 * 768 + 255) / 256), dim3(256), 0, stream,
                       Wl3, BpL3, 128, 768);
    hipLaunchKernelGGL(repack_kernel, dim3((128 * 768 + 255) / 256), dim3(256), 0, stream,
                       Wr3, BpR3, 128, 768);

    const dim3 AGG_GRID(N_NODES / 4);

    // ---- layer 1 (fused small-K transform) ----
    hipLaunchKernelGGL(l1_transform, dim3((N_NODES + 63) / 64), dim3(192), 0, stream,
                       x, Wl1, bl1, Wr1, br1, XLu, XRu, N_NODES);
    hipLaunchKernelGGL((gat_head<64, 0>), AGG_GRID, dim3(256), 0, stream,
                       XLu, XRu, 192, 0,   att1 + 0,   b1, offsets, srcs, h1u, N_NODES);
    hipLaunchKernelGGL((gat_head<64, 1>), AGG_GRID, dim3(256), 0, stream,
                       XLu, XRu, 192, 64,  att1 + 64,  b1, offsets, srcs, h1u, N_NODES);
    hipLaunchKernelGGL((gat_head<64, 2>), AGG_GRID, dim3(256), 0, stream,
                       XLu, XRu, 192, 128, att1 + 128, b1, offsets, srcs, h1u, N_NODES);

    // ---- layer 2 (K=64, CHH=128, MFMA fused Wl|Wr per head) ----
    for (int h = 0; h < 3; ++h) {
        hipLaunchKernelGGL((mfma_gemm<64, 128>), dim3(2, 391), dim3(256), 0, stream,
                           h1u, BpL2, BpR2, bl2 + h * 128, br2 + h * 128,
                           XLb, XRb, N_NODES, 384, h * 128);
        if (h == 0)      hipLaunchKernelGGL((gat_head<128, 0>), AGG_GRID, dim3(256), 0, stream,
                             XLu, XRu, 128, 0, att2 + h * 128, b2, offsets, srcs, h2u, N_NODES);
        else if (h == 1) hipLaunchKernelGGL((gat_head<128, 1>), AGG_GRID, dim3(256), 0, stream,
                             XLu, XRu, 128, 0, att2 + h * 128, b2, offsets, srcs, h2u, N_NODES);
        else             hipLaunchKernelGGL((gat_head<128, 2>), AGG_GRID, dim3(256), 0, stream,
                             XLu, XRu, 128, 0, att2 + h * 128, b2, offsets, srcs, h2u, N_NODES);
    }

    // ---- layer 3 (K=128, CHH=256, MFMA fused Wl|Wr per head) ----
    for (int h = 0; h < 3; ++h) {
        hipLaunchKernelGGL((mfma_gemm<128, 256>), dim3(4, 391), dim3(256), 0, stream,
                           h2u, BpL3, BpR3, bl3 + h * 256, br3 + h * 256,
                           XLb, XRb, N_NODES, 768, h * 256);
        if (h == 0)      hipLaunchKernelGGL((gat_head<256, 0>), AGG_GRID, dim3(256), 0, stream,
                             XLu, XRu, 256, 0, att3 + h * 256, b3, offsets, srcs, h3u, N_NODES);
        else if (h == 1) hipLaunchKernelGGL((gat_head<256, 1>), AGG_GRID, dim3(256), 0, stream,
                             XLu, XRu, 256, 0, att3 + h * 256, b3, offsets, srcs, h3u, N_NODES);
        else             hipLaunchKernelGGL((gat_head<256, 2>), AGG_GRID, dim3(256), 0, stream,
                             XLu, XRu, 256, 0, att3 + h * 256, b3, offsets, srcs, h3u, N_NODES);
    }

    // ---- pool ----
    hipLaunchKernelGGL(pool_kernel, dim3(NUM_GRAPHS), dim3(256), 0, stream, h3u, batch, G);

    // ---- VAE heads + decoder (fp32, 32x64-tile GEMM) ----
    hipLaunchKernelGGL((gemm_dec<false>), dim3(1, 64), dim3(256), 0, stream,
                       G, Wmu, bmu, out + MU_OFF, NUM_GRAPHS, 64, 256, 256, 64, 64);
    hipLaunchKernelGGL((gemm_dec<false>), dim3(1, 64), dim3(256), 0, stream,
                       G, Wlv, blv, out + LV_OFF, NUM_GRAPHS, 64, 256, 256, 64, 64);
    hipLaunchKernelGGL((gemm_dec<true>), dim3(4, 64), dim3(256), 0, stream,
                       out + MU_OFF, Wd1, bd1, O1, NUM_GRAPHS, 256, 64, 64, 256, 256);
    hipLaunchKernelGGL((gemm_dec<true>), dim3(8, 64), dim3(256), 0, stream,
                       O1, Wd2, bd2, O2, NUM_GRAPHS, 512, 256, 256, 512, 512);
    hipLaunchKernelGGL((gemm_dec<false>), dim3(19, 64), dim3(256), 0, stream,
                       O2, Wd3, bd3, O3, NUM_GRAPHS, 1160, 512, 512, 1160, 1160);
    hipLaunchKernelGGL(assemble_kernel, dim3(NUM_GRAPHS), dim3(256), 0, stream, O3, out);
}

// Round 6
// 1123.455 us; speedup vs baseline: 1.9603x; 1.0647x over previous
//
#include <hip/hip_runtime.h>
#include <hip/hip_bf16.h>

typedef __hip_bfloat16 bf16;
typedef unsigned short ushortT;
typedef ushortT u16x2 __attribute__((ext_vector_type(2)));
typedef ushortT u16x4 __attribute__((ext_vector_type(4)));
typedef ushortT u16x8 __attribute__((ext_vector_type(8)));
typedef __bf16   bf16x8 __attribute__((ext_vector_type(8)));
typedef float    f32x4  __attribute__((ext_vector_type(4)));

#define N_NODES    50000
#define E_EDGES    400000
#define E_TOT      450000
#define NUM_GRAPHS 2048

// ---------- helpers ----------
__device__ __forceinline__ float fromb(ushortT u) {
    unsigned int i = ((unsigned int)u) << 16;
    return __builtin_bit_cast(float, i);
}
__device__ __forceinline__ ushortT tob(float v) {
    bf16 h = __float2bfloat16(v);
    return __builtin_bit_cast(ushortT, h);
}

template <int VEC> struct RawV;
template <> struct RawV<1> { using T = ushortT; };
template <> struct RawV<2> { using T = u16x2; };
template <> struct RawV<4> { using T = u16x4; };

__device__ __forceinline__ void cvtv(ushortT r, float* f) { f[0] = fromb(r); }
__device__ __forceinline__ void cvtv(u16x2 r, float* f)   { f[0] = fromb(r.x); f[1] = fromb(r.y); }
__device__ __forceinline__ void cvtv(u16x4 r, float* f)   { f[0] = fromb(r.x); f[1] = fromb(r.y);
                                                            f[2] = fromb(r.z); f[3] = fromb(r.w); }

// ---------- diagnostic ----------
__global__ void diag_kernel(float* out, float v) { if (threadIdx.x == 0) out[0] = v; }

// ---------- CSR build ----------
__global__ void hist_kernel(const int* __restrict__ ei, int* __restrict__ counts) {
    int e = blockIdx.x * 256 + threadIdx.x;
    if (e >= E_TOT) return;
    int d = (e < E_EDGES) ? ei[E_EDGES + e] : (e - E_EDGES);
    atomicAdd(&counts[d], 1);
}

__global__ void scan_kernel(const int* __restrict__ counts, int* __restrict__ offsets) {
    __shared__ int sh[1024];
    const int N = N_NODES;
    const int CH = (N + 1023) / 1024;
    int t = threadIdx.x;
    int base = t * CH;
    int lsum = 0;
    for (int i = 0; i < CH; i++) {
        int idx = base + i;
        if (idx < N) lsum += counts[idx];
    }
    sh[t] = lsum;
    __syncthreads();
    for (int d = 1; d < 1024; d <<= 1) {
        int v = (t >= d) ? sh[t - d] : 0;
        __syncthreads();
        sh[t] += v;
        __syncthreads();
    }
    int run = sh[t] - lsum;
    for (int i = 0; i < CH; i++) {
        int idx = base + i;
        if (idx < N) { offsets[idx] = run; run += counts[idx]; }
    }
    if (t == 0) offsets[N] = E_TOT;
}

__global__ void copy_kernel(const int* __restrict__ src, int* __restrict__ dst, int n) {
    int i = blockIdx.x * 256 + threadIdx.x;
    if (i < n) dst[i] = src[i];
}

__global__ void scatter_kernel(const int* __restrict__ ei, int* __restrict__ cursor,
                               int* __restrict__ srcs) {
    int e = blockIdx.x * 256 + threadIdx.x;
    if (e >= E_TOT) return;
    int s, d;
    if (e < E_EDGES) { s = ei[e]; d = ei[E_EDGES + e]; }
    else             { s = d = e - E_EDGES; }
    int pos = atomicAdd(&cursor[d], 1);
    srcs[pos] = s;
}

// ---------- weight repack (bf16): W fp32 [K,N] -> Bp [(k>>3)*N + n]*8 + (k&7) ----------
__global__ void repack_kernel(const float* __restrict__ W, ushortT* __restrict__ Bp,
                              int K, int N) {
    int idx = blockIdx.x * 256 + threadIdx.x;
    if (idx >= K * N) return;
    int k = idx / N, n = idx % N;
    Bp[((size_t)(k >> 3) * N + n) * 8 + (k & 7)] = tob(W[idx]);
}

// ---------- weight repack split hi/lo (for fp32-accurate MFMA decoder) ----------
__global__ void repack_split(const float* __restrict__ W, ushortT* __restrict__ Bh,
                             ushortT* __restrict__ Bl, int K, int N, int Npad) {
    int idx = blockIdx.x * 256 + threadIdx.x;
    if (idx >= K * Npad) return;
    int k = idx / Npad, n = idx % Npad;
    float v = (n < N) ? W[(size_t)k * N + n] : 0.f;
    ushortT h = tob(v);
    float r = v - fromb(h);
    size_t o = ((size_t)(k >> 3) * Npad + n) * 8 + (k & 7);
    Bh[o] = h;
    Bl[o] = tob(r);
}

// ---------- layer-1 fused transform (K=11, N=192) ----------
__global__ __launch_bounds__(192) void l1_transform(const float* __restrict__ x,
                                                    const float* __restrict__ Wl,
                                                    const float* __restrict__ bl,
                                                    const float* __restrict__ Wr,
                                                    const float* __restrict__ br,
                                                    ushortT* __restrict__ XL,
                                                    ushortT* __restrict__ XR, int M) {
    __shared__ float xs[64][11];
    const int tid = threadIdx.x;
    const int bm  = blockIdx.x * 64;
    const int rows = (M - bm < 64) ? (M - bm) : 64;

    float wl[11], wr[11];
    #pragma unroll
    for (int k = 0; k < 11; k++) {
        wl[k] = Wl[k * 192 + tid];
        wr[k] = Wr[k * 192 + tid];
    }
    float blc = bl[tid], brc = br[tid];

    for (int i = tid; i < rows * 11; i += 192)
        xs[i / 11][i % 11] = x[(size_t)bm * 11 + i];
    __syncthreads();

    for (int r = 0; r < rows; r++) {
        float al = blc, ar = brc;
        #pragma unroll
        for (int k = 0; k < 11; k++) {
            float xv = xs[r][k];
            al += xv * wl[k];
            ar += xv * wr[k];
        }
        size_t o = (size_t)(bm + r) * 192 + tid;
        XL[o] = tob(al);
        XR[o] = tob(ar);
    }
}

// ---------- small fp32 SIMT GEMM (mu / logvar heads) ----------
template <bool RELU>
__global__ __launch_bounds__(256) void gemm_dec(const float* __restrict__ A,
                                                const float* __restrict__ B,
                                                const float* __restrict__ bias,
                                                float* __restrict__ C,
                                                int M, int N, int K,
                                                int lda, int ldb, int ldc) {
    __shared__ float As[32][33];
    __shared__ float Bs[32][65];
    int tid = threadIdx.x;
    int tm = tid >> 4, tn = tid & 15;
    int bm = blockIdx.y * 32, bn = blockIdx.x * 64;
    float acc[2][4] = {};
    for (int k0 = 0; k0 < K; k0 += 32) {
        #pragma unroll
        for (int i = 0; i < 4; i++) {
            int e = tid + i * 256;
            int r = e >> 5, k = e & 31;
            int row = bm + r, kk = k0 + k;
            float v = 0.f;
            if (row < M && kk < K) v = A[(size_t)row * lda + kk];
            As[k][r] = v;
        }
        #pragma unroll
        for (int i = 0; i < 8; i++) {
            int e = tid + i * 256;
            int k = e >> 6, n = e & 63;
            int kk = k0 + k, col = bn + n;
            float v = 0.f;
            if (kk < K && col < N) v = B[(size_t)kk * ldb + col];
            Bs[k][n] = v;
        }
        __syncthreads();
        #pragma unroll
        for (int k = 0; k < 32; k++) {
            float a0 = As[k][tm * 2 + 0], a1 = As[k][tm * 2 + 1];
            float b0 = Bs[k][tn * 4 + 0], b1 = Bs[k][tn * 4 + 1];
            float b2 = Bs[k][tn * 4 + 2], b3 = Bs[k][tn * 4 + 3];
            acc[0][0] += a0 * b0; acc[0][1] += a0 * b1; acc[0][2] += a0 * b2; acc[0][3] += a0 * b3;
            acc[1][0] += a1 * b0; acc[1][1] += a1 * b1; acc[1][2] += a1 * b2; acc[1][3] += a1 * b3;
        }
        __syncthreads();
    }
    #pragma unroll
    for (int i = 0; i < 2; i++) {
        int row = bm + tm * 2 + i;
        if (row >= M) continue;
        #pragma unroll
        for (int j = 0; j < 4; j++) {
            int col = bn + tn * 4 + j;
            if (col >= N) continue;
            float v = acc[i][j] + bias[col];
            if (RELU) v = fmaxf(v, 0.f);
            C[(size_t)row * ldc + col] = v;
        }
    }
}

// ---------- split-bf16 MFMA decoder GEMM: fp32-accurate via Ah*Bh + Ah*Bl + Al*Bh ----
// A fp32 [M,K] lda; Bh/Bl packed [(k>>3)*Npad+n]*8+(k&7); C fp32 [M,N] ldc.
// Tile 128x128, 4 waves 2x2. Requires M % 128 == 0, K % 32 == 0, gridX = Npad/128.
template <bool RELU>
__global__ __launch_bounds__(256) void mfma_dec(const float* __restrict__ A,
                                                const ushortT* __restrict__ Bh,
                                                const ushortT* __restrict__ Bl,
                                                const float* __restrict__ bias,
                                                float* __restrict__ C,
                                                int M, int N, int K, int Npad,
                                                int lda, int ldc) {
    __shared__ ushortT Ah[4 * 128 * 8];
    __shared__ ushortT Al[4 * 128 * 8];
    const int tid = threadIdx.x;
    const int bm = blockIdx.y * 128;
    const int bn = blockIdx.x * 128;
    const int lane = tid & 63;
    const int l15 = lane & 15, lg = lane >> 4;
    const int wid = tid >> 6;
    const int wm = wid >> 1, wn = wid & 1;

    f32x4 acc[4][4] = {};

    for (int k0 = 0; k0 < K; k0 += 32) {
        __syncthreads();
        #pragma unroll
        for (int it = 0; it < 2; it++) {
            int c = tid + it * 256;
            int row = c >> 2, kg = c & 3;
            const float* ap = A + (size_t)(bm + row) * lda + k0 + kg * 8;
            u16x8 hv, lv;
            #pragma unroll
            for (int i = 0; i < 8; i++) {
                float v = ap[i];
                ushortT h = tob(v);
                hv[i] = h;
                lv[i] = tob(v - fromb(h));
            }
            int unit = (kg * 128 + row) ^ kg;
            *reinterpret_cast<u16x8*>(&Ah[unit * 8]) = hv;
            *reinterpret_cast<u16x8*>(&Al[unit * 8]) = lv;
        }
        __syncthreads();

        bf16x8 ah[4], al[4], bhf[4], blf[4];
        #pragma unroll
        for (int mf = 0; mf < 4; mf++) {
            int row = wm * 64 + mf * 16 + l15;
            int unit = (lg * 128 + row) ^ lg;
            ah[mf] = __builtin_bit_cast(bf16x8, *reinterpret_cast<const u16x8*>(&Ah[unit * 8]));
            al[mf] = __builtin_bit_cast(bf16x8, *reinterpret_cast<const u16x8*>(&Al[unit * 8]));
        }
        int kgG = (k0 >> 3) + lg;
        #pragma unroll
        for (int nf = 0; nf < 4; nf++) {
            int n = bn + wn * 64 + nf * 16 + l15;
            size_t o = ((size_t)kgG * Npad + n) * 8;
            bhf[nf] = __builtin_bit_cast(bf16x8, *reinterpret_cast<const u16x8*>(Bh + o));
            blf[nf] = __builtin_bit_cast(bf16x8, *reinterpret_cast<const u16x8*>(Bl + o));
        }
        #pragma unroll
        for (int mf = 0; mf < 4; mf++) {
            #pragma unroll
            for (int nf = 0; nf < 4; nf++) {
                acc[mf][nf] = __builtin_amdgcn_mfma_f32_16x16x32_bf16(ah[mf], bhf[nf], acc[mf][nf], 0, 0, 0);
                acc[mf][nf] = __builtin_amdgcn_mfma_f32_16x16x32_bf16(ah[mf], blf[nf], acc[mf][nf], 0, 0, 0);
                acc[mf][nf] = __builtin_amdgcn_mfma_f32_16x16x32_bf16(al[mf], bhf[nf], acc[mf][nf], 0, 0, 0);
            }
        }
    }

    #pragma unroll
    for (int nf = 0; nf < 4; nf++) {
        int col = bn + wn * 64 + nf * 16 + l15;
        if (col >= N) continue;
        float bv = bias[col];
        #pragma unroll
        for (int mf = 0; mf < 4; mf++) {
            #pragma unroll
            for (int q = 0; q < 4; q++) {
                int row = bm + wm * 64 + mf * 16 + lg * 4 + q;
                if (row < M) {
                    float v = acc[mf][nf][q] + bv;
                    if (RELU) v = fmaxf(v, 0.f);
                    C[(size_t)row * ldc + col] = v;
                }
            }
        }
    }
}

// ---------- MFMA bf16 GEMM for node transforms ----------
template <int K, int CHH>
__global__ __launch_bounds__(256) void mfma_gemm(const ushortT* __restrict__ A,
                                                 const ushortT* __restrict__ BpL,
                                                 const ushortT* __restrict__ BpR,
                                                 const float* __restrict__ bl,
                                                 const float* __restrict__ br,
                                                 bf16* __restrict__ XL,
                                                 bf16* __restrict__ XR,
                                                 int M, int Nfull, int n0) {
    constexpr int KU = K / 8;
    __shared__ ushortT Alds[KU * 128 * 8];
    const int tid = threadIdx.x;
    const int bm  = blockIdx.y * 128;
    const int bnb = blockIdx.x * 128;

    for (int u = tid; u < 128 * KU; u += 256) {
        int row = u / KU, kg = u % KU;
        int rg = bm + row; if (rg > M - 1) rg = M - 1;
        u16x8 v = *reinterpret_cast<const u16x8*>(A + (size_t)rg * K + kg * 8);
        int unit = (kg * 128 + row) ^ (kg & 7);
        *reinterpret_cast<u16x8*>(&Alds[unit * 8]) = v;
    }
    __syncthreads();

    const int lane = tid & 63;
    const int l15 = lane & 15, lg = lane >> 4;
    const int wid = tid >> 6;
    const int wm = wid >> 1, wn = wid & 1;

    f32x4 acc[4][4] = {};
    #pragma unroll
    for (int s = 0; s < K / 32; s++) {
        int kg = s * 4 + lg;
        bf16x8 a[4], b[4];
        #pragma unroll
        for (int mf = 0; mf < 4; mf++) {
            int row = wm * 64 + mf * 16 + l15;
            int unit = (kg * 128 + row) ^ (kg & 7);
            a[mf] = __builtin_bit_cast(bf16x8,
                    *reinterpret_cast<const u16x8*>(&Alds[unit * 8]));
        }
        #pragma unroll
        for (int nf = 0; nf < 4; nf++) {
            int cb = bnb + wn * 64 + nf * 16;
            const ushortT* bp; int n;
            if (cb < CHH) { bp = BpL; n = n0 + cb + l15; }
            else          { bp = BpR; n = n0 + cb - CHH + l15; }
            b[nf] = __builtin_bit_cast(bf16x8,
                    *reinterpret_cast<const u16x8*>(bp + ((size_t)kg * Nfull + n) * 8));
        }
        #pragma unroll
        for (int mf = 0; mf < 4; mf++)
            #pragma unroll
            for (int nf = 0; nf < 4; nf++)
                acc[mf][nf] = __builtin_amdgcn_mfma_f32_16x16x32_bf16(
                    a[mf], b[nf], acc[mf][nf], 0, 0, 0);
    }

    #pragma unroll
    for (int nf = 0; nf < 4; nf++) {
        int cb = bnb + wn * 64 + nf * 16;
        bf16* Cp; const float* bs; int c;
        if (cb < CHH) { Cp = XL; bs = bl; c = cb + l15; }
        else          { Cp = XR; bs = br; c = cb - CHH + l15; }
        float bv = bs[c];
        #pragma unroll
        for (int mf = 0; mf < 4; mf++) {
            #pragma unroll
            for (int q = 0; q < 4; q++) {
                int r = bm + wm * 64 + mf * 16 + lg * 4 + q;
                if (r < M) Cp[(size_t)r * CHH + c] = __float2bfloat16(acc[mf][nf][q] + bv);
            }
        }
    }
}

// ---------- GATv2 aggregation per head: wave/node, online softmax, depth-4 prefetch ----
template <int CHH, int MODE>
__global__ __launch_bounds__(256) void gat_head(const ushortT* __restrict__ XL,
                                                const ushortT* __restrict__ XR,
                                                int ldx, int offx,
                                                const float* __restrict__ att_h,
                                                const float* __restrict__ bias,
                                                const int* __restrict__ offsets,
                                                const int* __restrict__ srcs,
                                                ushortT* __restrict__ OUT, int N) {
    constexpr int VEC = CHH / 64;
    using RT = typename RawV<VEC>::T;
    int wid  = threadIdx.x >> 6;
    int lane = threadIdx.x & 63;
    int n = blockIdx.x * 4 + wid;
    if (n >= N) return;

    float xr_[VEC], att_[VEC], acc[VEC];
    const ushortT* xrp = XR + (size_t)n * ldx + offx + VEC * lane;
    #pragma unroll
    for (int i = 0; i < VEC; i++) {
        xr_[i]  = fromb(xrp[i]);
        att_[i] = att_h[VEC * lane + i];
        acc[i]  = 0.f;
    }
    float m = -3.0e38f, denom = 0.f;

    const int e0 = offsets[n], e1 = offsets[n + 1];
    const int deg = e1 - e0;
    const int loff = offx + VEC * lane;

    for (int base = 0; base < deg; base += 64) {
        int cnt = deg - base; if (cnt > 64) cnt = 64;
        int sl = srcs[e0 + base + ((lane < cnt) ? lane : (cnt - 1))];

        RT pf0, pf1, pf2, pf3;
        pf0 = *reinterpret_cast<const RT*>(XL + (size_t)__shfl(sl, 0) * ldx + loff);
        pf1 = (cnt > 1) ? *reinterpret_cast<const RT*>(XL + (size_t)__shfl(sl, 1) * ldx + loff) : pf0;
        pf2 = (cnt > 2) ? *reinterpret_cast<const RT*>(XL + (size_t)__shfl(sl, 2) * ldx + loff) : pf0;
        pf3 = (cnt > 3) ? *reinterpret_cast<const RT*>(XL + (size_t)__shfl(sl, 3) * ldx + loff) : pf0;

        for (int j = 0; j < cnt; ++j) {
            RT cur = pf0;
            pf0 = pf1; pf1 = pf2; pf2 = pf3;
            if (j + 4 < cnt)
                pf3 = *reinterpret_cast<const RT*>(XL + (size_t)__shfl(sl, j + 4) * ldx + loff);

            float xl[VEC];
            cvtv(cur, xl);
            float part = 0.f;
            #pragma unroll
            for (int i = 0; i < VEC; i++) {
                float v = xl[i] + xr_[i];
                v = (v > 0.f) ? v : 0.2f * v;       // leaky_relu(0.2)
                part += att_[i] * v;
            }
            #pragma unroll
            for (int ofs = 32; ofs > 0; ofs >>= 1)
                part += __shfl_xor(part, ofs);

            float mn = fmaxf(m, part);
            float sc = __expf(m - mn);
            float w  = __expf(part - mn);
            denom = denom * sc + w;
            m = mn;
            #pragma unroll
            for (int i = 0; i < VEC; i++) acc[i] = acc[i] * sc + w * xl[i];
        }
    }

    float inv = 1.f / (denom + 1e-16f);
    #pragma unroll
    for (int i = 0; i < VEC; i++) {
        int c = VEC * lane + i;
        size_t idx = (size_t)n * CHH + c;
        float v = acc[i] * inv;
        if (MODE > 0) v += fromb(OUT[idx]);
        if (MODE == 2) { v = v * (1.f / 3.f) + bias[c]; v = fmaxf(v, 0.f); }
        OUT[idx] = tob(v);
    }
}

// ---------- pool: block per graph, binary search on sorted batch ----------
__global__ void pool_kernel(const ushortT* __restrict__ h3, const int* __restrict__ batch,
                            float* __restrict__ G) {
    int g = blockIdx.x;
    int c = threadIdx.x;
    int lo = 0, hi = N_NODES;
    while (lo < hi) { int mid = (lo + hi) >> 1; if (batch[mid] < g) lo = mid + 1; else hi = mid; }
    int s0 = lo;
    hi = N_NODES;
    while (lo < hi) { int mid = (lo + hi) >> 1; if (batch[mid] < g + 1) lo = mid + 1; else hi = mid; }
    int s1 = lo;
    float sum = 0.f;
    for (int n = s0; n < s1; n++) sum += fromb(h3[(size_t)n * 256 + c]);
    G[(size_t)g * 256 + c] = sum;
}

// ---------- output assembly ----------
__global__ void assemble_kernel(const float* __restrict__ o3, float* __restrict__ out) {
    int g = blockIdx.x;
    const float* row = o3 + (size_t)g * 1160;
    float* xrec = out + (size_t)g * 319;
    for (int p = threadIdx.x; p < 319; p += 256) xrec[p] = row[p];
    float* adj = out + 653312 + (size_t)g * 841;
    for (int p = threadIdx.x; p < 841; p += 256) {
        int i = p / 29, j = p % 29;
        adj[p] = 0.5f * (row[319 + p] + row[319 + j * 29 + i]);
    }
}

// ---------- launch ----------
extern "C" void kernel_launch(void* const* d_in, const int* in_sizes, int n_in,
                              void* d_out, int out_size, void* d_ws, size_t ws_size,
                              hipStream_t stream) {
    const float* x     = (const float*)d_in[0];
    const int*   ei    = (const int*)d_in[1];
    const int*   batch = (const int*)d_in[2];
    const float* Wl1 = (const float*)d_in[3];
    const float* bl1 = (const float*)d_in[4];
    const float* Wr1 = (const float*)d_in[5];
    const float* br1 = (const float*)d_in[6];
    const float* att1= (const float*)d_in[7];
    const float* b1  = (const float*)d_in[8];
    const float* Wl2 = (const float*)d_in[9];
    const float* bl2 = (const float*)d_in[10];
    const float* Wr2 = (const float*)d_in[11];
    const float* br2 = (const float*)d_in[12];
    const float* att2= (const float*)d_in[13];
    const float* b2  = (const float*)d_in[14];
    const float* Wl3 = (const float*)d_in[15];
    const float* bl3 = (const float*)d_in[16];
    const float* Wr3 = (const float*)d_in[17];
    const float* br3 = (const float*)d_in[18];
    const float* att3= (const float*)d_in[19];
    const float* b3  = (const float*)d_in[20];
    const float* Wmu = (const float*)d_in[21];
    const float* bmu = (const float*)d_in[22];
    const float* Wlv = (const float*)d_in[23];
    const float* blv = (const float*)d_in[24];
    const float* Wd1 = (const float*)d_in[25];
    const float* bd1 = (const float*)d_in[26];
    const float* Wd2 = (const float*)d_in[27];
    const float* bd2 = (const float*)d_in[28];
    const float* Wd3 = (const float*)d_in[29];
    const float* bd3 = (const float*)d_in[30];
    float* out = (float*)d_out;

    // ---- workspace layout (bytes) ----
    char* wsb = (char*)d_ws;
    ushortT* h3u = (ushortT*)(wsb + 0);         // 50000x256 (aliases h1)
    ushortT* h1u = (ushortT*)(wsb + 0);         // 50000x64
    ushortT* h2u = (ushortT*)(wsb + 25600000);  // 50000x128
    bf16*    XLb = (bf16*)(wsb + 38400000);
    ushortT* XLu = (ushortT*)(wsb + 38400000);
    bf16*    XRb = (bf16*)(wsb + 64000000);
    ushortT* XRu = (ushortT*)(wsb + 64000000);
    float* G  = (float*)(wsb + 38400000);       // decoder scratch aliases XL (dead after L3)
    float* O1 = G  + 524288;
    float* O2 = O1 + 524288;
    float* O3 = O2 + 1048576;
    // decoder split weights alias XR (dead after last gat_head)
    ushortT* BhD3 = (ushortT*)(wsb + 64000000); // 64*1280*8 u16 = 1.31 MB
    ushortT* BlD3 = (ushortT*)(wsb + 65400000);
    ushortT* BhD2 = (ushortT*)(wsb + 66800000); // 32*512*8 u16 = 0.26 MB
    ushortT* BlD2 = (ushortT*)(wsb + 67100000);
    ushortT* BhD1 = (ushortT*)(wsb + 67400000); // 8*256*8 u16 = 32 KB
    ushortT* BlD1 = (ushortT*)(wsb + 67500000);
    int* counts  = (int*)(wsb + 89600000);
    int* offsets = counts + (N_NODES + 1);
    int* cursor  = offsets + (N_NODES + 1);
    int* srcs    = cursor + (N_NODES + 1);
    ushortT* BpL2 = (ushortT*)(wsb + 92000016);
    ushortT* BpR2 = (ushortT*)(wsb + 92049168);
    ushortT* BpL3 = (ushortT*)(wsb + 92098320);
    ushortT* BpR3 = (ushortT*)(wsb + 92294928);

    size_t needed = 92491536;
    if (ws_size < needed) {
        hipLaunchKernelGGL(diag_kernel, dim3(1), dim3(64), 0, stream, out, (float)(ws_size >> 20));
        return;
    }

    const int MU_OFF = 2375680;
    const int LV_OFF = 2506752;

    // ---- CSR build ----
    hipMemsetAsync(counts, 0, sizeof(int) * (N_NODES + 1), stream);
    hipLaunchKernelGGL(hist_kernel, dim3((E_TOT + 255) / 256), dim3(256), 0, stream, ei, counts);
    hipLaunchKernelGGL(scan_kernel, dim3(1), dim3(1024), 0, stream, counts, offsets);
    hipLaunchKernelGGL(copy_kernel, dim3((N_NODES + 255) / 256), dim3(256), 0, stream,
                       offsets, cursor, N_NODES);
    hipLaunchKernelGGL(scatter_kernel, dim3((E_TOT + 255) / 256), dim3(256), 0, stream,
                       ei, cursor, srcs);

    // ---- GAT weight repack ----
    hipLaunchKernelGGL(repack_kernel, dim3((64 * 384 + 255) / 256), dim3(256), 0, stream,
                       Wl2, BpL2, 64, 384);
    hipLaunchKernelGGL(repack_kernel, dim3((64 * 384 + 255) / 256), dim3(256), 0, stream,
                       Wr2, BpR2, 64, 384);
    hipLaunchKernelGGL(repack_kernel, dim3((128 * 768 + 255) / 256), dim3(256), 0, stream,
                       Wl3, BpL3, 128, 768);
    hipLaunchKernelGGL(repack_kernel, dim3((128 * 768 + 255) / 256), dim3(256), 0, stream,
                       Wr3, BpR3, 128, 768);

    const dim3 AGG_GRID(N_NODES / 4);

    // ---- layer 1 ----
    hipLaunchKernelGGL(l1_transform, dim3((N_NODES + 63) / 64), dim3(192), 0, stream,
                       x, Wl1, bl1, Wr1, br1, XLu, XRu, N_NODES);
    hipLaunchKernelGGL((gat_head<64, 0>), AGG_GRID, dim3(256), 0, stream,
                       XLu, XRu, 192, 0,   att1 + 0,   b1, offsets, srcs, h1u, N_NODES);
    hipLaunchKernelGGL((gat_head<64, 1>), AGG_GRID, dim3(256), 0, stream,
                       XLu, XRu, 192, 64,  att1 + 64,  b1, offsets, srcs, h1u, N_NODES);
    hipLaunchKernelGGL((gat_head<64, 2>), AGG_GRID, dim3(256), 0, stream,
                       XLu, XRu, 192, 128, att1 + 128, b1, offsets, srcs, h1u, N_NODES);

    // ---- layer 2 (K=64, CHH=128) ----
    for (int h = 0; h < 3; ++h) {
        hipLaunchKernelGGL((mfma_gemm<64, 128>), dim3(2, 391), dim3(256), 0, stream,
                           h1u, BpL2, BpR2, bl2 + h * 128, br2 + h * 128,
                           XLb, XRb, N_NODES, 384, h * 128);
        if (h == 0)      hipLaunchKernelGGL((gat_head<128, 0>), AGG_GRID, dim3(256), 0, stream,
                             XLu, XRu, 128, 0, att2 + h * 128, b2, offsets, srcs, h2u, N_NODES);
        else if (h == 1) hipLaunchKernelGGL((gat_head<128, 1>), AGG_GRID, dim3(256), 0, stream,
                             XLu, XRu, 128, 0, att2 + h * 128, b2, offsets, srcs, h2u, N_NODES);
        else             hipLaunchKernelGGL((gat_head<128, 2>), AGG_GRID, dim3(256), 0, stream,
                             XLu, XRu, 128, 0, att2 + h * 128, b2, offsets, srcs, h2u, N_NODES);
    }

    // ---- layer 3 (K=128, CHH=256) ----
    for (int h = 0; h < 3; ++h) {
        hipLaunchKernelGGL((mfma_gemm<128, 256>), dim3(4, 391), dim3(256), 0, stream,
                           h2u, BpL3, BpR3, bl3 + h * 256, br3 + h * 256,
                           XLb, XRb, N_NODES, 768, h * 256);
        if (h == 0)      hipLaunchKernelGGL((gat_head<256, 0>), AGG_GRID, dim3(256), 0, stream,
                             XLu, XRu, 256, 0, att3 + h * 256, b3, offsets, srcs, h3u, N_NODES);
        else if (h == 1) hipLaunchKernelGGL((gat_head<256, 1>), AGG_GRID, dim3(256), 0, stream,
                             XLu, XRu, 256, 0, att3 + h * 256, b3, offsets, srcs, h3u, N_NODES);
        else             hipLaunchKernelGGL((gat_head<256, 2>), AGG_GRID, dim3(256), 0, stream,
                             XLu, XRu, 256, 0, att3 + h * 256, b3, offsets, srcs, h3u, N_NODES);
    }

    // ---- decoder split-weight repack (XR now dead) ----
    hipLaunchKernelGGL(repack_split, dim3((64 * 256 + 255) / 256), dim3(256), 0, stream,
                       Wd1, BhD1, BlD1, 64, 256, 256);
    hipLaunchKernelGGL(repack_split, dim3((256 * 512 + 255) / 256), dim3(256), 0, stream,
                       Wd2, BhD2, BlD2, 256, 512, 512);
    hipLaunchKernelGGL(repack_split, dim3((512 * 1280 + 255) / 256), dim3(256), 0, stream,
                       Wd3, BhD3, BlD3, 512, 1160, 1280);

    // ---- pool ----
    hipLaunchKernelGGL(pool_kernel, dim3(NUM_GRAPHS), dim3(256), 0, stream, h3u, batch, G);

    // ---- VAE heads (SIMT) + decoder (split-bf16 MFMA) ----
    hipLaunchKernelGGL((gemm_dec<false>), dim3(1, 64), dim3(256), 0, stream,
                       G, Wmu, bmu, out + MU_OFF, NUM_GRAPHS, 64, 256, 256, 64, 64);
    hipLaunchKernelGGL((gemm_dec<false>), dim3(1, 64), dim3(256), 0, stream,
                       G, Wlv, blv, out + LV_OFF, NUM_GRAPHS, 64, 256, 256, 64, 64);
    hipLaunchKernelGGL((mfma_dec<true>), dim3(2, 16), dim3(256), 0, stream,
                       out + MU_OFF, BhD1, BlD1, bd1, O1, NUM_GRAPHS, 256, 64, 256, 64, 256);
    hipLaunchKernelGGL((mfma_dec<true>), dim3(4, 16), dim3(256), 0, stream,
                       O1, BhD2, BlD2, bd2, O2, NUM_GRAPHS, 512, 256, 512, 256, 512);
    hipLaunchKernelGGL((mfma_dec<false>), dim3(10, 16), dim3(256), 0, stream,
                       O2, BhD3, BlD3, bd3, O3, NUM_GRAPHS, 1160, 512, 1280, 512, 1160);
    hipLaunchKernelGGL(assemble_kernel, dim3(NUM_GRAPHS), dim3(256), 0, stream, O3, out);
}

// Round 8
// 1039.176 us; speedup vs baseline: 2.1193x; 1.0811x over previous
//
#include <hip/hip_runtime.h>
#include <hip/hip_bf16.h>

typedef __hip_bfloat16 bf16;
typedef unsigned short ushortT;
typedef ushortT u16x2 __attribute__((ext_vector_type(2)));
typedef ushortT u16x4 __attribute__((ext_vector_type(4)));
typedef ushortT u16x8 __attribute__((ext_vector_type(8)));
typedef __bf16   bf16x8 __attribute__((ext_vector_type(8)));
typedef float    f32x4  __attribute__((ext_vector_type(4)));

#define N_NODES    50000
#define E_EDGES    400000
#define E_TOT      450000
#define NUM_GRAPHS 2048
#define SCAN_CHUNK 1024
#define N_CHUNKS   ((N_NODES + SCAN_CHUNK - 1) / SCAN_CHUNK)   // 49

// ---------- helpers ----------
__device__ __forceinline__ float fromb(ushortT u) {
    unsigned int i = ((unsigned int)u) << 16;
    return __builtin_bit_cast(float, i);
}
__device__ __forceinline__ ushortT tob(float v) {
    bf16 h = __float2bfloat16(v);
    return __builtin_bit_cast(ushortT, h);
}

template <int VEC> struct RawV;
template <> struct RawV<1> { using T = ushortT; };
template <> struct RawV<2> { using T = u16x2; };
template <> struct RawV<4> { using T = u16x4; };

__device__ __forceinline__ void cvtv(ushortT r, float* f) { f[0] = fromb(r); }
__device__ __forceinline__ void cvtv(u16x2 r, float* f)   { f[0] = fromb(r.x); f[1] = fromb(r.y); }
__device__ __forceinline__ void cvtv(u16x4 r, float* f)   { f[0] = fromb(r.x); f[1] = fromb(r.y);
                                                            f[2] = fromb(r.z); f[3] = fromb(r.w); }

// ---------- diagnostic ----------
__global__ void diag_kernel(float* out, float v) { if (threadIdx.x == 0) out[0] = v; }

// ---------- CSR build ----------
__global__ void hist_kernel(const int* __restrict__ ei, int* __restrict__ counts) {
    int e = blockIdx.x * 256 + threadIdx.x;
    if (e >= E_TOT) return;
    int d = (e < E_EDGES) ? ei[E_EDGES + e] : (e - E_EDGES);
    atomicAdd(&counts[d], 1);
}

// hierarchical exclusive scan of counts[0..N_NODES) -> offsets[0..N_NODES]
__global__ __launch_bounds__(256) void scan_sums(const int* __restrict__ counts,
                                                 int* __restrict__ chunk_sums) {
    __shared__ int red[4];
    int base = blockIdx.x * SCAN_CHUNK;
    int t = threadIdx.x;
    int s = 0;
    #pragma unroll
    for (int i = 0; i < 4; i++) {
        int idx = base + t + i * 256;
        if (idx < N_NODES) s += counts[idx];
    }
    #pragma unroll
    for (int o = 32; o > 0; o >>= 1) s += __shfl_xor(s, o);
    if ((t & 63) == 0) red[t >> 6] = s;
    __syncthreads();
    if (t == 0) chunk_sums[blockIdx.x] = red[0] + red[1] + red[2] + red[3];
}

__global__ __launch_bounds__(64) void scan_chunks(const int* __restrict__ chunk_sums,
                                                  int* __restrict__ chunk_base) {
    int t = threadIdx.x;
    int v = (t < N_CHUNKS) ? chunk_sums[t] : 0;
    int orig = v;
    #pragma unroll
    for (int o = 1; o < 64; o <<= 1) {
        int u = __shfl_up(v, o);
        if (t >= o) v += u;
    }
    if (t < N_CHUNKS) chunk_base[t] = v - orig;   // exclusive
}

__global__ __launch_bounds__(256) void scan_write(const int* __restrict__ counts,
                                                  const int* __restrict__ chunk_base,
                                                  int* __restrict__ offsets) {
    __shared__ int wsum[4];
    int chunk = blockIdx.x;
    int base = chunk * SCAN_CHUNK;
    int t = threadIdx.x;
    int lane = t & 63, w = t >> 6;

    int c[4];
    int e0 = base + t * 4;
    #pragma unroll
    for (int k = 0; k < 4; k++) {
        int idx = e0 + k;
        c[k] = (idx < N_NODES) ? counts[idx] : 0;
    }
    int local = c[0] + c[1] + c[2] + c[3];

    // wave-inclusive scan of local
    int v = local;
    #pragma unroll
    for (int o = 1; o < 64; o <<= 1) {
        int u = __shfl_up(v, o);
        if (lane >= o) v += u;
    }
    if (lane == 63) wsum[w] = v;
    __syncthreads();
    int wbase = 0;
    for (int i = 0; i < w; i++) wbase += wsum[i];

    int run = chunk_base[chunk] + wbase + (v - local);
    #pragma unroll
    for (int k = 0; k < 4; k++) {
        int idx = e0 + k;
        if (idx < N_NODES) offsets[idx] = run;
        run += c[k];
    }
    if (chunk == 0 && t == 0) offsets[N_NODES] = E_TOT;
}

__global__ void copy_kernel(const int* __restrict__ src, int* __restrict__ dst, int n) {
    int i = blockIdx.x * 256 + threadIdx.x;
    if (i < n) dst[i] = src[i];
}

__global__ void scatter_kernel(const int* __restrict__ ei, int* __restrict__ cursor,
                               int* __restrict__ srcs) {
    int e = blockIdx.x * 256 + threadIdx.x;
    if (e >= E_TOT) return;
    int s, d;
    if (e < E_EDGES) { s = ei[e]; d = ei[E_EDGES + e]; }
    else             { s = d = e - E_EDGES; }
    int pos = atomicAdd(&cursor[d], 1);
    srcs[pos] = s;
}

// ---------- weight repack (bf16): W fp32 [K,N] -> Bp [(k>>3)*N + n]*8 + (k&7) ----------
__global__ void repack_kernel(const float* __restrict__ W, ushortT* __restrict__ Bp,
                              int K, int N) {
    int idx = blockIdx.x * 256 + threadIdx.x;
    if (idx >= K * N) return;
    int k = idx / N, n = idx % N;
    Bp[((size_t)(k >> 3) * N + n) * 8 + (k & 7)] = tob(W[idx]);
}

// ---------- weight repack split hi/lo (for fp32-accurate MFMA decoder) ----------
__global__ void repack_split(const float* __restrict__ W, ushortT* __restrict__ Bh,
                             ushortT* __restrict__ Bl, int K, int N, int Npad) {
    int idx = blockIdx.x * 256 + threadIdx.x;
    if (idx >= K * Npad) return;
    int k = idx / Npad, n = idx % Npad;
    float v = (n < N) ? W[(size_t)k * N + n] : 0.f;
    ushortT h = tob(v);
    float r = v - fromb(h);
    size_t o = ((size_t)(k >> 3) * Npad + n) * 8 + (k & 7);
    Bh[o] = h;
    Bl[o] = tob(r);
}

// ---------- layer-1 fused transform (K=11, N=192) ----------
__global__ __launch_bounds__(192) void l1_transform(const float* __restrict__ x,
                                                    const float* __restrict__ Wl,
                                                    const float* __restrict__ bl,
                                                    const float* __restrict__ Wr,
                                                    const float* __restrict__ br,
                                                    ushortT* __restrict__ XL,
                                                    ushortT* __restrict__ XR, int M) {
    __shared__ float xs[64][11];
    const int tid = threadIdx.x;
    const int bm  = blockIdx.x * 64;
    const int rows = (M - bm < 64) ? (M - bm) : 64;

    float wl[11], wr[11];
    #pragma unroll
    for (int k = 0; k < 11; k++) {
        wl[k] = Wl[k * 192 + tid];
        wr[k] = Wr[k * 192 + tid];
    }
    float blc = bl[tid], brc = br[tid];

    for (int i = tid; i < rows * 11; i += 192)
        xs[i / 11][i % 11] = x[(size_t)bm * 11 + i];
    __syncthreads();

    for (int r = 0; r < rows; r++) {
        float al = blc, ar = brc;
        #pragma unroll
        for (int k = 0; k < 11; k++) {
            float xv = xs[r][k];
            al += xv * wl[k];
            ar += xv * wr[k];
        }
        size_t o = (size_t)(bm + r) * 192 + tid;
        XL[o] = tob(al);
        XR[o] = tob(ar);
    }
}

// ---------- small fp32 SIMT GEMM (mu / logvar heads) ----------
template <bool RELU>
__global__ __launch_bounds__(256) void gemm_dec(const float* __restrict__ A,
                                                const float* __restrict__ B,
                                                const float* __restrict__ bias,
                                                float* __restrict__ C,
                                                int M, int N, int K,
                                                int lda, int ldb, int ldc) {
    __shared__ float As[32][33];
    __shared__ float Bs[32][65];
    int tid = threadIdx.x;
    int tm = tid >> 4, tn = tid & 15;
    int bm = blockIdx.y * 32, bn = blockIdx.x * 64;
    float acc[2][4] = {};
    for (int k0 = 0; k0 < K; k0 += 32) {
        #pragma unroll
        for (int i = 0; i < 4; i++) {
            int e = tid + i * 256;
            int r = e >> 5, k = e & 31;
            int row = bm + r, kk = k0 + k;
            float v = 0.f;
            if (row < M && kk < K) v = A[(size_t)row * lda + kk];
            As[k][r] = v;
        }
        #pragma unroll
        for (int i = 0; i < 8; i++) {
            int e = tid + i * 256;
            int k = e >> 6, n = e & 63;
            int kk = k0 + k, col = bn + n;
            float v = 0.f;
            if (kk < K && col < N) v = B[(size_t)kk * ldb + col];
            Bs[k][n] = v;
        }
        __syncthreads();
        #pragma unroll
        for (int k = 0; k < 32; k++) {
            float a0 = As[k][tm * 2 + 0], a1 = As[k][tm * 2 + 1];
            float b0 = Bs[k][tn * 4 + 0], b1 = Bs[k][tn * 4 + 1];
            float b2 = Bs[k][tn * 4 + 2], b3 = Bs[k][tn * 4 + 3];
            acc[0][0] += a0 * b0; acc[0][1] += a0 * b1; acc[0][2] += a0 * b2; acc[0][3] += a0 * b3;
            acc[1][0] += a1 * b0; acc[1][1] += a1 * b1; acc[1][2] += a1 * b2; acc[1][3] += a1 * b3;
        }
        __syncthreads();
    }
    #pragma unroll
    for (int i = 0; i < 2; i++) {
        int row = bm + tm * 2 + i;
        if (row >= M) continue;
        #pragma unroll
        for (int j = 0; j < 4; j++) {
            int col = bn + tn * 4 + j;
            if (col >= N) continue;
            float v = acc[i][j] + bias[col];
            if (RELU) v = fmaxf(v, 0.f);
            C[(size_t)row * ldc + col] = v;
        }
    }
}

// ---------- split-bf16 MFMA decoder GEMM: fp32-accurate via Ah*Bh + Ah*Bl + Al*Bh ----
template <bool RELU>
__global__ __launch_bounds__(256) void mfma_dec(const float* __restrict__ A,
                                                const ushortT* __restrict__ Bh,
                                                const ushortT* __restrict__ Bl,
                                                const float* __restrict__ bias,
                                                float* __restrict__ C,
                                                int M, int N, int K, int Npad,
                                                int lda, int ldc) {
    __shared__ ushortT Ah[4 * 128 * 8];
    __shared__ ushortT Al[4 * 128 * 8];
    const int tid = threadIdx.x;
    const int bm = blockIdx.y * 128;
    const int bn = blockIdx.x * 128;
    const int lane = tid & 63;
    const int l15 = lane & 15, lg = lane >> 4;
    const int wid = tid >> 6;
    const int wm = wid >> 1, wn = wid & 1;

    f32x4 acc[4][4] = {};

    for (int k0 = 0; k0 < K; k0 += 32) {
        __syncthreads();
        #pragma unroll
        for (int it = 0; it < 2; it++) {
            int c = tid + it * 256;
            int row = c >> 2, kg = c & 3;
            const float* ap = A + (size_t)(bm + row) * lda + k0 + kg * 8;
            u16x8 hv, lv;
            #pragma unroll
            for (int i = 0; i < 8; i++) {
                float v = ap[i];
                ushortT h = tob(v);
                hv[i] = h;
                lv[i] = tob(v - fromb(h));
            }
            int unit = (kg * 128 + row) ^ kg;
            *reinterpret_cast<u16x8*>(&Ah[unit * 8]) = hv;
            *reinterpret_cast<u16x8*>(&Al[unit * 8]) = lv;
        }
        __syncthreads();

        bf16x8 ah[4], al[4], bhf[4], blf[4];
        #pragma unroll
        for (int mf = 0; mf < 4; mf++) {
            int row = wm * 64 + mf * 16 + l15;
            int unit = (lg * 128 + row) ^ lg;
            ah[mf] = __builtin_bit_cast(bf16x8, *reinterpret_cast<const u16x8*>(&Ah[unit * 8]));
            al[mf] = __builtin_bit_cast(bf16x8, *reinterpret_cast<const u16x8*>(&Al[unit * 8]));
        }
        int kgG = (k0 >> 3) + lg;
        #pragma unroll
        for (int nf = 0; nf < 4; nf++) {
            int n = bn + wn * 64 + nf * 16 + l15;
            size_t o = ((size_t)kgG * Npad + n) * 8;
            bhf[nf] = __builtin_bit_cast(bf16x8, *reinterpret_cast<const u16x8*>(Bh + o));
            blf[nf] = __builtin_bit_cast(bf16x8, *reinterpret_cast<const u16x8*>(Bl + o));
        }
        #pragma unroll
        for (int mf = 0; mf < 4; mf++) {
            #pragma unroll
            for (int nf = 0; nf < 4; nf++) {
                acc[mf][nf] = __builtin_amdgcn_mfma_f32_16x16x32_bf16(ah[mf], bhf[nf], acc[mf][nf], 0, 0, 0);
                acc[mf][nf] = __builtin_amdgcn_mfma_f32_16x16x32_bf16(ah[mf], blf[nf], acc[mf][nf], 0, 0, 0);
                acc[mf][nf] = __builtin_amdgcn_mfma_f32_16x16x32_bf16(al[mf], bhf[nf], acc[mf][nf], 0, 0, 0);
            }
        }
    }

    #pragma unroll
    for (int nf = 0; nf < 4; nf++) {
        int col = bn + wn * 64 + nf * 16 + l15;
        if (col >= N) continue;
        float bv = bias[col];
        #pragma unroll
        for (int mf = 0; mf < 4; mf++) {
            #pragma unroll
            for (int q = 0; q < 4; q++) {
                int row = bm + wm * 64 + mf * 16 + lg * 4 + q;
                if (row < M) {
                    float v = acc[mf][nf][q] + bv;
                    if (RELU) v = fmaxf(v, 0.f);
                    C[(size_t)row * ldc + col] = v;
                }
            }
        }
    }
}

// ---------- MFMA bf16 GEMM for node transforms ----------
template <int K, int CHH>
__global__ __launch_bounds__(256) void mfma_gemm(const ushortT* __restrict__ A,
                                                 const ushortT* __restrict__ BpL,
                                                 const ushortT* __restrict__ BpR,
                                                 const float* __restrict__ bl,
                                                 const float* __restrict__ br,
                                                 bf16* __restrict__ XL,
                                                 bf16* __restrict__ XR,
                                                 int M, int Nfull, int n0) {
    constexpr int KU = K / 8;
    __shared__ ushortT Alds[KU * 128 * 8];
    const int tid = threadIdx.x;
    const int bm  = blockIdx.y * 128;
    const int bnb = blockIdx.x * 128;

    for (int u = tid; u < 128 * KU; u += 256) {
        int row = u / KU, kg = u % KU;
        int rg = bm + row; if (rg > M - 1) rg = M - 1;
        u16x8 v = *reinterpret_cast<const u16x8*>(A + (size_t)rg * K + kg * 8);
        int unit = (kg * 128 + row) ^ (kg & 7);
        *reinterpret_cast<u16x8*>(&Alds[unit * 8]) = v;
    }
    __syncthreads();

    const int lane = tid & 63;
    const int l15 = lane & 15, lg = lane >> 4;
    const int wid = tid >> 6;
    const int wm = wid >> 1, wn = wid & 1;

    f32x4 acc[4][4] = {};
    #pragma unroll
    for (int s = 0; s < K / 32; s++) {
        int kg = s * 4 + lg;
        bf16x8 a[4], b[4];
        #pragma unroll
        for (int mf = 0; mf < 4; mf++) {
            int row = wm * 64 + mf * 16 + l15;
            int unit = (kg * 128 + row) ^ (kg & 7);
            a[mf] = __builtin_bit_cast(bf16x8,
                    *reinterpret_cast<const u16x8*>(&Alds[unit * 8]));
        }
        #pragma unroll
        for (int nf = 0; nf < 4; nf++) {
            int cb = bnb + wn * 64 + nf * 16;
            const ushortT* bp; int n;
            if (cb < CHH) { bp = BpL; n = n0 + cb + l15; }
            else          { bp = BpR; n = n0 + cb - CHH + l15; }
            b[nf] = __builtin_bit_cast(bf16x8,
                    *reinterpret_cast<const u16x8*>(bp + ((size_t)kg * Nfull + n) * 8));
        }
        #pragma unroll
        for (int mf = 0; mf < 4; mf++)
            #pragma unroll
            for (int nf = 0; nf < 4; nf++)
                acc[mf][nf] = __builtin_amdgcn_mfma_f32_16x16x32_bf16(
                    a[mf], b[nf], acc[mf][nf], 0, 0, 0);
    }

    #pragma unroll
    for (int nf = 0; nf < 4; nf++) {
        int cb = bnb + wn * 64 + nf * 16;
        bf16* Cp; const float* bs; int c;
        if (cb < CHH) { Cp = XL; bs = bl; c = cb + l15; }
        else          { Cp = XR; bs = br; c = cb - CHH + l15; }
        float bv = bs[c];
        #pragma unroll
        for (int mf = 0; mf < 4; mf++) {
            #pragma unroll
            for (int q = 0; q < 4; q++) {
                int r = bm + wm * 64 + mf * 16 + lg * 4 + q;
                if (r < M) Cp[(size_t)r * CHH + c] = __float2bfloat16(acc[mf][nf][q] + bv);
            }
        }
    }
}

// ---------- GATv2 aggregation per head: wave/node, online softmax, depth-4 prefetch ----
template <int CHH, int MODE>
__global__ __launch_bounds__(256) void gat_head(const ushortT* __restrict__ XL,
                                                const ushortT* __restrict__ XR,
                                                int ldx, int offx,
                                                const float* __restrict__ att_h,
                                                const float* __restrict__ bias,
                                                const int* __restrict__ offsets,
                                                const int* __restrict__ srcs,
                                                ushortT* __restrict__ OUT, int N) {
    constexpr int VEC = CHH / 64;
    using RT = typename RawV<VEC>::T;
    int wid  = threadIdx.x >> 6;
    int lane = threadIdx.x & 63;
    int n = blockIdx.x * 4 + wid;
    if (n >= N) return;

    float xr_[VEC], att_[VEC], acc[VEC];
    const ushortT* xrp = XR + (size_t)n * ldx + offx + VEC * lane;
    #pragma unroll
    for (int i = 0; i < VEC; i++) {
        xr_[i]  = fromb(xrp[i]);
        att_[i] = att_h[VEC * lane + i];
        acc[i]  = 0.f;
    }
    float m = -3.0e38f, denom = 0.f;

    const int e0 = offsets[n], e1 = offsets[n + 1];
    const int deg = e1 - e0;
    const int loff = offx + VEC * lane;

    for (int base = 0; base < deg; base += 64) {
        int cnt = deg - base; if (cnt > 64) cnt = 64;
        int sl = srcs[e0 + base + ((lane < cnt) ? lane : (cnt - 1))];

        RT pf0, pf1, pf2, pf3;
        pf0 = *reinterpret_cast<const RT*>(XL + (size_t)__shfl(sl, 0) * ldx + loff);
        pf1 = (cnt > 1) ? *reinterpret_cast<const RT*>(XL + (size_t)__shfl(sl, 1) * ldx + loff) : pf0;
        pf2 = (cnt > 2) ? *reinterpret_cast<const RT*>(XL + (size_t)__shfl(sl, 2) * ldx + loff) : pf0;
        pf3 = (cnt > 3) ? *reinterpret_cast<const RT*>(XL + (size_t)__shfl(sl, 3) * ldx + loff) : pf0;

        for (int j = 0; j < cnt; ++j) {
            RT cur = pf0;
            pf0 = pf1; pf1 = pf2; pf2 = pf3;
            if (j + 4 < cnt)
                pf3 = *reinterpret_cast<const RT*>(XL + (size_t)__shfl(sl, j + 4) * ldx + loff);

            float xl[VEC];
            cvtv(cur, xl);
            float part = 0.f;
            #pragma unroll
            for (int i = 0; i < VEC; i++) {
                float v = xl[i] + xr_[i];
                v = (v > 0.f) ? v : 0.2f * v;       // leaky_relu(0.2)
                part += att_[i] * v;
            }
            #pragma unroll
            for (int ofs = 32; ofs > 0; ofs >>= 1)
                part += __shfl_xor(part, ofs);

            float mn = fmaxf(m, part);
            float sc = __expf(m - mn);
            float w  = __expf(part - mn);
            denom = denom * sc + w;
            m = mn;
            #pragma unroll
            for (int i = 0; i < VEC; i++) acc[i] = acc[i] * sc + w * xl[i];
        }
    }

    float inv = 1.f / (denom + 1e-16f);
    #pragma unroll
    for (int i = 0; i < VEC; i++) {
        int c = VEC * lane + i;
        size_t idx = (size_t)n * CHH + c;
        float v = acc[i] * inv;
        if (MODE > 0) v += fromb(OUT[idx]);
        if (MODE == 2) { v = v * (1.f / 3.f) + bias[c]; v = fmaxf(v, 0.f); }
        OUT[idx] = tob(v);
    }
}

// ---------- pool: block per graph, binary search on sorted batch ----------
__global__ void pool_kernel(const ushortT* __restrict__ h3, const int* __restrict__ batch,
                            float* __restrict__ G) {
    int g = blockIdx.x;
    int c = threadIdx.x;
    int lo = 0, hi = N_NODES;
    while (lo < hi) { int mid = (lo + hi) >> 1; if (batch[mid] < g) lo = mid + 1; else hi = mid; }
    int s0 = lo;
    hi = N_NODES;
    while (lo < hi) { int mid = (lo + hi) >> 1; if (batch[mid] < g + 1) lo = mid + 1; else hi = mid; }
    int s1 = lo;
    float sum = 0.f;
    for (int n = s0; n < s1; n++) sum += fromb(h3[(size_t)n * 256 + c]);
    G[(size_t)g * 256 + c] = sum;
}

// ---------- output assembly ----------
__global__ void assemble_kernel(const float* __restrict__ o3, float* __restrict__ out) {
    int g = blockIdx.x;
    const float* row = o3 + (size_t)g * 1160;
    float* xrec = out + (size_t)g * 319;
    for (int p = threadIdx.x; p < 319; p += 256) xrec[p] = row[p];
    float* adj = out + 653312 + (size_t)g * 841;
    for (int p = threadIdx.x; p < 841; p += 256) {
        int i = p / 29, j = p % 29;
        adj[p] = 0.5f * (row[319 + p] + row[319 + j * 29 + i]);
    }
}

// ---------- launch ----------
extern "C" void kernel_launch(void* const* d_in, const int* in_sizes, int n_in,
                              void* d_out, int out_size, void* d_ws, size_t ws_size,
                              hipStream_t stream) {
    const float* x     = (const float*)d_in[0];
    const int*   ei    = (const int*)d_in[1];
    const int*   batch = (const int*)d_in[2];
    const float* Wl1 = (const float*)d_in[3];
    const float* bl1 = (const float*)d_in[4];
    const float* Wr1 = (const float*)d_in[5];
    const float* br1 = (const float*)d_in[6];
    const float* att1= (const float*)d_in[7];
    const float* b1  = (const float*)d_in[8];
    const float* Wl2 = (const float*)d_in[9];
    const float* bl2 = (const float*)d_in[10];
    const float* Wr2 = (const float*)d_in[11];
    const float* br2 = (const float*)d_in[12];
    const float* att2= (const float*)d_in[13];
    const float* b2  = (const float*)d_in[14];
    const float* Wl3 = (const float*)d_in[15];
    const float* bl3 = (const float*)d_in[16];
    const float* Wr3 = (const float*)d_in[17];
    const float* br3 = (const float*)d_in[18];
    const float* att3= (const float*)d_in[19];
    const float* b3  = (const float*)d_in[20];
    const float* Wmu = (const float*)d_in[21];
    const float* bmu = (const float*)d_in[22];
    const float* Wlv = (const float*)d_in[23];
    const float* blv = (const float*)d_in[24];
    const float* Wd1 = (const float*)d_in[25];
    const float* bd1 = (const float*)d_in[26];
    const float* Wd2 = (const float*)d_in[27];
    const float* bd2 = (const float*)d_in[28];
    const float* Wd3 = (const float*)d_in[29];
    const float* bd3 = (const float*)d_in[30];
    float* out = (float*)d_out;

    // ---- workspace layout (bytes) ----
    char* wsb = (char*)d_ws;
    ushortT* h3u = (ushortT*)(wsb + 0);         // 50000x256 (aliases h1)
    ushortT* h1u = (ushortT*)(wsb + 0);         // 50000x64
    ushortT* h2u = (ushortT*)(wsb + 25600000);  // 50000x128
    bf16*    XLb = (bf16*)(wsb + 38400000);
    ushortT* XLu = (ushortT*)(wsb + 38400000);
    bf16*    XRb = (bf16*)(wsb + 64000000);
    ushortT* XRu = (ushortT*)(wsb + 64000000);
    float* G  = (float*)(wsb + 38400000);       // decoder scratch aliases XL (dead after L3)
    float* O1 = G  + 524288;
    float* O2 = O1 + 524288;
    float* O3 = O2 + 1048576;
    // decoder split weights alias XR (dead after last gat_head)
    ushortT* BhD3 = (ushortT*)(wsb + 64000000);
    ushortT* BlD3 = (ushortT*)(wsb + 65400000);
    ushortT* BhD2 = (ushortT*)(wsb + 66800000);
    ushortT* BlD2 = (ushortT*)(wsb + 67100000);
    ushortT* BhD1 = (ushortT*)(wsb + 67400000);
    ushortT* BlD1 = (ushortT*)(wsb + 67500000);
    int* counts  = (int*)(wsb + 89600000);
    int* offsets = counts + (N_NODES + 1);
    int* cursor  = offsets + (N_NODES + 1);
    int* srcs    = cursor + (N_NODES + 1);
    int* chunk_sums = srcs + E_TOT;             // 49 + 49 ints
    int* chunk_base = chunk_sums + 64;
    ushortT* BpL2 = (ushortT*)(wsb + 92000528);
    ushortT* BpR2 = (ushortT*)(wsb + 92049680);
    ushortT* BpL3 = (ushortT*)(wsb + 92098832);
    ushortT* BpR3 = (ushortT*)(wsb + 92295440);

    size_t needed = 92492048;
    if (ws_size < needed) {
        hipLaunchKernelGGL(diag_kernel, dim3(1), dim3(64), 0, stream, out, (float)(ws_size >> 20));
        return;
    }

    const int MU_OFF = 2375680;
    const int LV_OFF = 2506752;

    // ---- CSR build (hierarchical scan) ----
    hipMemsetAsync(counts, 0, sizeof(int) * (N_NODES + 1), stream);
    hipLaunchKernelGGL(hist_kernel, dim3((E_TOT + 255) / 256), dim3(256), 0, stream, ei, counts);
    hipLaunchKernelGGL(scan_sums,   dim3(N_CHUNKS), dim3(256), 0, stream, counts, chunk_sums);
    hipLaunchKernelGGL(scan_chunks, dim3(1), dim3(64), 0, stream, chunk_sums, chunk_base);
    hipLaunchKernelGGL(scan_write,  dim3(N_CHUNKS), dim3(256), 0, stream,
                       counts, chunk_base, offsets);
    hipLaunchKernelGGL(copy_kernel, dim3((N_NODES + 255) / 256), dim3(256), 0, stream,
                       offsets, cursor, N_NODES);
    hipLaunchKernelGGL(scatter_kernel, dim3((E_TOT + 255) / 256), dim3(256), 0, stream,
                       ei, cursor, srcs);

    // ---- GAT weight repack ----
    hipLaunchKernelGGL(repack_kernel, dim3((64 * 384 + 255) / 256), dim3(256), 0, stream,
                       Wl2, BpL2, 64, 384);
    hipLaunchKernelGGL(repack_kernel, dim3((64 * 384 + 255) / 256), dim3(256), 0, stream,
                       Wr2, BpR2, 64, 384);
    hipLaunchKernelGGL(repack_kernel, dim3((128 * 768 + 255) / 256), dim3(256), 0, stream,
                       Wl3, BpL3, 128, 768);
    hipLaunchKernelGGL(repack_kernel, dim3((128 * 768 + 255) / 256), dim3(256), 0, stream,
                       Wr3, BpR3, 128, 768);

    const dim3 AGG_GRID(N_NODES / 4);

    // ---- layer 1 ----
    hipLaunchKernelGGL(l1_transform, dim3((N_NODES + 63) / 64), dim3(192), 0, stream,
                       x, Wl1, bl1, Wr1, br1, XLu, XRu, N_NODES);
    hipLaunchKernelGGL((gat_head<64, 0>), AGG_GRID, dim3(256), 0, stream,
                       XLu, XRu, 192, 0,   att1 + 0,   b1, offsets, srcs, h1u, N_NODES);
    hipLaunchKernelGGL((gat_head<64, 1>), AGG_GRID, dim3(256), 0, stream,
                       XLu, XRu, 192, 64,  att1 + 64,  b1, offsets, srcs, h1u, N_NODES);
    hipLaunchKernelGGL((gat_head<64, 2>), AGG_GRID, dim3(256), 0, stream,
                       XLu, XRu, 192, 128, att1 + 128, b1, offsets, srcs, h1u, N_NODES);

    // ---- layer 2 (K=64, CHH=128) ----
    for (int h = 0; h < 3; ++h) {
        hipLaunchKernelGGL((mfma_gemm<64, 128>), dim3(2, 391), dim3(256), 0, stream,
                           h1u, BpL2, BpR2, bl2 + h * 128, br2 + h * 128,
                           XLb, XRb, N_NODES, 384, h * 128);
        if (h == 0)      hipLaunchKernelGGL((gat_head<128, 0>), AGG_GRID, dim3(256), 0, stream,
                             XLu, XRu, 128, 0, att2 + h * 128, b2, offsets, srcs, h2u, N_NODES);
        else if (h == 1) hipLaunchKernelGGL((gat_head<128, 1>), AGG_GRID, dim3(256), 0, stream,
                             XLu, XRu, 128, 0, att2 + h * 128, b2, offsets, srcs, h2u, N_NODES);
        else             hipLaunchKernelGGL((gat_head<128, 2>), AGG_GRID, dim3(256), 0, stream,
                             XLu, XRu, 128, 0, att2 + h * 128, b2, offsets, srcs, h2u, N_NODES);
    }

    // ---- layer 3 (K=128, CHH=256) ----
    for (int h = 0; h < 3; ++h) {
        hipLaunchKernelGGL((mfma_gemm<128, 256>), dim3(4, 391), dim3(256), 0, stream,
                           h2u, BpL3, BpR3, bl3 + h * 256, br3 + h * 256,
                           XLb, XRb, N_NODES, 768, h * 256);
        if (h == 0)      hipLaunchKernelGGL((gat_head<256, 0>), AGG_GRID, dim3(256), 0, stream,
                             XLu, XRu, 256, 0, att3 + h * 256, b3, offsets, srcs, h3u, N_NODES);
        else if (h == 1) hipLaunchKernelGGL((gat_head<256, 1>), AGG_GRID, dim3(256), 0, stream,
                             XLu, XRu, 256, 0, att3 + h * 256, b3, offsets, srcs, h3u, N_NODES);
        else             hipLaunchKernelGGL((gat_head<256, 2>), AGG_GRID, dim3(256), 0, stream,
                             XLu, XRu, 256, 0, att3 + h * 256, b3, offsets, srcs, h3u, N_NODES);
    }

    // ---- decoder split-weight repack (XR now dead) ----
    hipLaunchKernelGGL(repack_split, dim3((64 * 256 + 255) / 256), dim3(256), 0, stream,
                       Wd1, BhD1, BlD1, 64, 256, 256);
    hipLaunchKernelGGL(repack_split, dim3((256 * 512 + 255) / 256), dim3(256), 0, stream,
                       Wd2, BhD2, BlD2, 256, 512, 512);
    hipLaunchKernelGGL(repack_split, dim3((512 * 1280 + 255) / 256), dim3(256), 0, stream,
                       Wd3, BhD3, BlD3, 512, 1160, 1280);

    // ---- pool ----
    hipLaunchKernelGGL(pool_kernel, dim3(NUM_GRAPHS), dim3(256), 0, stream, h3u, batch, G);

    // ---- VAE heads (SIMT) + decoder (split-bf16 MFMA) ----
    hipLaunchKernelGGL((gemm_dec<false>), dim3(1, 64), dim3(256), 0, stream,
                       G, Wmu, bmu, out + MU_OFF, NUM_GRAPHS, 64, 256, 256, 64, 64);
    hipLaunchKernelGGL((gemm_dec<false>), dim3(1, 64), dim3(256), 0, stream,
                       G, Wlv, blv, out + LV_OFF, NUM_GRAPHS, 64, 256, 256, 64, 64);
    hipLaunchKernelGGL((mfma_dec<true>), dim3(2, 16), dim3(256), 0, stream,
                       out + MU_OFF, BhD1, BlD1, bd1, O1, NUM_GRAPHS, 256, 64, 256, 64, 256);
    hipLaunchKernelGGL((mfma_dec<true>), dim3(4, 16), dim3(256), 0, stream,
                       O1, BhD2, BlD2, bd2, O2, NUM_GRAPHS, 512, 256, 512, 256, 512);
    hipLaunchKernelGGL((mfma_dec<false>), dim3(10, 16), dim3(256), 0, stream,
                       O2, BhD3, BlD3, bd3, O3, NUM_GRAPHS, 1160, 512, 1280, 512, 1160);
    hipLaunchKernelGGL(assemble_kernel, dim3(NUM_GRAPHS), dim3(256), 0, stream, O3, out);
}

// Round 9
// 992.592 us; speedup vs baseline: 2.2187x; 1.0469x over previous
//
#include <hip/hip_runtime.h>
#include <hip/hip_bf16.h>

typedef __hip_bfloat16 bf16;
typedef unsigned short ushortT;
typedef ushortT u16x2 __attribute__((ext_vector_type(2)));
typedef ushortT u16x4 __attribute__((ext_vector_type(4)));
typedef ushortT u16x8 __attribute__((ext_vector_type(8)));
typedef __bf16   bf16x8 __attribute__((ext_vector_type(8)));
typedef float    f32x4  __attribute__((ext_vector_type(4)));

#define N_NODES    50000
#define E_EDGES    400000
#define E_TOT      450000
#define NUM_GRAPHS 2048
#define SCAN_CHUNK 1024
#define N_CHUNKS   ((N_NODES + SCAN_CHUNK - 1) / SCAN_CHUNK)   // 49

// ---------- helpers ----------
__device__ __forceinline__ float fromb(ushortT u) {
    unsigned int i = ((unsigned int)u) << 16;
    return __builtin_bit_cast(float, i);
}
__device__ __forceinline__ ushortT tob(float v) {
    bf16 h = __float2bfloat16(v);
    return __builtin_bit_cast(ushortT, h);
}

template <int VEC> struct RawV;
template <> struct RawV<1> { using T = ushortT; };
template <> struct RawV<2> { using T = u16x2; };
template <> struct RawV<4> { using T = u16x4; };

__device__ __forceinline__ void cvtv(ushortT r, float* f) { f[0] = fromb(r); }
__device__ __forceinline__ void cvtv(u16x2 r, float* f)   { f[0] = fromb(r.x); f[1] = fromb(r.y); }
__device__ __forceinline__ void cvtv(u16x4 r, float* f)   { f[0] = fromb(r.x); f[1] = fromb(r.y);
                                                            f[2] = fromb(r.z); f[3] = fromb(r.w); }

// ---------- diagnostic ----------
__global__ void diag_kernel(float* out, float v) { if (threadIdx.x == 0) out[0] = v; }

// ---------- CSR build ----------
__global__ void hist_kernel(const int* __restrict__ ei, int* __restrict__ counts) {
    int e = blockIdx.x * 256 + threadIdx.x;
    if (e >= E_TOT) return;
    int d = (e < E_EDGES) ? ei[E_EDGES + e] : (e - E_EDGES);
    atomicAdd(&counts[d], 1);
}

// hierarchical exclusive scan of counts[0..N_NODES) -> offsets[0..N_NODES]
__global__ __launch_bounds__(256) void scan_sums(const int* __restrict__ counts,
                                                 int* __restrict__ chunk_sums) {
    __shared__ int red[4];
    int base = blockIdx.x * SCAN_CHUNK;
    int t = threadIdx.x;
    int s = 0;
    #pragma unroll
    for (int i = 0; i < 4; i++) {
        int idx = base + t + i * 256;
        if (idx < N_NODES) s += counts[idx];
    }
    #pragma unroll
    for (int o = 32; o > 0; o >>= 1) s += __shfl_xor(s, o);
    if ((t & 63) == 0) red[t >> 6] = s;
    __syncthreads();
    if (t == 0) chunk_sums[blockIdx.x] = red[0] + red[1] + red[2] + red[3];
}

__global__ __launch_bounds__(64) void scan_chunks(const int* __restrict__ chunk_sums,
                                                  int* __restrict__ chunk_base) {
    int t = threadIdx.x;
    int v = (t < N_CHUNKS) ? chunk_sums[t] : 0;
    int orig = v;
    #pragma unroll
    for (int o = 1; o < 64; o <<= 1) {
        int u = __shfl_up(v, o);
        if (t >= o) v += u;
    }
    if (t < N_CHUNKS) chunk_base[t] = v - orig;   // exclusive
}

__global__ __launch_bounds__(256) void scan_write(const int* __restrict__ counts,
                                                  const int* __restrict__ chunk_base,
                                                  int* __restrict__ offsets) {
    __shared__ int wsum[4];
    int chunk = blockIdx.x;
    int base = chunk * SCAN_CHUNK;
    int t = threadIdx.x;
    int lane = t & 63, w = t >> 6;

    int c[4];
    int e0 = base + t * 4;
    #pragma unroll
    for (int k = 0; k < 4; k++) {
        int idx = e0 + k;
        c[k] = (idx < N_NODES) ? counts[idx] : 0;
    }
    int local = c[0] + c[1] + c[2] + c[3];

    // wave-inclusive scan of local
    int v = local;
    #pragma unroll
    for (int o = 1; o < 64; o <<= 1) {
        int u = __shfl_up(v, o);
        if (lane >= o) v += u;
    }
    if (lane == 63) wsum[w] = v;
    __syncthreads();
    int wbase = 0;
    for (int i = 0; i < w; i++) wbase += wsum[i];

    int run = chunk_base[chunk] + wbase + (v - local);
    #pragma unroll
    for (int k = 0; k < 4; k++) {
        int idx = e0 + k;
        if (idx < N_NODES) offsets[idx] = run;
        run += c[k];
    }
    if (chunk == 0 && t == 0) offsets[N_NODES] = E_TOT;
}

__global__ void copy_kernel(const int* __restrict__ src, int* __restrict__ dst, int n) {
    int i = blockIdx.x * 256 + threadIdx.x;
    if (i < n) dst[i] = src[i];
}

__global__ void scatter_kernel(const int* __restrict__ ei, int* __restrict__ cursor,
                               int* __restrict__ srcs) {
    int e = blockIdx.x * 256 + threadIdx.x;
    if (e >= E_TOT) return;
    int s, d;
    if (e < E_EDGES) { s = ei[e]; d = ei[E_EDGES + e]; }
    else             { s = d = e - E_EDGES; }
    int pos = atomicAdd(&cursor[d], 1);
    srcs[pos] = s;
}

// ---------- weight repack (bf16): W fp32 [K,N] -> Bp [(k>>3)*N + n]*8 + (k&7) ----------
__global__ void repack_kernel(const float* __restrict__ W, ushortT* __restrict__ Bp,
                              int K, int N) {
    int idx = blockIdx.x * 256 + threadIdx.x;
    if (idx >= K * N) return;
    int k = idx / N, n = idx % N;
    Bp[((size_t)(k >> 3) * N + n) * 8 + (k & 7)] = tob(W[idx]);
}

// ---------- weight repack split hi/lo (for fp32-accurate MFMA decoder) ----------
__global__ void repack_split(const float* __restrict__ W, ushortT* __restrict__ Bh,
                             ushortT* __restrict__ Bl, int K, int N, int Npad) {
    int idx = blockIdx.x * 256 + threadIdx.x;
    if (idx >= K * Npad) return;
    int k = idx / Npad, n = idx % Npad;
    float v = (n < N) ? W[(size_t)k * N + n] : 0.f;
    ushortT h = tob(v);
    float r = v - fromb(h);
    size_t o = ((size_t)(k >> 3) * Npad + n) * 8 + (k & 7);
    Bh[o] = h;
    Bl[o] = tob(r);
}

// ---------- layer-1 fused transform (K=11, N=192) ----------
__global__ __launch_bounds__(192) void l1_transform(const float* __restrict__ x,
                                                    const float* __restrict__ Wl,
                                                    const float* __restrict__ bl,
                                                    const float* __restrict__ Wr,
                                                    const float* __restrict__ br,
                                                    ushortT* __restrict__ XL,
                                                    ushortT* __restrict__ XR, int M) {
    __shared__ float xs[64][11];
    const int tid = threadIdx.x;
    const int bm  = blockIdx.x * 64;
    const int rows = (M - bm < 64) ? (M - bm) : 64;

    float wl[11], wr[11];
    #pragma unroll
    for (int k = 0; k < 11; k++) {
        wl[k] = Wl[k * 192 + tid];
        wr[k] = Wr[k * 192 + tid];
    }
    float blc = bl[tid], brc = br[tid];

    for (int i = tid; i < rows * 11; i += 192)
        xs[i / 11][i % 11] = x[(size_t)bm * 11 + i];
    __syncthreads();

    for (int r = 0; r < rows; r++) {
        float al = blc, ar = brc;
        #pragma unroll
        for (int k = 0; k < 11; k++) {
            float xv = xs[r][k];
            al += xv * wl[k];
            ar += xv * wr[k];
        }
        size_t o = (size_t)(bm + r) * 192 + tid;
        XL[o] = tob(al);
        XR[o] = tob(ar);
    }
}

// ---------- small fp32 SIMT GEMM (mu / logvar heads) ----------
template <bool RELU>
__global__ __launch_bounds__(256) void gemm_dec(const float* __restrict__ A,
                                                const float* __restrict__ B,
                                                const float* __restrict__ bias,
                                                float* __restrict__ C,
                                                int M, int N, int K,
                                                int lda, int ldb, int ldc) {
    __shared__ float As[32][33];
    __shared__ float Bs[32][65];
    int tid = threadIdx.x;
    int tm = tid >> 4, tn = tid & 15;
    int bm = blockIdx.y * 32, bn = blockIdx.x * 64;
    float acc[2][4] = {};
    for (int k0 = 0; k0 < K; k0 += 32) {
        #pragma unroll
        for (int i = 0; i < 4; i++) {
            int e = tid + i * 256;
            int r = e >> 5, k = e & 31;
            int row = bm + r, kk = k0 + k;
            float v = 0.f;
            if (row < M && kk < K) v = A[(size_t)row * lda + kk];
            As[k][r] = v;
        }
        #pragma unroll
        for (int i = 0; i < 8; i++) {
            int e = tid + i * 256;
            int k = e >> 6, n = e & 63;
            int kk = k0 + k, col = bn + n;
            float v = 0.f;
            if (kk < K && col < N) v = B[(size_t)kk * ldb + col];
            Bs[k][n] = v;
        }
        __syncthreads();
        #pragma unroll
        for (int k = 0; k < 32; k++) {
            float a0 = As[k][tm * 2 + 0], a1 = As[k][tm * 2 + 1];
            float b0 = Bs[k][tn * 4 + 0], b1 = Bs[k][tn * 4 + 1];
            float b2 = Bs[k][tn * 4 + 2], b3 = Bs[k][tn * 4 + 3];
            acc[0][0] += a0 * b0; acc[0][1] += a0 * b1; acc[0][2] += a0 * b2; acc[0][3] += a0 * b3;
            acc[1][0] += a1 * b0; acc[1][1] += a1 * b1; acc[1][2] += a1 * b2; acc[1][3] += a1 * b3;
        }
        __syncthreads();
    }
    #pragma unroll
    for (int i = 0; i < 2; i++) {
        int row = bm + tm * 2 + i;
        if (row >= M) continue;
        #pragma unroll
        for (int j = 0; j < 4; j++) {
            int col = bn + tn * 4 + j;
            if (col >= N) continue;
            float v = acc[i][j] + bias[col];
            if (RELU) v = fmaxf(v, 0.f);
            C[(size_t)row * ldc + col] = v;
        }
    }
}

// ---------- split-bf16 MFMA decoder GEMM: fp32-accurate via Ah*Bh + Ah*Bl + Al*Bh ----
template <bool RELU>
__global__ __launch_bounds__(256) void mfma_dec(const float* __restrict__ A,
                                                const ushortT* __restrict__ Bh,
                                                const ushortT* __restrict__ Bl,
                                                const float* __restrict__ bias,
                                                float* __restrict__ C,
                                                int M, int N, int K, int Npad,
                                                int lda, int ldc) {
    __shared__ ushortT Ah[4 * 128 * 8];
    __shared__ ushortT Al[4 * 128 * 8];
    const int tid = threadIdx.x;
    const int bm = blockIdx.y * 128;
    const int bn = blockIdx.x * 128;
    const int lane = tid & 63;
    const int l15 = lane & 15, lg = lane >> 4;
    const int wid = tid >> 6;
    const int wm = wid >> 1, wn = wid & 1;

    f32x4 acc[4][4] = {};

    for (int k0 = 0; k0 < K; k0 += 32) {
        __syncthreads();
        #pragma unroll
        for (int it = 0; it < 2; it++) {
            int c = tid + it * 256;
            int row = c >> 2, kg = c & 3;
            const float* ap = A + (size_t)(bm + row) * lda + k0 + kg * 8;
            u16x8 hv, lv;
            #pragma unroll
            for (int i = 0; i < 8; i++) {
                float v = ap[i];
                ushortT h = tob(v);
                hv[i] = h;
                lv[i] = tob(v - fromb(h));
            }
            int unit = (kg * 128 + row) ^ kg;
            *reinterpret_cast<u16x8*>(&Ah[unit * 8]) = hv;
            *reinterpret_cast<u16x8*>(&Al[unit * 8]) = lv;
        }
        __syncthreads();

        bf16x8 ah[4], al[4], bhf[4], blf[4];
        #pragma unroll
        for (int mf = 0; mf < 4; mf++) {
            int row = wm * 64 + mf * 16 + l15;
            int unit = (lg * 128 + row) ^ lg;
            ah[mf] = __builtin_bit_cast(bf16x8, *reinterpret_cast<const u16x8*>(&Ah[unit * 8]));
            al[mf] = __builtin_bit_cast(bf16x8, *reinterpret_cast<const u16x8*>(&Al[unit * 8]));
        }
        int kgG = (k0 >> 3) + lg;
        #pragma unroll
        for (int nf = 0; nf < 4; nf++) {
            int n = bn + wn * 64 + nf * 16 + l15;
            size_t o = ((size_t)kgG * Npad + n) * 8;
            bhf[nf] = __builtin_bit_cast(bf16x8, *reinterpret_cast<const u16x8*>(Bh + o));
            blf[nf] = __builtin_bit_cast(bf16x8, *reinterpret_cast<const u16x8*>(Bl + o));
        }
        #pragma unroll
        for (int mf = 0; mf < 4; mf++) {
            #pragma unroll
            for (int nf = 0; nf < 4; nf++) {
                acc[mf][nf] = __builtin_amdgcn_mfma_f32_16x16x32_bf16(ah[mf], bhf[nf], acc[mf][nf], 0, 0, 0);
                acc[mf][nf] = __builtin_amdgcn_mfma_f32_16x16x32_bf16(ah[mf], blf[nf], acc[mf][nf], 0, 0, 0);
                acc[mf][nf] = __builtin_amdgcn_mfma_f32_16x16x32_bf16(al[mf], bhf[nf], acc[mf][nf], 0, 0, 0);
            }
        }
    }

    #pragma unroll
    for (int nf = 0; nf < 4; nf++) {
        int col = bn + wn * 64 + nf * 16 + l15;
        if (col >= N) continue;
        float bv = bias[col];
        #pragma unroll
        for (int mf = 0; mf < 4; mf++) {
            #pragma unroll
            for (int q = 0; q < 4; q++) {
                int row = bm + wm * 64 + mf * 16 + lg * 4 + q;
                if (row < M) {
                    float v = acc[mf][nf][q] + bv;
                    if (RELU) v = fmaxf(v, 0.f);
                    C[(size_t)row * ldc + col] = v;
                }
            }
        }
    }
}

// ---------- MFMA bf16 GEMM for node transforms ----------
template <int K, int CHH>
__global__ __launch_bounds__(256) void mfma_gemm(const ushortT* __restrict__ A,
                                                 const ushortT* __restrict__ BpL,
                                                 const ushortT* __restrict__ BpR,
                                                 const float* __restrict__ bl,
                                                 const float* __restrict__ br,
                                                 bf16* __restrict__ XL,
                                                 bf16* __restrict__ XR,
                                                 int M, int Nfull, int n0) {
    constexpr int KU = K / 8;
    __shared__ ushortT Alds[KU * 128 * 8];
    const int tid = threadIdx.x;
    const int bm  = blockIdx.y * 128;
    const int bnb = blockIdx.x * 128;

    for (int u = tid; u < 128 * KU; u += 256) {
        int row = u / KU, kg = u % KU;
        int rg = bm + row; if (rg > M - 1) rg = M - 1;
        u16x8 v = *reinterpret_cast<const u16x8*>(A + (size_t)rg * K + kg * 8);
        int unit = (kg * 128 + row) ^ (kg & 7);
        *reinterpret_cast<u16x8*>(&Alds[unit * 8]) = v;
    }
    __syncthreads();

    const int lane = tid & 63;
    const int l15 = lane & 15, lg = lane >> 4;
    const int wid = tid >> 6;
    const int wm = wid >> 1, wn = wid & 1;

    f32x4 acc[4][4] = {};
    #pragma unroll
    for (int s = 0; s < K / 32; s++) {
        int kg = s * 4 + lg;
        bf16x8 a[4], b[4];
        #pragma unroll
        for (int mf = 0; mf < 4; mf++) {
            int row = wm * 64 + mf * 16 + l15;
            int unit = (kg * 128 + row) ^ (kg & 7);
            a[mf] = __builtin_bit_cast(bf16x8,
                    *reinterpret_cast<const u16x8*>(&Alds[unit * 8]));
        }
        #pragma unroll
        for (int nf = 0; nf < 4; nf++) {
            int cb = bnb + wn * 64 + nf * 16;
            const ushortT* bp; int n;
            if (cb < CHH) { bp = BpL; n = n0 + cb + l15; }
            else          { bp = BpR; n = n0 + cb - CHH + l15; }
            b[nf] = __builtin_bit_cast(bf16x8,
                    *reinterpret_cast<const u16x8*>(bp + ((size_t)kg * Nfull + n) * 8));
        }
        #pragma unroll
        for (int mf = 0; mf < 4; mf++)
            #pragma unroll
            for (int nf = 0; nf < 4; nf++)
                acc[mf][nf] = __builtin_amdgcn_mfma_f32_16x16x32_bf16(
                    a[mf], b[nf], acc[mf][nf], 0, 0, 0);
    }

    #pragma unroll
    for (int nf = 0; nf < 4; nf++) {
        int cb = bnb + wn * 64 + nf * 16;
        bf16* Cp; const float* bs; int c;
        if (cb < CHH) { Cp = XL; bs = bl; c = cb + l15; }
        else          { Cp = XR; bs = br; c = cb - CHH + l15; }
        float bv = bs[c];
        #pragma unroll
        for (int mf = 0; mf < 4; mf++) {
            #pragma unroll
            for (int q = 0; q < 4; q++) {
                int r = bm + wm * 64 + mf * 16 + lg * 4 + q;
                if (r < M) Cp[(size_t)r * CHH + c] = __float2bfloat16(acc[mf][nf][q] + bv);
            }
        }
    }
}

// ---------- GATv2 aggregation per head: wave/node, direct exp (no max), depth-4 prefetch
// Safe: |logit| <= ||att||*||e|| << 87, so exp(logit)/sum == softmax exactly.
// leaky_relu(0.2) folded into the dot: att*leaky(v) = (0.6att)*v + (0.4att)*|v|.
template <int CHH, int MODE>
__global__ __launch_bounds__(256) void gat_head(const ushortT* __restrict__ XL,
                                                const ushortT* __restrict__ XR,
                                                int ldx, int offx,
                                                const float* __restrict__ att_h,
                                                const float* __restrict__ bias,
                                                const int* __restrict__ offsets,
                                                const int* __restrict__ srcs,
                                                ushortT* __restrict__ OUT, int N) {
    constexpr int VEC = CHH / 64;
    using RT = typename RawV<VEC>::T;
    int wid  = threadIdx.x >> 6;
    int lane = threadIdx.x & 63;
    int n = blockIdx.x * 4 + wid;
    if (n >= N) return;

    float xr_[VEC], a06[VEC], a04[VEC], acc[VEC];
    const ushortT* xrp = XR + (size_t)n * ldx + offx + VEC * lane;
    #pragma unroll
    for (int i = 0; i < VEC; i++) {
        xr_[i] = fromb(xrp[i]);
        float a = att_h[VEC * lane + i];
        a06[i] = 0.6f * a;
        a04[i] = 0.4f * a;
        acc[i] = 0.f;
    }
    float denom = 0.f;

    const int e0 = offsets[n], e1 = offsets[n + 1];
    const int deg = e1 - e0;
    const int loff = offx + VEC * lane;

    for (int base = 0; base < deg; base += 64) {
        int cnt = deg - base; if (cnt > 64) cnt = 64;
        int sl = srcs[e0 + base + ((lane < cnt) ? lane : (cnt - 1))];

        RT pf0, pf1, pf2, pf3;
        pf0 = *reinterpret_cast<const RT*>(XL + (size_t)__shfl(sl, 0) * ldx + loff);
        pf1 = (cnt > 1) ? *reinterpret_cast<const RT*>(XL + (size_t)__shfl(sl, 1) * ldx + loff) : pf0;
        pf2 = (cnt > 2) ? *reinterpret_cast<const RT*>(XL + (size_t)__shfl(sl, 2) * ldx + loff) : pf0;
        pf3 = (cnt > 3) ? *reinterpret_cast<const RT*>(XL + (size_t)__shfl(sl, 3) * ldx + loff) : pf0;

        for (int j = 0; j < cnt; ++j) {
            RT cur = pf0;
            pf0 = pf1; pf1 = pf2; pf2 = pf3;
            if (j + 4 < cnt)
                pf3 = *reinterpret_cast<const RT*>(XL + (size_t)__shfl(sl, j + 4) * ldx + loff);

            float xl[VEC];
            cvtv(cur, xl);
            float part = 0.f;
            #pragma unroll
            for (int i = 0; i < VEC; i++) {
                float v = xl[i] + xr_[i];
                float av = fabsf(v);
                part = fmaf(a06[i], v, part);
                part = fmaf(a04[i], av, part);
            }
            #pragma unroll
            for (int ofs = 32; ofs > 0; ofs >>= 1)
                part += __shfl_xor(part, ofs);

            float w = __expf(part);
            denom += w;
            #pragma unroll
            for (int i = 0; i < VEC; i++) acc[i] = fmaf(w, xl[i], acc[i]);
        }
    }

    float inv = 1.f / (denom + 1e-16f);
    #pragma unroll
    for (int i = 0; i < VEC; i++) {
        int c = VEC * lane + i;
        size_t idx = (size_t)n * CHH + c;
        float v = acc[i] * inv;
        if (MODE > 0) v += fromb(OUT[idx]);
        if (MODE == 2) { v = v * (1.f / 3.f) + bias[c]; v = fmaxf(v, 0.f); }
        OUT[idx] = tob(v);
    }
}

// ---------- pool: block per graph, binary search on sorted batch ----------
__global__ void pool_kernel(const ushortT* __restrict__ h3, const int* __restrict__ batch,
                            float* __restrict__ G) {
    int g = blockIdx.x;
    int c = threadIdx.x;
    int lo = 0, hi = N_NODES;
    while (lo < hi) { int mid = (lo + hi) >> 1; if (batch[mid] < g) lo = mid + 1; else hi = mid; }
    int s0 = lo;
    hi = N_NODES;
    while (lo < hi) { int mid = (lo + hi) >> 1; if (batch[mid] < g + 1) lo = mid + 1; else hi = mid; }
    int s1 = lo;
    float sum = 0.f;
    for (int n = s0; n < s1; n++) sum += fromb(h3[(size_t)n * 256 + c]);
    G[(size_t)g * 256 + c] = sum;
}

// ---------- output assembly ----------
__global__ void assemble_kernel(const float* __restrict__ o3, float* __restrict__ out) {
    int g = blockIdx.x;
    const float* row = o3 + (size_t)g * 1160;
    float* xrec = out + (size_t)g * 319;
    for (int p = threadIdx.x; p < 319; p += 256) xrec[p] = row[p];
    float* adj = out + 653312 + (size_t)g * 841;
    for (int p = threadIdx.x; p < 841; p += 256) {
        int i = p / 29, j = p % 29;
        adj[p] = 0.5f * (row[319 + p] + row[319 + j * 29 + i]);
    }
}

// ---------- launch ----------
extern "C" void kernel_launch(void* const* d_in, const int* in_sizes, int n_in,
                              void* d_out, int out_size, void* d_ws, size_t ws_size,
                              hipStream_t stream) {
    const float* x     = (const float*)d_in[0];
    const int*   ei    = (const int*)d_in[1];
    const int*   batch = (const int*)d_in[2];
    const float* Wl1 = (const float*)d_in[3];
    const float* bl1 = (const float*)d_in[4];
    const float* Wr1 = (const float*)d_in[5];
    const float* br1 = (const float*)d_in[6];
    const float* att1= (const float*)d_in[7];
    const float* b1  = (const float*)d_in[8];
    const float* Wl2 = (const float*)d_in[9];
    const float* bl2 = (const float*)d_in[10];
    const float* Wr2 = (const float*)d_in[11];
    const float* br2 = (const float*)d_in[12];
    const float* att2= (const float*)d_in[13];
    const float* b2  = (const float*)d_in[14];
    const float* Wl3 = (const float*)d_in[15];
    const float* bl3 = (const float*)d_in[16];
    const float* Wr3 = (const float*)d_in[17];
    const float* br3 = (const float*)d_in[18];
    const float* att3= (const float*)d_in[19];
    const float* b3  = (const float*)d_in[20];
    const float* Wmu = (const float*)d_in[21];
    const float* bmu = (const float*)d_in[22];
    const float* Wlv = (const float*)d_in[23];
    const float* blv = (const float*)d_in[24];
    const float* Wd1 = (const float*)d_in[25];
    const float* bd1 = (const float*)d_in[26];
    const float* Wd2 = (const float*)d_in[27];
    const float* bd2 = (const float*)d_in[28];
    const float* Wd3 = (const float*)d_in[29];
    const float* bd3 = (const float*)d_in[30];
    float* out = (float*)d_out;

    // ---- workspace layout (bytes) ----
    char* wsb = (char*)d_ws;
    ushortT* h3u = (ushortT*)(wsb + 0);         // 50000x256 (aliases h1)
    ushortT* h1u = (ushortT*)(wsb + 0);         // 50000x64
    ushortT* h2u = (ushortT*)(wsb + 25600000);  // 50000x128
    bf16*    XLb = (bf16*)(wsb + 38400000);
    ushortT* XLu = (ushortT*)(wsb + 38400000);
    bf16*    XRb = (bf16*)(wsb + 64000000);
    ushortT* XRu = (ushortT*)(wsb + 64000000);
    float* G  = (float*)(wsb + 38400000);       // decoder scratch aliases XL (dead after L3)
    float* O1 = G  + 524288;
    float* O2 = O1 + 524288;
    float* O3 = O2 + 1048576;
    // decoder split weights alias XR (dead after last gat_head)
    ushortT* BhD3 = (ushortT*)(wsb + 64000000);
    ushortT* BlD3 = (ushortT*)(wsb + 65400000);
    ushortT* BhD2 = (ushortT*)(wsb + 66800000);
    ushortT* BlD2 = (ushortT*)(wsb + 67100000);
    ushortT* BhD1 = (ushortT*)(wsb + 67400000);
    ushortT* BlD1 = (ushortT*)(wsb + 67500000);
    int* counts  = (int*)(wsb + 89600000);
    int* offsets = counts + (N_NODES + 1);
    int* cursor  = offsets + (N_NODES + 1);
    int* srcs    = cursor + (N_NODES + 1);
    int* chunk_sums = srcs + E_TOT;             // 49 + 49 ints
    int* chunk_base = chunk_sums + 64;
    ushortT* BpL2 = (ushortT*)(wsb + 92000528);
    ushortT* BpR2 = (ushortT*)(wsb + 92049680);
    ushortT* BpL3 = (ushortT*)(wsb + 92098832);
    ushortT* BpR3 = (ushortT*)(wsb + 92295440);

    size_t needed = 92492048;
    if (ws_size < needed) {
        hipLaunchKernelGGL(diag_kernel, dim3(1), dim3(64), 0, stream, out, (float)(ws_size >> 20));
        return;
    }

    const int MU_OFF = 2375680;
    const int LV_OFF = 2506752;

    // ---- CSR build (hierarchical scan) ----
    hipMemsetAsync(counts, 0, sizeof(int) * (N_NODES + 1), stream);
    hipLaunchKernelGGL(hist_kernel, dim3((E_TOT + 255) / 256), dim3(256), 0, stream, ei, counts);
    hipLaunchKernelGGL(scan_sums,   dim3(N_CHUNKS), dim3(256), 0, stream, counts, chunk_sums);
    hipLaunchKernelGGL(scan_chunks, dim3(1), dim3(64), 0, stream, chunk_sums, chunk_base);
    hipLaunchKernelGGL(scan_write,  dim3(N_CHUNKS), dim3(256), 0, stream,
                       counts, chunk_base, offsets);
    hipLaunchKernelGGL(copy_kernel, dim3((N_NODES + 255) / 256), dim3(256), 0, stream,
                       offsets, cursor, N_NODES);
    hipLaunchKernelGGL(scatter_kernel, dim3((E_TOT + 255) / 256), dim3(256), 0, stream,
                       ei, cursor, srcs);

    // ---- GAT weight repack ----
    hipLaunchKernelGGL(repack_kernel, dim3((64 * 384 + 255) / 256), dim3(256), 0, stream,
                       Wl2, BpL2, 64, 384);
    hipLaunchKernelGGL(repack_kernel, dim3((64 * 384 + 255) / 256), dim3(256), 0, stream,
                       Wr2, BpR2, 64, 384);
    hipLaunchKernelGGL(repack_kernel, dim3((128 * 768 + 255) / 256), dim3(256), 0, stream,
                       Wl3, BpL3, 128, 768);
    hipLaunchKernelGGL(repack_kernel, dim3((128 * 768 + 255) / 256), dim3(256), 0, stream,
                       Wr3, BpR3, 128, 768);

    const dim3 AGG_GRID(N_NODES / 4);

    // ---- layer 1 ----
    hipLaunchKernelGGL(l1_transform, dim3((N_NODES + 63) / 64), dim3(192), 0, stream,
                       x, Wl1, bl1, Wr1, br1, XLu, XRu, N_NODES);
    hipLaunchKernelGGL((gat_head<64, 0>), AGG_GRID, dim3(256), 0, stream,
                       XLu, XRu, 192, 0,   att1 + 0,   b1, offsets, srcs, h1u, N_NODES);
    hipLaunchKernelGGL((gat_head<64, 1>), AGG_GRID, dim3(256), 0, stream,
                       XLu, XRu, 192, 64,  att1 + 64,  b1, offsets, srcs, h1u, N_NODES);
    hipLaunchKernelGGL((gat_head<64, 2>), AGG_GRID, dim3(256), 0, stream,
                       XLu, XRu, 192, 128, att1 + 128, b1, offsets, srcs, h1u, N_NODES);

    // ---- layer 2 (K=64, CHH=128) ----
    for (int h = 0; h < 3; ++h) {
        hipLaunchKernelGGL((mfma_gemm<64, 128>), dim3(2, 391), dim3(256), 0, stream,
                           h1u, BpL2, BpR2, bl2 + h * 128, br2 + h * 128,
                           XLb, XRb, N_NODES, 384, h * 128);
        if (h == 0)      hipLaunchKernelGGL((gat_head<128, 0>), AGG_GRID, dim3(256), 0, stream,
                             XLu, XRu, 128, 0, att2 + h * 128, b2, offsets, srcs, h2u, N_NODES);
        else if (h == 1) hipLaunchKernelGGL((gat_head<128, 1>), AGG_GRID, dim3(256), 0, stream,
                             XLu, XRu, 128, 0, att2 + h * 128, b2, offsets, srcs, h2u, N_NODES);
        else             hipLaunchKernelGGL((gat_head<128, 2>), AGG_GRID, dim3(256), 0, stream,
                             XLu, XRu, 128, 0, att2 + h * 128, b2, offsets, srcs, h2u, N_NODES);
    }

    // ---- layer 3 (K=128, CHH=256) ----
    for (int h = 0; h < 3; ++h) {
        hipLaunchKernelGGL((mfma_gemm<128, 256>), dim3(4, 391), dim3(256), 0, stream,
                           h2u, BpL3, BpR3, bl3 + h * 256, br3 + h * 256,
                           XLb, XRb, N_NODES, 768, h * 256);
        if (h == 0)      hipLaunchKernelGGL((gat_head<256, 0>), AGG_GRID, dim3(256), 0, stream,
                             XLu, XRu, 256, 0, att3 + h * 256, b3, offsets, srcs, h3u, N_NODES);
        else if (h == 1) hipLaunchKernelGGL((gat_head<256, 1>), AGG_GRID, dim3(256), 0, stream,
                             XLu, XRu, 256, 0, att3 + h * 256, b3, offsets, srcs, h3u, N_NODES);
        else             hipLaunchKernelGGL((gat_head<256, 2>), AGG_GRID, dim3(256), 0, stream,
                             XLu, XRu, 256, 0, att3 + h * 256, b3, offsets, srcs, h3u, N_NODES);
    }

    // ---- decoder split-weight repack (XR now dead) ----
    hipLaunchKernelGGL(repack_split, dim3((64 * 256 + 255) / 256), dim3(256), 0, stream,
                       Wd1, BhD1, BlD1, 64, 256, 256);
    hipLaunchKernelGGL(repack_split, dim3((256 * 512 + 255) / 256), dim3(256), 0, stream,
                       Wd2, BhD2, BlD2, 256, 512, 512);
    hipLaunchKernelGGL(repack_split, dim3((512 * 1280 + 255) / 256), dim3(256), 0, stream,
                       Wd3, BhD3, BlD3, 512, 1160, 1280);

    // ---- pool ----
    hipLaunchKernelGGL(pool_kernel, dim3(NUM_GRAPHS), dim3(256), 0, stream, h3u, batch, G);

    // ---- VAE heads (SIMT) + decoder (split-bf16 MFMA) ----
    hipLaunchKernelGGL((gemm_dec<false>), dim3(1, 64), dim3(256), 0, stream,
                       G, Wmu, bmu, out + MU_OFF, NUM_GRAPHS, 64, 256, 256, 64, 64);
    hipLaunchKernelGGL((gemm_dec<false>), dim3(1, 64), dim3(256), 0, stream,
                       G, Wlv, blv, out + LV_OFF, NUM_GRAPHS, 64, 256, 256, 64, 64);
    hipLaunchKernelGGL((mfma_dec<true>), dim3(2, 16), dim3(256), 0, stream,
                       out + MU_OFF, BhD1, BlD1, bd1, O1, NUM_GRAPHS, 256, 64, 256, 64, 256);
    hipLaunchKernelGGL((mfma_dec<true>), dim3(4, 16), dim3(256), 0, stream,
                       O1, BhD2, BlD2, bd2, O2, NUM_GRAPHS, 512, 256, 512, 256, 512);
    hipLaunchKernelGGL((mfma_dec<false>), dim3(10, 16), dim3(256), 0, stream,
                       O2, BhD3, BlD3, bd3, O3, NUM_GRAPHS, 1160, 512, 1280, 512, 1160);
    hipLaunchKernelGGL(assemble_kernel, dim3(NUM_GRAPHS), dim3(256), 0, stream, O3, out);
}

// Round 10
// 846.347 us; speedup vs baseline: 2.6021x; 1.1728x over previous
//
#include <hip/hip_runtime.h>
#include <hip/hip_bf16.h>

typedef __hip_bfloat16 bf16;
typedef unsigned short ushortT;
typedef ushortT u16x2 __attribute__((ext_vector_type(2)));
typedef ushortT u16x4 __attribute__((ext_vector_type(4)));
typedef ushortT u16x8 __attribute__((ext_vector_type(8)));
typedef __bf16   bf16x8 __attribute__((ext_vector_type(8)));
typedef float    f32x4  __attribute__((ext_vector_type(4)));

#define N_NODES    50000
#define E_EDGES    400000
#define E_TOT      450000
#define NUM_GRAPHS 2048
#define SCAN_CHUNK 1024
#define N_CHUNKS   ((N_NODES + SCAN_CHUNK - 1) / SCAN_CHUNK)   // 49

// ---------- helpers ----------
__device__ __forceinline__ float fromb(ushortT u) {
    unsigned int i = ((unsigned int)u) << 16;
    return __builtin_bit_cast(float, i);
}
__device__ __forceinline__ ushortT tob(float v) {
    bf16 h = __float2bfloat16(v);
    return __builtin_bit_cast(ushortT, h);
}

template <int VEC> struct RawV;
template <> struct RawV<1> { using T = ushortT; };
template <> struct RawV<2> { using T = u16x2; };
template <> struct RawV<4> { using T = u16x4; };

__device__ __forceinline__ void cvtv(ushortT r, float* f) { f[0] = fromb(r); }
__device__ __forceinline__ void cvtv(u16x2 r, float* f)   { f[0] = fromb(r.x); f[1] = fromb(r.y); }
__device__ __forceinline__ void cvtv(u16x4 r, float* f)   { f[0] = fromb(r.x); f[1] = fromb(r.y);
                                                            f[2] = fromb(r.z); f[3] = fromb(r.w); }

// ---------- diagnostic ----------
__global__ void diag_kernel(float* out, float v) { if (threadIdx.x == 0) out[0] = v; }

// ---------- CSR build ----------
__global__ void hist_kernel(const int* __restrict__ ei, int* __restrict__ counts) {
    int e = blockIdx.x * 256 + threadIdx.x;
    if (e >= E_TOT) return;
    int d = (e < E_EDGES) ? ei[E_EDGES + e] : (e - E_EDGES);
    atomicAdd(&counts[d], 1);
}

__global__ __launch_bounds__(256) void scan_sums(const int* __restrict__ counts,
                                                 int* __restrict__ chunk_sums) {
    __shared__ int red[4];
    int base = blockIdx.x * SCAN_CHUNK;
    int t = threadIdx.x;
    int s = 0;
    #pragma unroll
    for (int i = 0; i < 4; i++) {
        int idx = base + t + i * 256;
        if (idx < N_NODES) s += counts[idx];
    }
    #pragma unroll
    for (int o = 32; o > 0; o >>= 1) s += __shfl_xor(s, o);
    if ((t & 63) == 0) red[t >> 6] = s;
    __syncthreads();
    if (t == 0) chunk_sums[blockIdx.x] = red[0] + red[1] + red[2] + red[3];
}

__global__ __launch_bounds__(64) void scan_chunks(const int* __restrict__ chunk_sums,
                                                  int* __restrict__ chunk_base) {
    int t = threadIdx.x;
    int v = (t < N_CHUNKS) ? chunk_sums[t] : 0;
    int orig = v;
    #pragma unroll
    for (int o = 1; o < 64; o <<= 1) {
        int u = __shfl_up(v, o);
        if (t >= o) v += u;
    }
    if (t < N_CHUNKS) chunk_base[t] = v - orig;   // exclusive
}

__global__ __launch_bounds__(256) void scan_write(const int* __restrict__ counts,
                                                  const int* __restrict__ chunk_base,
                                                  int* __restrict__ offsets) {
    __shared__ int wsum[4];
    int chunk = blockIdx.x;
    int base = chunk * SCAN_CHUNK;
    int t = threadIdx.x;
    int lane = t & 63, w = t >> 6;

    int c[4];
    int e0 = base + t * 4;
    #pragma unroll
    for (int k = 0; k < 4; k++) {
        int idx = e0 + k;
        c[k] = (idx < N_NODES) ? counts[idx] : 0;
    }
    int local = c[0] + c[1] + c[2] + c[3];

    int v = local;
    #pragma unroll
    for (int o = 1; o < 64; o <<= 1) {
        int u = __shfl_up(v, o);
        if (lane >= o) v += u;
    }
    if (lane == 63) wsum[w] = v;
    __syncthreads();
    int wbase = 0;
    for (int i = 0; i < w; i++) wbase += wsum[i];

    int run = chunk_base[chunk] + wbase + (v - local);
    #pragma unroll
    for (int k = 0; k < 4; k++) {
        int idx = e0 + k;
        if (idx < N_NODES) offsets[idx] = run;
        run += c[k];
    }
    if (chunk == 0 && t == 0) offsets[N_NODES] = E_TOT;
}

__global__ void copy_kernel(const int* __restrict__ src, int* __restrict__ dst, int n) {
    int i = blockIdx.x * 256 + threadIdx.x;
    if (i < n) dst[i] = src[i];
}

__global__ void scatter_kernel(const int* __restrict__ ei, int* __restrict__ cursor,
                               int* __restrict__ srcs) {
    int e = blockIdx.x * 256 + threadIdx.x;
    if (e >= E_TOT) return;
    int s, d;
    if (e < E_EDGES) { s = ei[e]; d = ei[E_EDGES + e]; }
    else             { s = d = e - E_EDGES; }
    int pos = atomicAdd(&cursor[d], 1);
    srcs[pos] = s;
}

// ---------- weight repack (bf16): W fp32 [K,N] -> Bp [(k>>3)*N + n]*8 + (k&7) ----------
__global__ void repack_kernel(const float* __restrict__ W, ushortT* __restrict__ Bp,
                              int K, int N) {
    int idx = blockIdx.x * 256 + threadIdx.x;
    if (idx >= K * N) return;
    int k = idx / N, n = idx % N;
    Bp[((size_t)(k >> 3) * N + n) * 8 + (k & 7)] = tob(W[idx]);
}

// ---------- weight repack split hi/lo ----------
__global__ void repack_split(const float* __restrict__ W, ushortT* __restrict__ Bh,
                             ushortT* __restrict__ Bl, int K, int N, int Npad) {
    int idx = blockIdx.x * 256 + threadIdx.x;
    if (idx >= K * Npad) return;
    int k = idx / Npad, n = idx % Npad;
    float v = (n < N) ? W[(size_t)k * N + n] : 0.f;
    ushortT h = tob(v);
    float r = v - fromb(h);
    size_t o = ((size_t)(k >> 3) * Npad + n) * 8 + (k & 7);
    Bh[o] = h;
    Bl[o] = tob(r);
}

// ---------- layer-1 fused transform (K=11, N=192) ----------
__global__ __launch_bounds__(192) void l1_transform(const float* __restrict__ x,
                                                    const float* __restrict__ Wl,
                                                    const float* __restrict__ bl,
                                                    const float* __restrict__ Wr,
                                                    const float* __restrict__ br,
                                                    ushortT* __restrict__ XL,
                                                    ushortT* __restrict__ XR, int M) {
    __shared__ float xs[64][11];
    const int tid = threadIdx.x;
    const int bm  = blockIdx.x * 64;
    const int rows = (M - bm < 64) ? (M - bm) : 64;

    float wl[11], wr[11];
    #pragma unroll
    for (int k = 0; k < 11; k++) {
        wl[k] = Wl[k * 192 + tid];
        wr[k] = Wr[k * 192 + tid];
    }
    float blc = bl[tid], brc = br[tid];

    for (int i = tid; i < rows * 11; i += 192)
        xs[i / 11][i % 11] = x[(size_t)bm * 11 + i];
    __syncthreads();

    for (int r = 0; r < rows; r++) {
        float al = blc, ar = brc;
        #pragma unroll
        for (int k = 0; k < 11; k++) {
            float xv = xs[r][k];
            al += xv * wl[k];
            ar += xv * wr[k];
        }
        size_t o = (size_t)(bm + r) * 192 + tid;
        XL[o] = tob(al);
        XR[o] = tob(ar);
    }
}

// ---------- small fp32 SIMT GEMM (mu / logvar heads) ----------
template <bool RELU>
__global__ __launch_bounds__(256) void gemm_dec(const float* __restrict__ A,
                                                const float* __restrict__ B,
                                                const float* __restrict__ bias,
                                                float* __restrict__ C,
                                                int M, int N, int K,
                                                int lda, int ldb, int ldc) {
    __shared__ float As[32][33];
    __shared__ float Bs[32][65];
    int tid = threadIdx.x;
    int tm = tid >> 4, tn = tid & 15;
    int bm = blockIdx.y * 32, bn = blockIdx.x * 64;
    float acc[2][4] = {};
    for (int k0 = 0; k0 < K; k0 += 32) {
        #pragma unroll
        for (int i = 0; i < 4; i++) {
            int e = tid + i * 256;
            int r = e >> 5, k = e & 31;
            int row = bm + r, kk = k0 + k;
            float v = 0.f;
            if (row < M && kk < K) v = A[(size_t)row * lda + kk];
            As[k][r] = v;
        }
        #pragma unroll
        for (int i = 0; i < 8; i++) {
            int e = tid + i * 256;
            int k = e >> 6, n = e & 63;
            int kk = k0 + k, col = bn + n;
            float v = 0.f;
            if (kk < K && col < N) v = B[(size_t)kk * ldb + col];
            Bs[k][n] = v;
        }
        __syncthreads();
        #pragma unroll
        for (int k = 0; k < 32; k++) {
            float a0 = As[k][tm * 2 + 0], a1 = As[k][tm * 2 + 1];
            float b0 = Bs[k][tn * 4 + 0], b1 = Bs[k][tn * 4 + 1];
            float b2 = Bs[k][tn * 4 + 2], b3 = Bs[k][tn * 4 + 3];
            acc[0][0] += a0 * b0; acc[0][1] += a0 * b1; acc[0][2] += a0 * b2; acc[0][3] += a0 * b3;
            acc[1][0] += a1 * b0; acc[1][1] += a1 * b1; acc[1][2] += a1 * b2; acc[1][3] += a1 * b3;
        }
        __syncthreads();
    }
    #pragma unroll
    for (int i = 0; i < 2; i++) {
        int row = bm + tm * 2 + i;
        if (row >= M) continue;
        #pragma unroll
        for (int j = 0; j < 4; j++) {
            int col = bn + tn * 4 + j;
            if (col >= N) continue;
            float v = acc[i][j] + bias[col];
            if (RELU) v = fmaxf(v, 0.f);
            C[(size_t)row * ldc + col] = v;
        }
    }
}

// ---------- split-bf16 MFMA decoder GEMM ----------
template <bool RELU>
__global__ __launch_bounds__(256) void mfma_dec(const float* __restrict__ A,
                                                const ushortT* __restrict__ Bh,
                                                const ushortT* __restrict__ Bl,
                                                const float* __restrict__ bias,
                                                float* __restrict__ C,
                                                int M, int N, int K, int Npad,
                                                int lda, int ldc) {
    __shared__ ushortT Ah[4 * 128 * 8];
    __shared__ ushortT Al[4 * 128 * 8];
    const int tid = threadIdx.x;
    const int bm = blockIdx.y * 128;
    const int bn = blockIdx.x * 128;
    const int lane = tid & 63;
    const int l15 = lane & 15, lg = lane >> 4;
    const int wid = tid >> 6;
    const int wm = wid >> 1, wn = wid & 1;

    f32x4 acc[4][4] = {};

    for (int k0 = 0; k0 < K; k0 += 32) {
        __syncthreads();
        #pragma unroll
        for (int it = 0; it < 2; it++) {
            int c = tid + it * 256;
            int row = c >> 2, kg = c & 3;
            const float* ap = A + (size_t)(bm + row) * lda + k0 + kg * 8;
            u16x8 hv, lv;
            #pragma unroll
            for (int i = 0; i < 8; i++) {
                float v = ap[i];
                ushortT h = tob(v);
                hv[i] = h;
                lv[i] = tob(v - fromb(h));
            }
            int unit = (kg * 128 + row) ^ kg;
            *reinterpret_cast<u16x8*>(&Ah[unit * 8]) = hv;
            *reinterpret_cast<u16x8*>(&Al[unit * 8]) = lv;
        }
        __syncthreads();

        bf16x8 ah[4], al[4], bhf[4], blf[4];
        #pragma unroll
        for (int mf = 0; mf < 4; mf++) {
            int row = wm * 64 + mf * 16 + l15;
            int unit = (lg * 128 + row) ^ lg;
            ah[mf] = __builtin_bit_cast(bf16x8, *reinterpret_cast<const u16x8*>(&Ah[unit * 8]));
            al[mf] = __builtin_bit_cast(bf16x8, *reinterpret_cast<const u16x8*>(&Al[unit * 8]));
        }
        int kgG = (k0 >> 3) + lg;
        #pragma unroll
        for (int nf = 0; nf < 4; nf++) {
            int n = bn + wn * 64 + nf * 16 + l15;
            size_t o = ((size_t)kgG * Npad + n) * 8;
            bhf[nf] = __builtin_bit_cast(bf16x8, *reinterpret_cast<const u16x8*>(Bh + o));
            blf[nf] = __builtin_bit_cast(bf16x8, *reinterpret_cast<const u16x8*>(Bl + o));
        }
        #pragma unroll
        for (int mf = 0; mf < 4; mf++) {
            #pragma unroll
            for (int nf = 0; nf < 4; nf++) {
                acc[mf][nf] = __builtin_amdgcn_mfma_f32_16x16x32_bf16(ah[mf], bhf[nf], acc[mf][nf], 0, 0, 0);
                acc[mf][nf] = __builtin_amdgcn_mfma_f32_16x16x32_bf16(ah[mf], blf[nf], acc[mf][nf], 0, 0, 0);
                acc[mf][nf] = __builtin_amdgcn_mfma_f32_16x16x32_bf16(al[mf], bhf[nf], acc[mf][nf], 0, 0, 0);
            }
        }
    }

    #pragma unroll
    for (int nf = 0; nf < 4; nf++) {
        int col = bn + wn * 64 + nf * 16 + l15;
        if (col >= N) continue;
        float bv = bias[col];
        #pragma unroll
        for (int mf = 0; mf < 4; mf++) {
            #pragma unroll
            for (int q = 0; q < 4; q++) {
                int row = bm + wm * 64 + mf * 16 + lg * 4 + q;
                if (row < M) {
                    float v = acc[mf][nf][q] + bv;
                    if (RELU) v = fmaxf(v, 0.f);
                    C[(size_t)row * ldc + col] = v;
                }
            }
        }
    }
}

// ---------- per-head MFMA bf16 GEMM (fallback path) ----------
template <int K, int CHH>
__global__ __launch_bounds__(256) void mfma_gemm(const ushortT* __restrict__ A,
                                                 const ushortT* __restrict__ BpL,
                                                 const ushortT* __restrict__ BpR,
                                                 const float* __restrict__ bl,
                                                 const float* __restrict__ br,
                                                 bf16* __restrict__ XL,
                                                 bf16* __restrict__ XR,
                                                 int M, int Nfull, int n0) {
    constexpr int KU = K / 8;
    __shared__ ushortT Alds[KU * 128 * 8];
    const int tid = threadIdx.x;
    const int bm  = blockIdx.y * 128;
    const int bnb = blockIdx.x * 128;

    for (int u = tid; u < 128 * KU; u += 256) {
        int row = u / KU, kg = u % KU;
        int rg = bm + row; if (rg > M - 1) rg = M - 1;
        u16x8 v = *reinterpret_cast<const u16x8*>(A + (size_t)rg * K + kg * 8);
        int unit = (kg * 128 + row) ^ (kg & 7);
        *reinterpret_cast<u16x8*>(&Alds[unit * 8]) = v;
    }
    __syncthreads();

    const int lane = tid & 63;
    const int l15 = lane & 15, lg = lane >> 4;
    const int wid = tid >> 6;
    const int wm = wid >> 1, wn = wid & 1;

    f32x4 acc[4][4] = {};
    #pragma unroll
    for (int s = 0; s < K / 32; s++) {
        int kg = s * 4 + lg;
        bf16x8 a[4], b[4];
        #pragma unroll
        for (int mf = 0; mf < 4; mf++) {
            int row = wm * 64 + mf * 16 + l15;
            int unit = (kg * 128 + row) ^ (kg & 7);
            a[mf] = __builtin_bit_cast(bf16x8,
                    *reinterpret_cast<const u16x8*>(&Alds[unit * 8]));
        }
        #pragma unroll
        for (int nf = 0; nf < 4; nf++) {
            int cb = bnb + wn * 64 + nf * 16;
            const ushortT* bp; int n;
            if (cb < CHH) { bp = BpL; n = n0 + cb + l15; }
            else          { bp = BpR; n = n0 + cb - CHH + l15; }
            b[nf] = __builtin_bit_cast(bf16x8,
                    *reinterpret_cast<const u16x8*>(bp + ((size_t)kg * Nfull + n) * 8));
        }
        #pragma unroll
        for (int mf = 0; mf < 4; mf++)
            #pragma unroll
            for (int nf = 0; nf < 4; nf++)
                acc[mf][nf] = __builtin_amdgcn_mfma_f32_16x16x32_bf16(
                    a[mf], b[nf], acc[mf][nf], 0, 0, 0);
    }

    #pragma unroll
    for (int nf = 0; nf < 4; nf++) {
        int cb = bnb + wn * 64 + nf * 16;
        bf16* Cp; const float* bs; int c;
        if (cb < CHH) { Cp = XL; bs = bl; c = cb + l15; }
        else          { Cp = XR; bs = br; c = cb - CHH + l15; }
        float bv = bs[c];
        #pragma unroll
        for (int mf = 0; mf < 4; mf++) {
            #pragma unroll
            for (int q = 0; q < 4; q++) {
                int r = bm + wm * 64 + mf * 16 + lg * 4 + q;
                if (r < M) Cp[(size_t)r * CHH + c] = __float2bfloat16(acc[mf][nf][q] + bv);
            }
        }
    }
}

// ---------- full-width MFMA bf16 GEMM: all heads, Wl|Wr, one launch ----------
// cols [0,NW) -> XL [M,NW]; cols [NW,2NW) -> XR [M,NW]. gridX = 2*NW/128.
template <int K, int NW>
__global__ __launch_bounds__(256) void mfma_gemmF(const ushortT* __restrict__ A,
                                                  const ushortT* __restrict__ BpL,
                                                  const ushortT* __restrict__ BpR,
                                                  const float* __restrict__ bl,
                                                  const float* __restrict__ br,
                                                  bf16* __restrict__ XL,
                                                  bf16* __restrict__ XR,
                                                  int M) {
    constexpr int KU = K / 8;
    __shared__ ushortT Alds[KU * 128 * 8];
    const int tid = threadIdx.x;
    const int bm  = blockIdx.y * 128;
    const int bnb = blockIdx.x * 128;

    for (int u = tid; u < 128 * KU; u += 256) {
        int row = u / KU, kg = u % KU;
        int rg = bm + row; if (rg > M - 1) rg = M - 1;
        u16x8 v = *reinterpret_cast<const u16x8*>(A + (size_t)rg * K + kg * 8);
        int unit = (kg * 128 + row) ^ (kg & 7);
        *reinterpret_cast<u16x8*>(&Alds[unit * 8]) = v;
    }
    __syncthreads();

    const int lane = tid & 63;
    const int l15 = lane & 15, lg = lane >> 4;
    const int wid = tid >> 6;
    const int wm = wid >> 1, wn = wid & 1;

    f32x4 acc[4][4] = {};
    #pragma unroll
    for (int s = 0; s < K / 32; s++) {
        int kg = s * 4 + lg;
        bf16x8 a[4], b[4];
        #pragma unroll
        for (int mf = 0; mf < 4; mf++) {
            int row = wm * 64 + mf * 16 + l15;
            int unit = (kg * 128 + row) ^ (kg & 7);
            a[mf] = __builtin_bit_cast(bf16x8,
                    *reinterpret_cast<const u16x8*>(&Alds[unit * 8]));
        }
        #pragma unroll
        for (int nf = 0; nf < 4; nf++) {
            int cb = bnb + wn * 64 + nf * 16;
            const ushortT* bp; int n;
            if (cb < NW) { bp = BpL; n = cb + l15; }
            else         { bp = BpR; n = cb - NW + l15; }
            b[nf] = __builtin_bit_cast(bf16x8,
                    *reinterpret_cast<const u16x8*>(bp + ((size_t)kg * NW + n) * 8));
        }
        #pragma unroll
        for (int mf = 0; mf < 4; mf++)
            #pragma unroll
            for (int nf = 0; nf < 4; nf++)
                acc[mf][nf] = __builtin_amdgcn_mfma_f32_16x16x32_bf16(
                    a[mf], b[nf], acc[mf][nf], 0, 0, 0);
    }

    #pragma unroll
    for (int nf = 0; nf < 4; nf++) {
        int cb = bnb + wn * 64 + nf * 16;
        bf16* Cp; const float* bs; int c;
        if (cb < NW) { Cp = XL; bs = bl; c = cb + l15; }
        else         { Cp = XR; bs = br; c = cb - NW + l15; }
        float bv = bs[c];
        #pragma unroll
        for (int mf = 0; mf < 4; mf++) {
            #pragma unroll
            for (int q = 0; q < 4; q++) {
                int r = bm + wm * 64 + mf * 16 + lg * 4 + q;
                if (r < M) Cp[(size_t)r * NW + c] = __float2bfloat16(acc[mf][nf][q] + bv);
            }
        }
    }
}

// ---------- per-head GAT aggregation (fallback path) ----------
template <int CHH, int MODE>
__global__ __launch_bounds__(256) void gat_head(const ushortT* __restrict__ XL,
                                                const ushortT* __restrict__ XR,
                                                int ldx, int offx,
                                                const float* __restrict__ att_h,
                                                const float* __restrict__ bias,
                                                const int* __restrict__ offsets,
                                                const int* __restrict__ srcs,
                                                ushortT* __restrict__ OUT, int N) {
    constexpr int VEC = CHH / 64;
    using RT = typename RawV<VEC>::T;
    int wid  = threadIdx.x >> 6;
    int lane = threadIdx.x & 63;
    int n = blockIdx.x * 4 + wid;
    if (n >= N) return;

    float xr_[VEC], a06[VEC], a04[VEC], acc[VEC];
    const ushortT* xrp = XR + (size_t)n * ldx + offx + VEC * lane;
    #pragma unroll
    for (int i = 0; i < VEC; i++) {
        xr_[i] = fromb(xrp[i]);
        float a = att_h[VEC * lane + i];
        a06[i] = 0.6f * a;
        a04[i] = 0.4f * a;
        acc[i] = 0.f;
    }
    float denom = 0.f;

    const int e0 = offsets[n], e1 = offsets[n + 1];
    const int deg = e1 - e0;
    const int loff = offx + VEC * lane;

    for (int base = 0; base < deg; base += 64) {
        int cnt = deg - base; if (cnt > 64) cnt = 64;
        int sl = srcs[e0 + base + ((lane < cnt) ? lane : (cnt - 1))];

        RT pf0, pf1, pf2, pf3;
        pf0 = *reinterpret_cast<const RT*>(XL + (size_t)__shfl(sl, 0) * ldx + loff);
        pf1 = (cnt > 1) ? *reinterpret_cast<const RT*>(XL + (size_t)__shfl(sl, 1) * ldx + loff) : pf0;
        pf2 = (cnt > 2) ? *reinterpret_cast<const RT*>(XL + (size_t)__shfl(sl, 2) * ldx + loff) : pf0;
        pf3 = (cnt > 3) ? *reinterpret_cast<const RT*>(XL + (size_t)__shfl(sl, 3) * ldx + loff) : pf0;

        for (int j = 0; j < cnt; ++j) {
            RT cur = pf0;
            pf0 = pf1; pf1 = pf2; pf2 = pf3;
            if (j + 4 < cnt)
                pf3 = *reinterpret_cast<const RT*>(XL + (size_t)__shfl(sl, j + 4) * ldx + loff);

            float xl[VEC];
            cvtv(cur, xl);
            float part = 0.f;
            #pragma unroll
            for (int i = 0; i < VEC; i++) {
                float v = xl[i] + xr_[i];
                float av = fabsf(v);
                part = fmaf(a06[i], v, part);
                part = fmaf(a04[i], av, part);
            }
            #pragma unroll
            for (int ofs = 32; ofs > 0; ofs >>= 1)
                part += __shfl_xor(part, ofs);

            float w = __expf(part);
            denom += w;
            #pragma unroll
            for (int i = 0; i < VEC; i++) acc[i] = fmaf(w, xl[i], acc[i]);
        }
    }

    float inv = 1.f / (denom + 1e-16f);
    #pragma unroll
    for (int i = 0; i < VEC; i++) {
        int c = VEC * lane + i;
        size_t idx = (size_t)n * CHH + c;
        float v = acc[i] * inv;
        if (MODE > 0) v += fromb(OUT[idx]);
        if (MODE == 2) { v = v * (1.f / 3.f) + bias[c]; v = fmaxf(v, 0.f); }
        OUT[idx] = tob(v);
    }
}

// ---------- fused 3-head GAT aggregation: one pass over edges, mean in registers ----
// XL/XR full-width [N, 3*CHH]; att [3*CHH] head-major; OUT [N, CHH] = relu(mean+bias).
template <int CHH>
__global__ __launch_bounds__(256) void gat_fused(const ushortT* __restrict__ XL,
                                                 const ushortT* __restrict__ XR,
                                                 const float* __restrict__ att,
                                                 const float* __restrict__ bias,
                                                 const int* __restrict__ offsets,
                                                 const int* __restrict__ srcs,
                                                 ushortT* __restrict__ OUT, int N) {
    constexpr int VEC = CHH / 64;
    constexpr int LDX = 3 * CHH;
    using RT = typename RawV<VEC>::T;
    int wid  = threadIdx.x >> 6;
    int lane = threadIdx.x & 63;
    int n = blockIdx.x * 4 + wid;
    if (n >= N) return;

    float xr_[3][VEC], a06[3][VEC], a04[3][VEC], acc[3][VEC];
    const ushortT* xrp = XR + (size_t)n * LDX + VEC * lane;
    #pragma unroll
    for (int h = 0; h < 3; h++) {
        #pragma unroll
        for (int i = 0; i < VEC; i++) {
            xr_[h][i] = fromb(xrp[h * CHH + i]);
            float a = att[h * CHH + VEC * lane + i];
            a06[h][i] = 0.6f * a;
            a04[h][i] = 0.4f * a;
            acc[h][i] = 0.f;
        }
    }
    float d0 = 0.f, d1 = 0.f, d2 = 0.f;

    const int e0 = offsets[n], e1 = offsets[n + 1];
    const int deg = e1 - e0;
    const int loff = VEC * lane;

    for (int base = 0; base < deg; base += 64) {
        int cnt = deg - base; if (cnt > 64) cnt = 64;
        int sl = srcs[e0 + base + ((lane < cnt) ? lane : (cnt - 1))];

        RT pA0, pA1, pA2, pB0, pB1, pB2;
        {
            const ushortT* r = XL + (size_t)__shfl(sl, 0) * LDX + loff;
            pA0 = *reinterpret_cast<const RT*>(r);
            pA1 = *reinterpret_cast<const RT*>(r + CHH);
            pA2 = *reinterpret_cast<const RT*>(r + 2 * CHH);
        }
        if (cnt > 1) {
            const ushortT* r = XL + (size_t)__shfl(sl, 1) * LDX + loff;
            pB0 = *reinterpret_cast<const RT*>(r);
            pB1 = *reinterpret_cast<const RT*>(r + CHH);
            pB2 = *reinterpret_cast<const RT*>(r + 2 * CHH);
        } else { pB0 = pA0; pB1 = pA1; pB2 = pA2; }

        for (int j = 0; j < cnt; ++j) {
            RT c0 = pA0, c1 = pA1, c2 = pA2;
            pA0 = pB0; pA1 = pB1; pA2 = pB2;
            if (j + 2 < cnt) {
                const ushortT* r = XL + (size_t)__shfl(sl, j + 2) * LDX + loff;
                pB0 = *reinterpret_cast<const RT*>(r);
                pB1 = *reinterpret_cast<const RT*>(r + CHH);
                pB2 = *reinterpret_cast<const RT*>(r + 2 * CHH);
            }

            float xl0[VEC], xl1[VEC], xl2[VEC];
            cvtv(c0, xl0); cvtv(c1, xl1); cvtv(c2, xl2);
            float p0 = 0.f, p1 = 0.f, p2 = 0.f;
            #pragma unroll
            for (int i = 0; i < VEC; i++) {
                float v0 = xl0[i] + xr_[0][i];
                float v1 = xl1[i] + xr_[1][i];
                float v2 = xl2[i] + xr_[2][i];
                p0 = fmaf(a06[0][i], v0, p0); p0 = fmaf(a04[0][i], fabsf(v0), p0);
                p1 = fmaf(a06[1][i], v1, p1); p1 = fmaf(a04[1][i], fabsf(v1), p1);
                p2 = fmaf(a06[2][i], v2, p2); p2 = fmaf(a04[2][i], fabsf(v2), p2);
            }
            #pragma unroll
            for (int ofs = 32; ofs > 0; ofs >>= 1) {
                p0 += __shfl_xor(p0, ofs);
                p1 += __shfl_xor(p1, ofs);
                p2 += __shfl_xor(p2, ofs);
            }

            float w0 = __expf(p0), w1 = __expf(p1), w2 = __expf(p2);
            d0 += w0; d1 += w1; d2 += w2;
            #pragma unroll
            for (int i = 0; i < VEC; i++) {
                acc[0][i] = fmaf(w0, xl0[i], acc[0][i]);
                acc[1][i] = fmaf(w1, xl1[i], acc[1][i]);
                acc[2][i] = fmaf(w2, xl2[i], acc[2][i]);
            }
        }
    }

    float i0 = 1.f / (d0 + 1e-16f);
    float i1 = 1.f / (d1 + 1e-16f);
    float i2 = 1.f / (d2 + 1e-16f);
    #pragma unroll
    for (int i = 0; i < VEC; i++) {
        int c = VEC * lane + i;
        float v = (acc[0][i] * i0 + acc[1][i] * i1 + acc[2][i] * i2) * (1.f / 3.f) + bias[c];
        v = fmaxf(v, 0.f);
        OUT[(size_t)n * CHH + c] = tob(v);
    }
}

// ---------- pool ----------
__global__ void pool_kernel(const ushortT* __restrict__ h3, const int* __restrict__ batch,
                            float* __restrict__ G) {
    int g = blockIdx.x;
    int c = threadIdx.x;
    int lo = 0, hi = N_NODES;
    while (lo < hi) { int mid = (lo + hi) >> 1; if (batch[mid] < g) lo = mid + 1; else hi = mid; }
    int s0 = lo;
    hi = N_NODES;
    while (lo < hi) { int mid = (lo + hi) >> 1; if (batch[mid] < g + 1) lo = mid + 1; else hi = mid; }
    int s1 = lo;
    float sum = 0.f;
    for (int n = s0; n < s1; n++) sum += fromb(h3[(size_t)n * 256 + c]);
    G[(size_t)g * 256 + c] = sum;
}

// ---------- output assembly ----------
__global__ void assemble_kernel(const float* __restrict__ o3, float* __restrict__ out) {
    int g = blockIdx.x;
    const float* row = o3 + (size_t)g * 1160;
    float* xrec = out + (size_t)g * 319;
    for (int p = threadIdx.x; p < 319; p += 256) xrec[p] = row[p];
    float* adj = out + 653312 + (size_t)g * 841;
    for (int p = threadIdx.x; p < 841; p += 256) {
        int i = p / 29, j = p % 29;
        adj[p] = 0.5f * (row[319 + p] + row[319 + j * 29 + i]);
    }
}

// ---------- launch ----------
extern "C" void kernel_launch(void* const* d_in, const int* in_sizes, int n_in,
                              void* d_out, int out_size, void* d_ws, size_t ws_size,
                              hipStream_t stream) {
    const float* x     = (const float*)d_in[0];
    const int*   ei    = (const int*)d_in[1];
    const int*   batch = (const int*)d_in[2];
    const float* Wl1 = (const float*)d_in[3];
    const float* bl1 = (const float*)d_in[4];
    const float* Wr1 = (const float*)d_in[5];
    const float* br1 = (const float*)d_in[6];
    const float* att1= (const float*)d_in[7];
    const float* b1  = (const float*)d_in[8];
    const float* Wl2 = (const float*)d_in[9];
    const float* bl2 = (const float*)d_in[10];
    const float* Wr2 = (const float*)d_in[11];
    const float* br2 = (const float*)d_in[12];
    const float* att2= (const float*)d_in[13];
    const float* b2  = (const float*)d_in[14];
    const float* Wl3 = (const float*)d_in[15];
    const float* bl3 = (const float*)d_in[16];
    const float* Wr3 = (const float*)d_in[17];
    const float* br3 = (const float*)d_in[18];
    const float* att3= (const float*)d_in[19];
    const float* b3  = (const float*)d_in[20];
    const float* Wmu = (const float*)d_in[21];
    const float* bmu = (const float*)d_in[22];
    const float* Wlv = (const float*)d_in[23];
    const float* blv = (const float*)d_in[24];
    const float* Wd1 = (const float*)d_in[25];
    const float* bd1 = (const float*)d_in[26];
    const float* Wd2 = (const float*)d_in[27];
    const float* bd2 = (const float*)d_in[28];
    const float* Wd3 = (const float*)d_in[29];
    const float* bd3 = (const float*)d_in[30];
    float* out = (float*)d_out;

    const int MU_OFF = 2375680;
    const int LV_OFF = 2506752;
    char* wsb = (char*)d_ws;

    const size_t NEED_FULL = 194892064;   // full-width fused path
    const size_t NEED_FB   = 92492048;    // fallback per-head path

    const dim3 AGG_GRID(N_NODES / 4);

    if (ws_size >= NEED_FULL) {
        // ================= FULL-WIDTH FUSED PATH =================
        ushortT* h3u = (ushortT*)(wsb + 0);          // 50000x256
        ushortT* h1u = (ushortT*)(wsb + 0);          // 50000x64 (disjoint lifetime)
        ushortT* h2u = (ushortT*)(wsb + 25600000);   // 50000x128
        bf16*    XLb = (bf16*)(wsb + 38400000);      // up to 50000x768 (76.8M)
        ushortT* XLu = (ushortT*)(wsb + 38400000);
        bf16*    XRb = (bf16*)(wsb + 115200000);     // up to 50000x768
        ushortT* XRu = (ushortT*)(wsb + 115200000);
        float* G  = (float*)(wsb + 38400000);        // decoder scratch aliases XL
        float* O1 = G  + 524288;
        float* O2 = O1 + 524288;
        float* O3 = O2 + 1048576;
        ushortT* BhD3 = (ushortT*)(wsb + 115200000); // alias XR (dead after last gat)
        ushortT* BlD3 = (ushortT*)(wsb + 116600000);
        ushortT* BhD2 = (ushortT*)(wsb + 118000000);
        ushortT* BlD2 = (ushortT*)(wsb + 118300000);
        ushortT* BhD1 = (ushortT*)(wsb + 118600000);
        ushortT* BlD1 = (ushortT*)(wsb + 118700000);
        int* counts  = (int*)(wsb + 192000000);
        int* offsets = counts + (N_NODES + 1);
        int* cursor  = offsets + (N_NODES + 1);
        int* srcs    = cursor + (N_NODES + 1);
        int* chunk_sums = srcs + E_TOT;
        int* chunk_base = chunk_sums + 64;
        ushortT* BpL2 = (ushortT*)(wsb + 194400544); // 16B-aligned
        ushortT* BpR2 = (ushortT*)(wsb + 194449696);
        ushortT* BpL3 = (ushortT*)(wsb + 194498848);
        ushortT* BpR3 = (ushortT*)(wsb + 194695456);

        hipMemsetAsync(counts, 0, sizeof(int) * (N_NODES + 1), stream);
        hipLaunchKernelGGL(hist_kernel, dim3((E_TOT + 255) / 256), dim3(256), 0, stream, ei, counts);
        hipLaunchKernelGGL(scan_sums,   dim3(N_CHUNKS), dim3(256), 0, stream, counts, chunk_sums);
        hipLaunchKernelGGL(scan_chunks, dim3(1), dim3(64), 0, stream, chunk_sums, chunk_base);
        hipLaunchKernelGGL(scan_write,  dim3(N_CHUNKS), dim3(256), 0, stream,
                           counts, chunk_base, offsets);
        hipLaunchKernelGGL(copy_kernel, dim3((N_NODES + 255) / 256), dim3(256), 0, stream,
                           offsets, cursor, N_NODES);
        hipLaunchKernelGGL(scatter_kernel, dim3((E_TOT + 255) / 256), dim3(256), 0, stream,
                           ei, cursor, srcs);

        hipLaunchKernelGGL(repack_kernel, dim3((64 * 384 + 255) / 256), dim3(256), 0, stream,
                           Wl2, BpL2, 64, 384);
        hipLaunchKernelGGL(repack_kernel, dim3((64 * 384 + 255) / 256), dim3(256), 0, stream,
                           Wr2, BpR2, 64, 384);
        hipLaunchKernelGGL(repack_kernel, dim3((128 * 768 + 255) / 256), dim3(256), 0, stream,
                           Wl3, BpL3, 128, 768);
        hipLaunchKernelGGL(repack_kernel, dim3((128 * 768 + 255) / 256), dim3(256), 0, stream,
                           Wr3, BpR3, 128, 768);

        // layer 1
        hipLaunchKernelGGL(l1_transform, dim3((N_NODES + 63) / 64), dim3(192), 0, stream,
                           x, Wl1, bl1, Wr1, br1, XLu, XRu, N_NODES);
        hipLaunchKernelGGL((gat_fused<64>), AGG_GRID, dim3(256), 0, stream,
                           XLu, XRu, att1, b1, offsets, srcs, h1u, N_NODES);
        // layer 2
        hipLaunchKernelGGL((mfma_gemmF<64, 384>), dim3(6, 391), dim3(256), 0, stream,
                           h1u, BpL2, BpR2, bl2, br2, XLb, XRb, N_NODES);
        hipLaunchKernelGGL((gat_fused<128>), AGG_GRID, dim3(256), 0, stream,
                           XLu, XRu, att2, b2, offsets, srcs, h2u, N_NODES);
        // layer 3
        hipLaunchKernelGGL((mfma_gemmF<128, 768>), dim3(12, 391), dim3(256), 0, stream,
                           h2u, BpL3, BpR3, bl3, br3, XLb, XRb, N_NODES);
        hipLaunchKernelGGL((gat_fused<256>), AGG_GRID, dim3(256), 0, stream,
                           XLu, XRu, att3, b3, offsets, srcs, h3u, N_NODES);

        hipLaunchKernelGGL(repack_split, dim3((64 * 256 + 255) / 256), dim3(256), 0, stream,
                           Wd1, BhD1, BlD1, 64, 256, 256);
        hipLaunchKernelGGL(repack_split, dim3((256 * 512 + 255) / 256), dim3(256), 0, stream,
                           Wd2, BhD2, BlD2, 256, 512, 512);
        hipLaunchKernelGGL(repack_split, dim3((512 * 1280 + 255) / 256), dim3(256), 0, stream,
                           Wd3, BhD3, BlD3, 512, 1160, 1280);

        hipLaunchKernelGGL(pool_kernel, dim3(NUM_GRAPHS), dim3(256), 0, stream, h3u, batch, G);

        hipLaunchKernelGGL((gemm_dec<false>), dim3(1, 64), dim3(256), 0, stream,
                           G, Wmu, bmu, out + MU_OFF, NUM_GRAPHS, 64, 256, 256, 64, 64);
        hipLaunchKernelGGL((gemm_dec<false>), dim3(1, 64), dim3(256), 0, stream,
                           G, Wlv, blv, out + LV_OFF, NUM_GRAPHS, 64, 256, 256, 64, 64);
        hipLaunchKernelGGL((mfma_dec<true>), dim3(2, 16), dim3(256), 0, stream,
                           out + MU_OFF, BhD1, BlD1, bd1, O1, NUM_GRAPHS, 256, 64, 256, 64, 256);
        hipLaunchKernelGGL((mfma_dec<true>), dim3(4, 16), dim3(256), 0, stream,
                           O1, BhD2, BlD2, bd2, O2, NUM_GRAPHS, 512, 256, 512, 256, 512);
        hipLaunchKernelGGL((mfma_dec<false>), dim3(10, 16), dim3(256), 0, stream,
                           O2, BhD3, BlD3, bd3, O3, NUM_GRAPHS, 1160, 512, 1280, 512, 1160);
        hipLaunchKernelGGL(assemble_kernel, dim3(NUM_GRAPHS), dim3(256), 0, stream, O3, out);
        return;
    }

    if (ws_size < NEED_FB) {
        hipLaunchKernelGGL(diag_kernel, dim3(1), dim3(64), 0, stream, out, (float)(ws_size >> 20));
        return;
    }

    // ================= FALLBACK PER-HEAD PATH (Round-9) =================
    ushortT* h3u = (ushortT*)(wsb + 0);
    ushortT* h1u = (ushortT*)(wsb + 0);
    ushortT* h2u = (ushortT*)(wsb + 25600000);
    bf16*    XLb = (bf16*)(wsb + 38400000);
    ushortT* XLu = (ushortT*)(wsb + 38400000);
    bf16*    XRb = (bf16*)(wsb + 64000000);
    ushortT* XRu = (ushortT*)(wsb + 64000000);
    float* G  = (float*)(wsb + 38400000);
    float* O1 = G  + 524288;
    float* O2 = O1 + 524288;
    float* O3 = O2 + 1048576;
    ushortT* BhD3 = (ushortT*)(wsb + 64000000);
    ushortT* BlD3 = (ushortT*)(wsb + 65400000);
    ushortT* BhD2 = (ushortT*)(wsb + 66800000);
    ushortT* BlD2 = (ushortT*)(wsb + 67100000);
    ushortT* BhD1 = (ushortT*)(wsb + 67400000);
    ushortT* BlD1 = (ushortT*)(wsb + 67500000);
    int* counts  = (int*)(wsb + 89600000);
    int* offsets = counts + (N_NODES + 1);
    int* cursor  = offsets + (N_NODES + 1);
    int* srcs    = cursor + (N_NODES + 1);
    int* chunk_sums = srcs + E_TOT;
    int* chunk_base = chunk_sums + 64;
    ushortT* BpL2 = (ushortT*)(wsb + 92000528);
    ushortT* BpR2 = (ushortT*)(wsb + 92049680);
    ushortT* BpL3 = (ushortT*)(wsb + 92098832);
    ushortT* BpR3 = (ushortT*)(wsb + 92295440);

    hipMemsetAsync(counts, 0, sizeof(int) * (N_NODES + 1), stream);
    hipLaunchKernelGGL(hist_kernel, dim3((E_TOT + 255) / 256), dim3(256), 0, stream, ei, counts);
    hipLaunchKernelGGL(scan_sums,   dim3(N_CHUNKS), dim3(256), 0, stream, counts, chunk_sums);
    hipLaunchKernelGGL(scan_chunks, dim3(1), dim3(64), 0, stream, chunk_sums, chunk_base);
    hipLaunchKernelGGL(scan_write,  dim3(N_CHUNKS), dim3(256), 0, stream,
                       counts, chunk_base, offsets);
    hipLaunchKernelGGL(copy_kernel, dim3((N_NODES + 255) / 256), dim3(256), 0, stream,
                       offsets, cursor, N_NODES);
    hipLaunchKernelGGL(scatter_kernel, dim3((E_TOT + 255) / 256), dim3(256), 0, stream,
                       ei, cursor, srcs);

    hipLaunchKernelGGL(repack_kernel, dim3((64 * 384 + 255) / 256), dim3(256), 0, stream,
                       Wl2, BpL2, 64, 384);
    hipLaunchKernelGGL(repack_kernel, dim3((64 * 384 + 255) / 256), dim3(256), 0, stream,
                       Wr2, BpR2, 64, 384);
    hipLaunchKernelGGL(repack_kernel, dim3((128 * 768 + 255) / 256), dim3(256), 0, stream,
                       Wl3, BpL3, 128, 768);
    hipLaunchKernelGGL(repack_kernel, dim3((128 * 768 + 255) / 256), dim3(256), 0, stream,
                       Wr3, BpR3, 128, 768);

    hipLaunchKernelGGL(l1_transform, dim3((N_NODES + 63) / 64), dim3(192), 0, stream,
                       x, Wl1, bl1, Wr1, br1, XLu, XRu, N_NODES);
    hipLaunchKernelGGL((gat_head<64, 0>), AGG_GRID, dim3(256), 0, stream,
                       XLu, XRu, 192, 0,   att1 + 0,   b1, offsets, srcs, h1u, N_NODES);
    hipLaunchKernelGGL((gat_head<64, 1>), AGG_GRID, dim3(256), 0, stream,
                       XLu, XRu, 192, 64,  att1 + 64,  b1, offsets, srcs, h1u, N_NODES);
    hipLaunchKernelGGL((gat_head<64, 2>), AGG_GRID, dim3(256), 0, stream,
                       XLu, XRu, 192, 128, att1 + 128, b1, offsets, srcs, h1u, N_NODES);

    for (int h = 0; h < 3; ++h) {
        hipLaunchKernelGGL((mfma_gemm<64, 128>), dim3(2, 391), dim3(256), 0, stream,
                           h1u, BpL2, BpR2, bl2 + h * 128, br2 + h * 128,
                           XLb, XRb, N_NODES, 384, h * 128);
        if (h == 0)      hipLaunchKernelGGL((gat_head<128, 0>), AGG_GRID, dim3(256), 0, stream,
                             XLu, XRu, 128, 0, att2 + h * 128, b2, offsets, srcs, h2u, N_NODES);
        else if (h == 1) hipLaunchKernelGGL((gat_head<128, 1>), AGG_GRID, dim3(256), 0, stream,
                             XLu, XRu, 128, 0, att2 + h * 128, b2, offsets, srcs, h2u, N_NODES);
        else             hipLaunchKernelGGL((gat_head<128, 2>), AGG_GRID, dim3(256), 0, stream,
                             XLu, XRu, 128, 0, att2 + h * 128, b2, offsets, srcs, h2u, N_NODES);
    }

    for (int h = 0; h < 3; ++h) {
        hipLaunchKernelGGL((mfma_gemm<128, 256>), dim3(4, 391), dim3(256), 0, stream,
                           h2u, BpL3, BpR3, bl3 + h * 256, br3 + h * 256,
                           XLb, XRb, N_NODES, 768, h * 256);
        if (h == 0)      hipLaunchKernelGGL((gat_head<256, 0>), AGG_GRID, dim3(256), 0, stream,
                             XLu, XRu, 256, 0, att3 + h * 256, b3, offsets, srcs, h3u, N_NODES);
        else if (h == 1) hipLaunchKernelGGL((gat_head<256, 1>), AGG_GRID, dim3(256), 0, stream,
                             XLu, XRu, 256, 0, att3 + h * 256, b3, offsets, srcs, h3u, N_NODES);
        else             hipLaunchKernelGGL((gat_head<256, 2>), AGG_GRID, dim3(256), 0, stream,
                             XLu, XRu, 256, 0, att3 + h * 256, b3, offsets, srcs, h3u, N_NODES);
    }

    hipLaunchKernelGGL(repack_split, dim3((64 * 256 + 255) / 256), dim3(256), 0, stream,
                       Wd1, BhD1, BlD1, 64, 256, 256);
    hipLaunchKernelGGL(repack_split, dim3((256 * 512 + 255) / 256), dim3(256), 0, stream,
                       Wd2, BhD2, BlD2, 256, 512, 512);
    hipLaunchKernelGGL(repack_split, dim3((512 * 1280 + 255) / 256), dim3(256), 0, stream,
                       Wd3, BhD3, BlD3, 512, 1160, 1280);

    hipLaunchKernelGGL(pool_kernel, dim3(NUM_GRAPHS), dim3(256), 0, stream, h3u, batch, G);

    hipLaunchKernelGGL((gemm_dec<false>), dim3(1, 64), dim3(256), 0, stream,
                       G, Wmu, bmu, out + MU_OFF, NUM_GRAPHS, 64, 256, 256, 64, 64);
    hipLaunchKernelGGL((gemm_dec<false>), dim3(1, 64), dim3(256), 0, stream,
                       G, Wlv, blv, out + LV_OFF, NUM_GRAPHS, 64, 256, 256, 64, 64);
    hipLaunchKernelGGL((mfma_dec<true>), dim3(2, 16), dim3(256), 0, stream,
                       out + MU_OFF, BhD1, BlD1, bd1, O1, NUM_GRAPHS, 256, 64, 256, 64, 256);
    hipLaunchKernelGGL((mfma_dec<true>), dim3(4, 16), dim3(256), 0, stream,
                       O1, BhD2, BlD2, bd2, O2, NUM_GRAPHS, 512, 256, 512, 256, 512);
    hipLaunchKernelGGL((mfma_dec<false>), dim3(10, 16), dim3(256), 0, stream,
                       O2, BhD3, BlD3, bd3, O3, NUM_GRAPHS, 1160, 512, 1280, 512, 1160);
    hipLaunchKernelGGL(assemble_kernel, dim3(NUM_GRAPHS), dim3(256), 0, stream, O3, out);
}

// Round 11
// 833.489 us; speedup vs baseline: 2.6423x; 1.0154x over previous
//
#include <hip/hip_runtime.h>
#include <hip/hip_bf16.h>

typedef __hip_bfloat16 bf16;
typedef unsigned short ushortT;
typedef ushortT u16x1 __attribute__((ext_vector_type(1)));
typedef ushortT u16x2 __attribute__((ext_vector_type(2)));
typedef ushortT u16x4 __attribute__((ext_vector_type(4)));
typedef ushortT u16x8 __attribute__((ext_vector_type(8)));
typedef __bf16   bf16x8 __attribute__((ext_vector_type(8)));
typedef float    f32x4  __attribute__((ext_vector_type(4)));

#define N_NODES    50000
#define E_EDGES    400000
#define E_TOT      450000
#define NUM_GRAPHS 2048
#define SCAN_CHUNK 1024
#define N_CHUNKS   ((N_NODES + SCAN_CHUNK - 1) / SCAN_CHUNK)   // 49

// ---------- helpers ----------
__device__ __forceinline__ float fromb(ushortT u) {
    unsigned int i = ((unsigned int)u) << 16;
    return __builtin_bit_cast(float, i);
}
__device__ __forceinline__ ushortT tob(float v) {
    bf16 h = __float2bfloat16(v);
    return __builtin_bit_cast(ushortT, h);
}

template <int VEC> struct RawV;
template <> struct RawV<1> { using T = u16x1; };
template <> struct RawV<2> { using T = u16x2; };
template <> struct RawV<4> { using T = u16x4; };

__device__ __forceinline__ void cvtv(u16x1 r, float* f) { f[0] = fromb(r[0]); }
__device__ __forceinline__ void cvtv(u16x2 r, float* f) { f[0] = fromb(r.x); f[1] = fromb(r.y); }
__device__ __forceinline__ void cvtv(u16x4 r, float* f) { f[0] = fromb(r.x); f[1] = fromb(r.y);
                                                          f[2] = fromb(r.z); f[3] = fromb(r.w); }

// ---------- diagnostic ----------
__global__ void diag_kernel(float* out, float v) { if (threadIdx.x == 0) out[0] = v; }

// ---------- CSR build ----------
__global__ void hist_kernel(const int* __restrict__ ei, int* __restrict__ counts) {
    int e = blockIdx.x * 256 + threadIdx.x;
    if (e >= E_TOT) return;
    int d = (e < E_EDGES) ? ei[E_EDGES + e] : (e - E_EDGES);
    atomicAdd(&counts[d], 1);
}

__global__ __launch_bounds__(256) void scan_sums(const int* __restrict__ counts,
                                                 int* __restrict__ chunk_sums) {
    __shared__ int red[4];
    int base = blockIdx.x * SCAN_CHUNK;
    int t = threadIdx.x;
    int s = 0;
    #pragma unroll
    for (int i = 0; i < 4; i++) {
        int idx = base + t + i * 256;
        if (idx < N_NODES) s += counts[idx];
    }
    #pragma unroll
    for (int o = 32; o > 0; o >>= 1) s += __shfl_xor(s, o);
    if ((t & 63) == 0) red[t >> 6] = s;
    __syncthreads();
    if (t == 0) chunk_sums[blockIdx.x] = red[0] + red[1] + red[2] + red[3];
}

__global__ __launch_bounds__(64) void scan_chunks(const int* __restrict__ chunk_sums,
                                                  int* __restrict__ chunk_base) {
    int t = threadIdx.x;
    int v = (t < N_CHUNKS) ? chunk_sums[t] : 0;
    int orig = v;
    #pragma unroll
    for (int o = 1; o < 64; o <<= 1) {
        int u = __shfl_up(v, o);
        if (t >= o) v += u;
    }
    if (t < N_CHUNKS) chunk_base[t] = v - orig;   // exclusive
}

// writes offsets AND cursor (copy folded in)
__global__ __launch_bounds__(256) void scan_write(const int* __restrict__ counts,
                                                  const int* __restrict__ chunk_base,
                                                  int* __restrict__ offsets,
                                                  int* __restrict__ cursor) {
    __shared__ int wsum[4];
    int chunk = blockIdx.x;
    int base = chunk * SCAN_CHUNK;
    int t = threadIdx.x;
    int lane = t & 63, w = t >> 6;

    int c[4];
    int e0 = base + t * 4;
    #pragma unroll
    for (int k = 0; k < 4; k++) {
        int idx = e0 + k;
        c[k] = (idx < N_NODES) ? counts[idx] : 0;
    }
    int local = c[0] + c[1] + c[2] + c[3];

    int v = local;
    #pragma unroll
    for (int o = 1; o < 64; o <<= 1) {
        int u = __shfl_up(v, o);
        if (lane >= o) v += u;
    }
    if (lane == 63) wsum[w] = v;
    __syncthreads();
    int wbase = 0;
    for (int i = 0; i < w; i++) wbase += wsum[i];

    int run = chunk_base[chunk] + wbase + (v - local);
    #pragma unroll
    for (int k = 0; k < 4; k++) {
        int idx = e0 + k;
        if (idx < N_NODES) { offsets[idx] = run; cursor[idx] = run; }
        run += c[k];
    }
    if (chunk == 0 && t == 0) offsets[N_NODES] = E_TOT;
}

__global__ void scatter_kernel(const int* __restrict__ ei, int* __restrict__ cursor,
                               int* __restrict__ srcs) {
    int e = blockIdx.x * 256 + threadIdx.x;
    if (e >= E_TOT) return;
    int s, d;
    if (e < E_EDGES) { s = ei[e]; d = ei[E_EDGES + e]; }
    else             { s = d = e - E_EDGES; }
    int pos = atomicAdd(&cursor[d], 1);
    srcs[pos] = s;
}

// ---------- merged GAT weight repack: 4 matrices in one launch ----------
__global__ void repack_gat_kernel(const float* __restrict__ Wl2, const float* __restrict__ Wr2,
                                  const float* __restrict__ Wl3, const float* __restrict__ Wr3,
                                  ushortT* __restrict__ BpL2, ushortT* __restrict__ BpR2,
                                  ushortT* __restrict__ BpL3, ushortT* __restrict__ BpR3) {
    const int S2 = 64 * 384, S3 = 128 * 768;
    int idx = blockIdx.x * 256 + threadIdx.x;
    const float* W; ushortT* Bp; int N, local;
    if (idx < S2)                { W = Wl2; Bp = BpL2; N = 384; local = idx; }
    else if (idx < 2 * S2)       { W = Wr2; Bp = BpR2; N = 384; local = idx - S2; }
    else if (idx < 2 * S2 + S3)  { W = Wl3; Bp = BpL3; N = 768; local = idx - 2 * S2; }
    else if (idx < 2 * (S2 + S3)){ W = Wr3; Bp = BpR3; N = 768; local = idx - 2 * S2 - S3; }
    else return;
    int k = local / N, n = local % N;
    Bp[((size_t)(k >> 3) * N + n) * 8 + (k & 7)] = tob(W[(size_t)k * N + n]);
}

// ---------- merged decoder split-repack: 3 matrices in one launch ----------
__global__ void repack_split3(const float* __restrict__ Wd1, const float* __restrict__ Wd2,
                              const float* __restrict__ Wd3,
                              ushortT* __restrict__ BhD1, ushortT* __restrict__ BlD1,
                              ushortT* __restrict__ BhD2, ushortT* __restrict__ BlD2,
                              ushortT* __restrict__ BhD3, ushortT* __restrict__ BlD3) {
    const int T1 = 64 * 256, T2 = 256 * 512, T3 = 512 * 1280;
    int idx = blockIdx.x * 256 + threadIdx.x;
    const float* W; ushortT *Bh, *Bl; int Npad, N, local;
    if (idx < T1)                { W = Wd1; Bh = BhD1; Bl = BlD1; Npad = 256;  N = 256;  local = idx; }
    else if (idx < T1 + T2)      { W = Wd2; Bh = BhD2; Bl = BlD2; Npad = 512;  N = 512;  local = idx - T1; }
    else if (idx < T1 + T2 + T3) { W = Wd3; Bh = BhD3; Bl = BlD3; Npad = 1280; N = 1160; local = idx - T1 - T2; }
    else return;
    int k = local / Npad, n = local % Npad;
    float v = (n < N) ? W[(size_t)k * N + n] : 0.f;
    ushortT h = tob(v);
    size_t o = ((size_t)(k >> 3) * Npad + n) * 8 + (k & 7);
    Bh[o] = h;
    Bl[o] = tob(v - fromb(h));
}

// ---------- layer-1 fused transform (K=11, N=192) ----------
__global__ __launch_bounds__(192) void l1_transform(const float* __restrict__ x,
                                                    const float* __restrict__ Wl,
                                                    const float* __restrict__ bl,
                                                    const float* __restrict__ Wr,
                                                    const float* __restrict__ br,
                                                    ushortT* __restrict__ XL,
                                                    ushortT* __restrict__ XR, int M) {
    __shared__ float xs[64][11];
    const int tid = threadIdx.x;
    const int bm  = blockIdx.x * 64;
    const int rows = (M - bm < 64) ? (M - bm) : 64;

    float wl[11], wr[11];
    #pragma unroll
    for (int k = 0; k < 11; k++) {
        wl[k] = Wl[k * 192 + tid];
        wr[k] = Wr[k * 192 + tid];
    }
    float blc = bl[tid], brc = br[tid];

    for (int i = tid; i < rows * 11; i += 192)
        xs[i / 11][i % 11] = x[(size_t)bm * 11 + i];
    __syncthreads();

    for (int r = 0; r < rows; r++) {
        float al = blc, ar = brc;
        #pragma unroll
        for (int k = 0; k < 11; k++) {
            float xv = xs[r][k];
            al += xv * wl[k];
            ar += xv * wr[k];
        }
        size_t o = (size_t)(bm + r) * 192 + tid;
        XL[o] = tob(al);
        XR[o] = tob(ar);
    }
}

// ---------- small fp32 SIMT GEMM (mu / logvar heads) ----------
template <bool RELU>
__global__ __launch_bounds__(256) void gemm_dec(const float* __restrict__ A,
                                                const float* __restrict__ B,
                                                const float* __restrict__ bias,
                                                float* __restrict__ C,
                                                int M, int N, int K,
                                                int lda, int ldb, int ldc) {
    __shared__ float As[32][33];
    __shared__ float Bs[32][65];
    int tid = threadIdx.x;
    int tm = tid >> 4, tn = tid & 15;
    int bm = blockIdx.y * 32, bn = blockIdx.x * 64;
    float acc[2][4] = {};
    for (int k0 = 0; k0 < K; k0 += 32) {
        #pragma unroll
        for (int i = 0; i < 4; i++) {
            int e = tid + i * 256;
            int r = e >> 5, k = e & 31;
            int row = bm + r, kk = k0 + k;
            float v = 0.f;
            if (row < M && kk < K) v = A[(size_t)row * lda + kk];
            As[k][r] = v;
        }
        #pragma unroll
        for (int i = 0; i < 8; i++) {
            int e = tid + i * 256;
            int k = e >> 6, n = e & 63;
            int kk = k0 + k, col = bn + n;
            float v = 0.f;
            if (kk < K && col < N) v = B[(size_t)kk * ldb + col];
            Bs[k][n] = v;
        }
        __syncthreads();
        #pragma unroll
        for (int k = 0; k < 32; k++) {
            float a0 = As[k][tm * 2 + 0], a1 = As[k][tm * 2 + 1];
            float b0 = Bs[k][tn * 4 + 0], b1 = Bs[k][tn * 4 + 1];
            float b2 = Bs[k][tn * 4 + 2], b3 = Bs[k][tn * 4 + 3];
            acc[0][0] += a0 * b0; acc[0][1] += a0 * b1; acc[0][2] += a0 * b2; acc[0][3] += a0 * b3;
            acc[1][0] += a1 * b0; acc[1][1] += a1 * b1; acc[1][2] += a1 * b2; acc[1][3] += a1 * b3;
        }
        __syncthreads();
    }
    #pragma unroll
    for (int i = 0; i < 2; i++) {
        int row = bm + tm * 2 + i;
        if (row >= M) continue;
        #pragma unroll
        for (int j = 0; j < 4; j++) {
            int col = bn + tn * 4 + j;
            if (col >= N) continue;
            float v = acc[i][j] + bias[col];
            if (RELU) v = fmaxf(v, 0.f);
            C[(size_t)row * ldc + col] = v;
        }
    }
}

// ---------- split-bf16 MFMA decoder GEMM ----------
template <bool RELU>
__global__ __launch_bounds__(256) void mfma_dec(const float* __restrict__ A,
                                                const ushortT* __restrict__ Bh,
                                                const ushortT* __restrict__ Bl,
                                                const float* __restrict__ bias,
                                                float* __restrict__ C,
                                                int M, int N, int K, int Npad,
                                                int lda, int ldc) {
    __shared__ ushortT Ah[4 * 128 * 8];
    __shared__ ushortT Al[4 * 128 * 8];
    const int tid = threadIdx.x;
    const int bm = blockIdx.y * 128;
    const int bn = blockIdx.x * 128;
    const int lane = tid & 63;
    const int l15 = lane & 15, lg = lane >> 4;
    const int wid = tid >> 6;
    const int wm = wid >> 1, wn = wid & 1;

    f32x4 acc[4][4] = {};

    for (int k0 = 0; k0 < K; k0 += 32) {
        __syncthreads();
        #pragma unroll
        for (int it = 0; it < 2; it++) {
            int c = tid + it * 256;
            int row = c >> 2, kg = c & 3;
            const float* ap = A + (size_t)(bm + row) * lda + k0 + kg * 8;
            u16x8 hv, lv;
            #pragma unroll
            for (int i = 0; i < 8; i++) {
                float v = ap[i];
                ushortT h = tob(v);
                hv[i] = h;
                lv[i] = tob(v - fromb(h));
            }
            int unit = (kg * 128 + row) ^ kg;
            *reinterpret_cast<u16x8*>(&Ah[unit * 8]) = hv;
            *reinterpret_cast<u16x8*>(&Al[unit * 8]) = lv;
        }
        __syncthreads();

        bf16x8 ah[4], al[4], bhf[4], blf[4];
        #pragma unroll
        for (int mf = 0; mf < 4; mf++) {
            int row = wm * 64 + mf * 16 + l15;
            int unit = (lg * 128 + row) ^ lg;
            ah[mf] = __builtin_bit_cast(bf16x8, *reinterpret_cast<const u16x8*>(&Ah[unit * 8]));
            al[mf] = __builtin_bit_cast(bf16x8, *reinterpret_cast<const u16x8*>(&Al[unit * 8]));
        }
        int kgG = (k0 >> 3) + lg;
        #pragma unroll
        for (int nf = 0; nf < 4; nf++) {
            int n = bn + wn * 64 + nf * 16 + l15;
            size_t o = ((size_t)kgG * Npad + n) * 8;
            bhf[nf] = __builtin_bit_cast(bf16x8, *reinterpret_cast<const u16x8*>(Bh + o));
            blf[nf] = __builtin_bit_cast(bf16x8, *reinterpret_cast<const u16x8*>(Bl + o));
        }
        #pragma unroll
        for (int mf = 0; mf < 4; mf++) {
            #pragma unroll
            for (int nf = 0; nf < 4; nf++) {
                acc[mf][nf] = __builtin_amdgcn_mfma_f32_16x16x32_bf16(ah[mf], bhf[nf], acc[mf][nf], 0, 0, 0);
                acc[mf][nf] = __builtin_amdgcn_mfma_f32_16x16x32_bf16(ah[mf], blf[nf], acc[mf][nf], 0, 0, 0);
                acc[mf][nf] = __builtin_amdgcn_mfma_f32_16x16x32_bf16(al[mf], bhf[nf], acc[mf][nf], 0, 0, 0);
            }
        }
    }

    #pragma unroll
    for (int nf = 0; nf < 4; nf++) {
        int col = bn + wn * 64 + nf * 16 + l15;
        if (col >= N) continue;
        float bv = bias[col];
        #pragma unroll
        for (int mf = 0; mf < 4; mf++) {
            #pragma unroll
            for (int q = 0; q < 4; q++) {
                int row = bm + wm * 64 + mf * 16 + lg * 4 + q;
                if (row < M) {
                    float v = acc[mf][nf][q] + bv;
                    if (RELU) v = fmaxf(v, 0.f);
                    C[(size_t)row * ldc + col] = v;
                }
            }
        }
    }
}

// ---------- full-width MFMA bf16 GEMM: all heads, Wl|Wr, one launch ----------
template <int K, int NW>
__global__ __launch_bounds__(256) void mfma_gemmF(const ushortT* __restrict__ A,
                                                  const ushortT* __restrict__ BpL,
                                                  const ushortT* __restrict__ BpR,
                                                  const float* __restrict__ bl,
                                                  const float* __restrict__ br,
                                                  bf16* __restrict__ XL,
                                                  bf16* __restrict__ XR,
                                                  int M) {
    constexpr int KU = K / 8;
    __shared__ ushortT Alds[KU * 128 * 8];
    const int tid = threadIdx.x;
    const int bm  = blockIdx.y * 128;
    const int bnb = blockIdx.x * 128;

    for (int u = tid; u < 128 * KU; u += 256) {
        int row = u / KU, kg = u % KU;
        int rg = bm + row; if (rg > M - 1) rg = M - 1;
        u16x8 v = *reinterpret_cast<const u16x8*>(A + (size_t)rg * K + kg * 8);
        int unit = (kg * 128 + row) ^ (kg & 7);
        *reinterpret_cast<u16x8*>(&Alds[unit * 8]) = v;
    }
    __syncthreads();

    const int lane = tid & 63;
    const int l15 = lane & 15, lg = lane >> 4;
    const int wid = tid >> 6;
    const int wm = wid >> 1, wn = wid & 1;

    f32x4 acc[4][4] = {};
    #pragma unroll
    for (int s = 0; s < K / 32; s++) {
        int kg = s * 4 + lg;
        bf16x8 a[4], b[4];
        #pragma unroll
        for (int mf = 0; mf < 4; mf++) {
            int row = wm * 64 + mf * 16 + l15;
            int unit = (kg * 128 + row) ^ (kg & 7);
            a[mf] = __builtin_bit_cast(bf16x8,
                    *reinterpret_cast<const u16x8*>(&Alds[unit * 8]));
        }
        #pragma unroll
        for (int nf = 0; nf < 4; nf++) {
            int cb = bnb + wn * 64 + nf * 16;
            const ushortT* bp; int n;
            if (cb < NW) { bp = BpL; n = cb + l15; }
            else         { bp = BpR; n = cb - NW + l15; }
            b[nf] = __builtin_bit_cast(bf16x8,
                    *reinterpret_cast<const u16x8*>(bp + ((size_t)kg * NW + n) * 8));
        }
        #pragma unroll
        for (int mf = 0; mf < 4; mf++)
            #pragma unroll
            for (int nf = 0; nf < 4; nf++)
                acc[mf][nf] = __builtin_amdgcn_mfma_f32_16x16x32_bf16(
                    a[mf], b[nf], acc[mf][nf], 0, 0, 0);
    }

    #pragma unroll
    for (int nf = 0; nf < 4; nf++) {
        int cb = bnb + wn * 64 + nf * 16;
        bf16* Cp; const float* bs; int c;
        if (cb < NW) { Cp = XL; bs = bl; c = cb + l15; }
        else         { Cp = XR; bs = br; c = cb - NW + l15; }
        float bv = bs[c];
        #pragma unroll
        for (int mf = 0; mf < 4; mf++) {
            #pragma unroll
            for (int q = 0; q < 4; q++) {
                int r = bm + wm * 64 + mf * 16 + lg * 4 + q;
                if (r < M) Cp[(size_t)r * NW + c] = __float2bfloat16(acc[mf][nf][q] + bv);
            }
        }
    }
}

// ---------- fused 3-head GAT aggregation, depth-3 gather pipeline ----------
// XL/XR full-width [N, 3*CHH]; att [3*CHH] head-major; OUT [N, CHH] = relu(mean+bias).
template <int CHH>
__global__ __launch_bounds__(256) void gat_fused(const ushortT* __restrict__ XL,
                                                 const ushortT* __restrict__ XR,
                                                 const float* __restrict__ att,
                                                 const float* __restrict__ bias,
                                                 const int* __restrict__ offsets,
                                                 const int* __restrict__ srcs,
                                                 ushortT* __restrict__ OUT, int N) {
    constexpr int VEC = CHH / 64;
    constexpr int LDX = 3 * CHH;
    using RT = typename RawV<VEC>::T;
    int wid  = threadIdx.x >> 6;
    int lane = threadIdx.x & 63;
    int n = blockIdx.x * 4 + wid;
    if (n >= N) return;

    const int loff = VEC * lane;
    float xr_[3][VEC], a06[3][VEC], a04[3][VEC], acc[3][VEC];
    const ushortT* xrp = XR + (size_t)n * LDX + loff;
    #pragma unroll
    for (int h = 0; h < 3; h++) {
        RT xrv = *reinterpret_cast<const RT*>(xrp + h * CHH);
        #pragma unroll
        for (int i = 0; i < VEC; i++) {
            xr_[h][i] = fromb(xrv[i]);
            float a = att[h * CHH + loff + i];
            a06[h][i] = 0.6f * a;
            a04[h][i] = 0.4f * a;
            acc[h][i] = 0.f;
        }
    }
    float d0 = 0.f, d1 = 0.f, d2 = 0.f;

    const int e0 = offsets[n];
    const int deg = offsets[n + 1] - e0;

    for (int base = 0; base < deg; base += 64) {
        int cnt = deg - base; if (cnt > 64) cnt = 64;
        int sl = srcs[e0 + base + ((lane < cnt) ? lane : (cnt - 1))];

        RT A0, A1, A2, B0, B1, B2, C0, C1, C2;
        {
            const ushortT* r = XL + (size_t)__shfl(sl, 0) * LDX + loff;
            A0 = *reinterpret_cast<const RT*>(r);
            A1 = *reinterpret_cast<const RT*>(r + CHH);
            A2 = *reinterpret_cast<const RT*>(r + 2 * CHH);
        }
        if (cnt > 1) {
            const ushortT* r = XL + (size_t)__shfl(sl, 1) * LDX + loff;
            B0 = *reinterpret_cast<const RT*>(r);
            B1 = *reinterpret_cast<const RT*>(r + CHH);
            B2 = *reinterpret_cast<const RT*>(r + 2 * CHH);
        } else { B0 = A0; B1 = A1; B2 = A2; }
        if (cnt > 2) {
            const ushortT* r = XL + (size_t)__shfl(sl, 2) * LDX + loff;
            C0 = *reinterpret_cast<const RT*>(r);
            C1 = *reinterpret_cast<const RT*>(r + CHH);
            C2 = *reinterpret_cast<const RT*>(r + 2 * CHH);
        } else { C0 = A0; C1 = A1; C2 = A2; }

        for (int j = 0; j < cnt; ++j) {
            RT c0 = A0, c1 = A1, c2 = A2;
            A0 = B0; A1 = B1; A2 = B2;
            B0 = C0; B1 = C1; B2 = C2;
            if (j + 3 < cnt) {
                const ushortT* r = XL + (size_t)__shfl(sl, j + 3) * LDX + loff;
                C0 = *reinterpret_cast<const RT*>(r);
                C1 = *reinterpret_cast<const RT*>(r + CHH);
                C2 = *reinterpret_cast<const RT*>(r + 2 * CHH);
            }

            float xl0[VEC], xl1[VEC], xl2[VEC];
            cvtv(c0, xl0); cvtv(c1, xl1); cvtv(c2, xl2);
            float p0 = 0.f, p1 = 0.f, p2 = 0.f;
            #pragma unroll
            for (int i = 0; i < VEC; i++) {
                float v0 = xl0[i] + xr_[0][i];
                float v1 = xl1[i] + xr_[1][i];
                float v2 = xl2[i] + xr_[2][i];
                p0 = fmaf(a06[0][i], v0, p0); p0 = fmaf(a04[0][i], fabsf(v0), p0);
                p1 = fmaf(a06[1][i], v1, p1); p1 = fmaf(a04[1][i], fabsf(v1), p1);
                p2 = fmaf(a06[2][i], v2, p2); p2 = fmaf(a04[2][i], fabsf(v2), p2);
            }
            #pragma unroll
            for (int ofs = 32; ofs > 0; ofs >>= 1) {
                p0 += __shfl_xor(p0, ofs);
                p1 += __shfl_xor(p1, ofs);
                p2 += __shfl_xor(p2, ofs);
            }

            float w0 = __expf(p0), w1 = __expf(p1), w2 = __expf(p2);
            d0 += w0; d1 += w1; d2 += w2;
            #pragma unroll
            for (int i = 0; i < VEC; i++) {
                acc[0][i] = fmaf(w0, xl0[i], acc[0][i]);
                acc[1][i] = fmaf(w1, xl1[i], acc[1][i]);
                acc[2][i] = fmaf(w2, xl2[i], acc[2][i]);
            }
        }
    }

    float i0 = 1.f / (d0 + 1e-16f);
    float i1 = 1.f / (d1 + 1e-16f);
    float i2 = 1.f / (d2 + 1e-16f);
    RT ov;
    #pragma unroll
    for (int i = 0; i < VEC; i++) {
        int c = loff + i;
        float v = (acc[0][i] * i0 + acc[1][i] * i1 + acc[2][i] * i2) * (1.f / 3.f) + bias[c];
        ov[i] = tob(fmaxf(v, 0.f));
    }
    *reinterpret_cast<RT*>(&OUT[(size_t)n * CHH + loff]) = ov;
}

// ---------- pool ----------
__global__ void pool_kernel(const ushortT* __restrict__ h3, const int* __restrict__ batch,
                            float* __restrict__ G) {
    int g = blockIdx.x;
    int c = threadIdx.x;
    int lo = 0, hi = N_NODES;
    while (lo < hi) { int mid = (lo + hi) >> 1; if (batch[mid] < g) lo = mid + 1; else hi = mid; }
    int s0 = lo;
    hi = N_NODES;
    while (lo < hi) { int mid = (lo + hi) >> 1; if (batch[mid] < g + 1) lo = mid + 1; else hi = mid; }
    int s1 = lo;
    float sum = 0.f;
    for (int n = s0; n < s1; n++) sum += fromb(h3[(size_t)n * 256 + c]);
    G[(size_t)g * 256 + c] = sum;
}

// ---------- output assembly ----------
__global__ void assemble_kernel(const float* __restrict__ o3, float* __restrict__ out) {
    int g = blockIdx.x;
    const float* row = o3 + (size_t)g * 1160;
    float* xrec = out + (size_t)g * 319;
    for (int p = threadIdx.x; p < 319; p += 256) xrec[p] = row[p];
    float* adj = out + 653312 + (size_t)g * 841;
    for (int p = threadIdx.x; p < 841; p += 256) {
        int i = p / 29, j = p % 29;
        adj[p] = 0.5f * (row[319 + p] + row[319 + j * 29 + i]);
    }
}

// ---------- launch ----------
extern "C" void kernel_launch(void* const* d_in, const int* in_sizes, int n_in,
                              void* d_out, int out_size, void* d_ws, size_t ws_size,
                              hipStream_t stream) {
    const float* x     = (const float*)d_in[0];
    const int*   ei    = (const int*)d_in[1];
    const int*   batch = (const int*)d_in[2];
    const float* Wl1 = (const float*)d_in[3];
    const float* bl1 = (const float*)d_in[4];
    const float* Wr1 = (const float*)d_in[5];
    const float* br1 = (const float*)d_in[6];
    const float* att1= (const float*)d_in[7];
    const float* b1  = (const float*)d_in[8];
    const float* Wl2 = (const float*)d_in[9];
    const float* bl2 = (const float*)d_in[10];
    const float* Wr2 = (const float*)d_in[11];
    const float* br2 = (const float*)d_in[12];
    const float* att2= (const float*)d_in[13];
    const float* b2  = (const float*)d_in[14];
    const float* Wl3 = (const float*)d_in[15];
    const float* bl3 = (const float*)d_in[16];
    const float* Wr3 = (const float*)d_in[17];
    const float* br3 = (const float*)d_in[18];
    const float* att3= (const float*)d_in[19];
    const float* b3  = (const float*)d_in[20];
    const float* Wmu = (const float*)d_in[21];
    const float* bmu = (const float*)d_in[22];
    const float* Wlv = (const float*)d_in[23];
    const float* blv = (const float*)d_in[24];
    const float* Wd1 = (const float*)d_in[25];
    const float* bd1 = (const float*)d_in[26];
    const float* Wd2 = (const float*)d_in[27];
    const float* bd2 = (const float*)d_in[28];
    const float* Wd3 = (const float*)d_in[29];
    const float* bd3 = (const float*)d_in[30];
    float* out = (float*)d_out;

    const int MU_OFF = 2375680;
    const int LV_OFF = 2506752;
    char* wsb = (char*)d_ws;

    const size_t NEED_FULL = 194892064;
    const dim3 AGG_GRID(N_NODES / 4);

    if (ws_size < NEED_FULL) {
        hipLaunchKernelGGL(diag_kernel, dim3(1), dim3(64), 0, stream, out, (float)(ws_size >> 20));
        return;
    }

    // ---- workspace layout (full-width path) ----
    ushortT* h3u = (ushortT*)(wsb + 0);          // 50000x256
    ushortT* h1u = (ushortT*)(wsb + 0);          // 50000x64 (disjoint lifetime)
    ushortT* h2u = (ushortT*)(wsb + 25600000);   // 50000x128
    bf16*    XLb = (bf16*)(wsb + 38400000);      // up to 50000x768
    ushortT* XLu = (ushortT*)(wsb + 38400000);
    bf16*    XRb = (bf16*)(wsb + 115200000);
    ushortT* XRu = (ushortT*)(wsb + 115200000);
    float* G  = (float*)(wsb + 38400000);        // decoder scratch aliases XL
    float* O1 = G  + 524288;
    float* O2 = O1 + 524288;
    float* O3 = O2 + 1048576;
    ushortT* BhD3 = (ushortT*)(wsb + 115200000); // alias XR (dead after last gat)
    ushortT* BlD3 = (ushortT*)(wsb + 116600000);
    ushortT* BhD2 = (ushortT*)(wsb + 118000000);
    ushortT* BlD2 = (ushortT*)(wsb + 118300000);
    ushortT* BhD1 = (ushortT*)(wsb + 118600000);
    ushortT* BlD1 = (ushortT*)(wsb + 118700000);
    int* counts  = (int*)(wsb + 192000000);
    int* offsets = counts + (N_NODES + 1);
    int* cursor  = offsets + (N_NODES + 1);
    int* srcs    = cursor + (N_NODES + 1);
    int* chunk_sums = srcs + E_TOT;
    int* chunk_base = chunk_sums + 64;
    ushortT* BpL2 = (ushortT*)(wsb + 194400544); // 16B-aligned
    ushortT* BpR2 = (ushortT*)(wsb + 194449696);
    ushortT* BpL3 = (ushortT*)(wsb + 194498848);
    ushortT* BpR3 = (ushortT*)(wsb + 194695456);

    // ---- CSR build ----
    hipMemsetAsync(counts, 0, sizeof(int) * (N_NODES + 1), stream);
    hipLaunchKernelGGL(hist_kernel, dim3((E_TOT + 255) / 256), dim3(256), 0, stream, ei, counts);
    hipLaunchKernelGGL(scan_sums,   dim3(N_CHUNKS), dim3(256), 0, stream, counts, chunk_sums);
    hipLaunchKernelGGL(scan_chunks, dim3(1), dim3(64), 0, stream, chunk_sums, chunk_base);
    hipLaunchKernelGGL(scan_write,  dim3(N_CHUNKS), dim3(256), 0, stream,
                       counts, chunk_base, offsets, cursor);
    hipLaunchKernelGGL(scatter_kernel, dim3((E_TOT + 255) / 256), dim3(256), 0, stream,
                       ei, cursor, srcs);

    // ---- GAT weight repack (merged) ----
    hipLaunchKernelGGL(repack_gat_kernel, dim3(960), dim3(256), 0, stream,
                       Wl2, Wr2, Wl3, Wr3, BpL2, BpR2, BpL3, BpR3);

    // ---- layer 1 ----
    hipLaunchKernelGGL(l1_transform, dim3((N_NODES + 63) / 64), dim3(192), 0, stream,
                       x, Wl1, bl1, Wr1, br1, XLu, XRu, N_NODES);
    hipLaunchKernelGGL((gat_fused<64>), AGG_GRID, dim3(256), 0, stream,
                       XLu, XRu, att1, b1, offsets, srcs, h1u, N_NODES);
    // ---- layer 2 ----
    hipLaunchKernelGGL((mfma_gemmF<64, 384>), dim3(6, 391), dim3(256), 0, stream,
                       h1u, BpL2, BpR2, bl2, br2, XLb, XRb, N_NODES);
    hipLaunchKernelGGL((gat_fused<128>), AGG_GRID, dim3(256), 0, stream,
                       XLu, XRu, att2, b2, offsets, srcs, h2u, N_NODES);
    // ---- layer 3 ----
    hipLaunchKernelGGL((mfma_gemmF<128, 768>), dim3(12, 391), dim3(256), 0, stream,
                       h2u, BpL3, BpR3, bl3, br3, XLb, XRb, N_NODES);
    hipLaunchKernelGGL((gat_fused<256>), AGG_GRID, dim3(256), 0, stream,
                       XLu, XRu, att3, b3, offsets, srcs, h3u, N_NODES);

    // ---- decoder split-weight repack (merged; XR dead now) ----
    hipLaunchKernelGGL(repack_split3, dim3(3136), dim3(256), 0, stream,
                       Wd1, Wd2, Wd3, BhD1, BlD1, BhD2, BlD2, BhD3, BlD3);

    // ---- pool ----
    hipLaunchKernelGGL(pool_kernel, dim3(NUM_GRAPHS), dim3(256), 0, stream, h3u, batch, G);

    // ---- VAE heads + decoder ----
    hipLaunchKernelGGL((gemm_dec<false>), dim3(1, 64), dim3(256), 0, stream,
                       G, Wmu, bmu, out + MU_OFF, NUM_GRAPHS, 64, 256, 256, 64, 64);
    hipLaunchKernelGGL((gemm_dec<false>), dim3(1, 64), dim3(256), 0, stream,
                       G, Wlv, blv, out + LV_OFF, NUM_GRAPHS, 64, 256, 256, 64, 64);
    hipLaunchKernelGGL((mfma_dec<true>), dim3(2, 16), dim3(256), 0, stream,
                       out + MU_OFF, BhD1, BlD1, bd1, O1, NUM_GRAPHS, 256, 64, 256, 64, 256);
    hipLaunchKernelGGL((mfma_dec<true>), dim3(4, 16), dim3(256), 0, stream,
                       O1, BhD2, BlD2, bd2, O2, NUM_GRAPHS, 512, 256, 512, 256, 512);
    hipLaunchKernelGGL((mfma_dec<false>), dim3(10, 16), dim3(256), 0, stream,
                       O2, BhD3, BlD3, bd3, O3, NUM_GRAPHS, 1160, 512, 1280, 512, 1160);
    hipLaunchKernelGGL(assemble_kernel, dim3(NUM_GRAPHS), dim3(256), 0, stream, O3, out);
}